// Round 4
// baseline (2392.247 us; speedup 1.0000x reference)
//
#include <hip/hip_runtime.h>
#include <math.h>

// x[50000,128] w1[128,64] b1[64] w2[192,16] b2[16] lin_w[48,16] lin_b[16]
// edge_index[2,800000] edge_index2[2,3000000] (int32 on device, row0=src, row1=dst)
//
// Strategy: coarse dst-partition (64 nodes/bucket) with LDS-staged dense writes,
// then per-bucket LDS-atomic aggregation (ds_add_f32). No global float atomics,
// no fine CSR sort. Packed edge word: src(16b) | dstlocal(6b)<<16 | bucket(10b)<<22.

#define NPB   64      // nodes per bucket
#define CHUNK 16384   // edges per partition block

// ---------------- GEMM1: HW1 = x @ w1  ([n,128]@[128,64]) ----------------
__global__ void k_gemm1(const float* __restrict__ x, const float* __restrict__ w1,
                        float* __restrict__ hw, int n) {
    __shared__ float ws[128 * 64];
    __shared__ float xs[4 * 128];
    int t = threadIdx.x;
    for (int i = t; i < 128 * 64; i += 256) ws[i] = w1[i];
    int row0 = blockIdx.x * 4;
    for (int i = t; i < 4 * 128; i += 256) {
        int r = row0 + (i >> 7);
        xs[i] = (r < n) ? x[r * 128 + (i & 127)] : 0.f;
    }
    __syncthreads();
    int r = t >> 6, c = t & 63;
    int v = row0 + r;
    if (v >= n) return;
    float acc = 0.f;
    const float* xr = &xs[r * 128];
    #pragma unroll 8
    for (int k = 0; k < 128; ++k) acc += xr[k] * ws[k * 64 + c];
    hw[v * 64 + c] = acc;
}

// ------- histogram of dst buckets (LDS-staged) + global degree atomics -------
__global__ void k_histdeg(const int* __restrict__ dst, int* __restrict__ deg,
                          int* __restrict__ bhist, int E) {
    __shared__ int lh[1024];
    int t = threadIdx.x;
    for (int i = t; i < 1024; i += 256) lh[i] = 0;
    __syncthreads();
    int base = blockIdx.x * 4096;
    int cnt = min(4096, E - base);
    for (int i = t; i < cnt; i += 256) {
        int d = dst[base + i];
        atomicAdd(&deg[d], 1);
        atomicAdd(&lh[d >> 6], 1);
    }
    __syncthreads();
    for (int b = t; b < 1024; b += 256)
        if (lh[b]) atomicAdd(&bhist[b], lh[b]);
}

__global__ void k_dinv(const int* __restrict__ deg1, float* __restrict__ dinv1,
                       const int* __restrict__ deg2, float* __restrict__ dinv2, int n) {
    int i = blockIdx.x * 256 + threadIdx.x;
    if (i >= n) return;
    int d = deg1[i];
    dinv1[i] = (d > 0) ? rsqrtf((float)d) : 0.f;
    d = deg2[i];
    dinv2[i] = (d > 0) ? rsqrtf((float)d) : 0.f;
}

// ------- scan bucket histograms -> bbase (exclusive) and bcur (cursor) -------
// grid = 2 (block 0: set A, block 1: set B), 64 threads
__global__ void k_bscan(const int* __restrict__ bhA, int* __restrict__ bbA, int* __restrict__ bcA,
                        const int* __restrict__ bhB, int* __restrict__ bbB, int* __restrict__ bcB,
                        int B) {
    const int* bh = blockIdx.x ? bhB : bhA;
    int* bb = blockIdx.x ? bbB : bbA;
    int* bc = blockIdx.x ? bcB : bcA;
    int t = threadIdx.x;
    int carry = 0;
    int nch = (B + 63) >> 6;
    for (int c = 0; c < nch; ++c) {
        int idx = c * 64 + t;
        int v = (idx < B) ? bh[idx] : 0;
        int incl = v;
        #pragma unroll
        for (int off = 1; off < 64; off <<= 1) {
            int tv = __shfl_up(incl, off);
            if (t >= off) incl += tv;
        }
        if (idx < B) { bb[idx] = incl - v + carry; bc[idx] = incl - v + carry; }
        carry += __shfl(incl, 63);
    }
    if (t == 0) bb[B] = carry;
}

// ------- coarse partition: stage in LDS, write packed words dense by bucket -------
__global__ void __launch_bounds__(256)
k_part(const int* __restrict__ src, const int* __restrict__ dst,
       int* __restrict__ bcur, unsigned int* __restrict__ out, int E) {
    __shared__ int lh[1024];
    __shared__ int loff[1024];
    __shared__ int gof[1024];
    __shared__ int lcur[1024];
    __shared__ unsigned int stage[CHUNK];   // 64 KB
    int t = threadIdx.x;
    int base = blockIdx.x * CHUNK;
    int cnt = min(CHUNK, E - base);
    for (int i = t; i < 1024; i += 256) lh[i] = 0;
    __syncthreads();
    for (int i = t; i < cnt; i += 256) atomicAdd(&lh[dst[base + i] >> 6], 1);
    __syncthreads();
    if (t < 64) {   // wave 0 scans 1024 entries in 16 chunks
        int carry = 0;
        #pragma unroll
        for (int c = 0; c < 16; ++c) {
            int idx = c * 64 + t;
            int v = lh[idx];
            int incl = v;
            #pragma unroll
            for (int off = 1; off < 64; off <<= 1) {
                int tv = __shfl_up(incl, off);
                if (t >= off) incl += tv;
            }
            loff[idx] = incl - v + carry;
            carry += __shfl(incl, 63);
        }
    }
    __syncthreads();
    for (int b = t; b < 1024; b += 256) {
        int c = lh[b];
        gof[b] = c ? atomicAdd(&bcur[b], c) : 0;
        lcur[b] = loff[b];
    }
    __syncthreads();
    for (int i = t; i < cnt; i += 256) {
        int d = dst[base + i];
        int s = src[base + i];
        int bkt = d >> 6;
        unsigned int dl = (unsigned int)(d & 63);
        int p = atomicAdd(&lcur[bkt], 1);
        stage[p] = (unsigned int)s | (dl << 16) | ((unsigned int)bkt << 22);
    }
    __syncthreads();
    for (int i = t; i < cnt; i += 256) {
        unsigned int e = stage[i];
        int bkt = (int)(e >> 22);
        out[gof[bkt] + (i - loff[bkt])] = e & 0x3FFFFFu;
    }
}

// ------- layer-1 aggregate: one block per bucket, LDS f32 atomics, fused epilogue ----
__global__ void __launch_bounds__(256)
k_agg_l1(const int* __restrict__ bbase, const unsigned int* __restrict__ ebuf,
         const float* __restrict__ dinv_src, const float* __restrict__ dinv_dst,
         const float4* __restrict__ hw4, const float* __restrict__ b1,
         float* __restrict__ R1, int col_off, int n) {
    __shared__ float acc[64 * 65];   // [feat][node+pad] — pad 65 breaks bank aliasing
    int t = threadIdx.x, b = blockIdx.x;
    for (int i = t; i < 64 * 65; i += 256) acc[i] = 0.f;
    __syncthreads();
    int beg = bbase[b], end = bbase[b + 1];
    int q = t & 3;    // 4 lanes per edge, 16 feats each
    for (int i = beg + (t >> 2); i < end; i += 64) {
        unsigned int e = ebuf[i];
        int s = (int)(e & 0xFFFFu);
        int dl = (int)((e >> 16) & 63u);
        float sc = dinv_src[s];
        const float4* hr = &hw4[s * 16 + q * 4];
        #pragma unroll
        for (int r = 0; r < 4; ++r) {
            float4 h = hr[r];
            int f = q * 16 + r * 4;
            atomicAdd(&acc[(f + 0) * 65 + dl], h.x * sc);
            atomicAdd(&acc[(f + 1) * 65 + dl], h.y * sc);
            atomicAdd(&acc[(f + 2) * 65 + dl], h.z * sc);
            atomicAdd(&acc[(f + 3) * 65 + dl], h.w * sc);
        }
    }
    __syncthreads();
    int v0 = b * NPB;
    for (int i = t; i < NPB * 64; i += 256) {
        int f = i & 63, dl = i >> 6;
        int v = v0 + dl;
        if (v < n) {
            float o = fmaf(acc[f * 65 + dl], dinv_dst[v], b1[f]);
            R1[v * 192 + col_off + f] = o > 0.f ? o : 0.f;
        }
    }
}

// ------- layer-1 self branch: R1[:,128:192] = relu(hw + b1) ----------------
__global__ void k_self64(const float* __restrict__ hw, const float* __restrict__ b1,
                         float* __restrict__ R1, int n) {
    int idx = blockIdx.x * 256 + threadIdx.x;
    if (idx >= n * 64) return;
    int v = idx >> 6, f = idx & 63;
    float c = hw[idx] + b1[f];
    R1[v * 192 + 128 + f] = c > 0.f ? c : 0.f;
}

// ---------------- GEMM2: hw2 = R1 @ w2  ([n,192]@[192,16]) ----------------
__global__ void k_gemm2(const float* __restrict__ R1, const float* __restrict__ w2,
                        float* __restrict__ hw2, int n) {
    __shared__ float ws[192 * 16];
    __shared__ float rs[16][193];
    int t = threadIdx.x;
    for (int i = t; i < 192 * 16; i += 256) ws[i] = w2[i];
    int row0 = blockIdx.x * 16;
    for (int i = t; i < 16 * 192; i += 256) {
        int r = i / 192, j = i - r * 192;
        int v = row0 + r;
        rs[r][j] = (v < n) ? R1[v * 192 + j] : 0.f;
    }
    __syncthreads();
    int r = t >> 4, c = t & 15;
    int v = row0 + r;
    if (v >= n) return;
    float acc = 0.f;
    #pragma unroll 8
    for (int j = 0; j < 192; ++j) acc += rs[r][j] * ws[j * 16 + c];
    hw2[v * 16 + c] = acc;
}

// ------- layer-2 aggregate: one block per bucket, raw sums -> acc2 ----------
__global__ void __launch_bounds__(256)
k_agg_l2(const int* __restrict__ bbase, const unsigned int* __restrict__ ebuf,
         const float* __restrict__ dinv_src, const float4* __restrict__ hw4,
         float* __restrict__ acc2, int n) {
    __shared__ float acc[16 * 65];
    int t = threadIdx.x, b = blockIdx.x;
    for (int i = t; i < 16 * 65; i += 256) acc[i] = 0.f;
    __syncthreads();
    int beg = bbase[b], end = bbase[b + 1];
    int q = t & 3;   // 4 lanes per edge, 4 feats each
    for (int i = beg + (t >> 2); i < end; i += 64) {
        unsigned int e = ebuf[i];
        int s = (int)(e & 0xFFFFu);
        int dl = (int)((e >> 16) & 63u);
        float sc = dinv_src[s];
        float4 h = hw4[s * 4 + q];
        int f = q * 4;
        atomicAdd(&acc[(f + 0) * 65 + dl], h.x * sc);
        atomicAdd(&acc[(f + 1) * 65 + dl], h.y * sc);
        atomicAdd(&acc[(f + 2) * 65 + dl], h.z * sc);
        atomicAdd(&acc[(f + 3) * 65 + dl], h.w * sc);
    }
    __syncthreads();
    int v0 = b * NPB;
    for (int i = t; i < NPB * 16; i += 256) {
        int f = i & 15, dl = i >> 4;
        int v = v0 + dl;
        if (v < n) acc2[v * 16 + f] = acc[f * 65 + dl];
    }
}

// ------- final: combine layer-2 branches, linear head, log_softmax ----------
__global__ void k_final(const float* __restrict__ hw2, const float* __restrict__ acc2a,
                        const float* __restrict__ acc2b, const float* __restrict__ dinv1,
                        const float* __restrict__ dinv2, const float* __restrict__ b2,
                        const float* __restrict__ lw, const float* __restrict__ lb,
                        float* __restrict__ out, int n) {
    __shared__ float lws[48 * 16];
    __shared__ float r2s[16][49];
    int t = threadIdx.x;
    for (int i = t; i < 48 * 16; i += 256) lws[i] = lw[i];
    int ni = t >> 4, c = t & 15;
    int v = blockIdx.x * 16 + ni;
    if (v < n) {
        float bb = b2[c];
        r2s[ni][c]      = fmaf(dinv1[v], acc2a[v * 16 + c], bb);
        r2s[ni][16 + c] = fmaf(dinv2[v], acc2b[v * 16 + c], bb);
        r2s[ni][32 + c] = hw2[v * 16 + c] + bb;
    }
    __syncthreads();
    if (v >= n) return;
    float o = lb[c];
    #pragma unroll
    for (int j = 0; j < 48; ++j) o += r2s[ni][j] * lws[j * 16 + c];
    float m = o;
    for (int off = 8; off >= 1; off >>= 1) m = fmaxf(m, __shfl_xor(m, off, 16));
    float e = expf(o - m);
    float ssum = e;
    for (int off = 8; off >= 1; off >>= 1) ssum += __shfl_xor(ssum, off, 16);
    out[v * 16 + c] = (o - m) - logf(ssum);
}

extern "C" void kernel_launch(void* const* d_in, const int* in_sizes, int n_in,
                              void* d_out, int out_size, void* d_ws, size_t ws_size,
                              hipStream_t stream) {
    const float* x     = (const float*)d_in[0];
    const float* w1    = (const float*)d_in[1];
    const float* b1    = (const float*)d_in[2];
    const float* w2    = (const float*)d_in[3];
    const float* b2    = (const float*)d_in[4];
    const float* lin_w = (const float*)d_in[5];
    const float* lin_b = (const float*)d_in[6];
    const int*   ei    = (const int*)d_in[7];
    const int*   ei2   = (const int*)d_in[8];

    const int n  = in_sizes[0] / 128;   // 50000
    const int E1 = in_sizes[7] / 2;     // 800000
    const int E2 = in_sizes[8] / 2;     // 3000000
    const int B  = (n + NPB - 1) / NPB; // 782

    char* ws = (char*)d_ws;
    float*        hw     = (float*)(ws + 0);            // [n,64] HW1; later hw2 [n,16]
    float*        R1     = (float*)(ws + 12800000);     // [n,192]
    unsigned int* ebuf1  = (unsigned int*)(ws + 51200000);  // [E1]
    unsigned int* ebuf2  = (unsigned int*)(ws + 54400000);  // [E2]
    float*        acc2a  = (float*)(ws + 66400000);     // [n,16]
    float*        acc2b  = (float*)(ws + 69600000);     // [n,16]
    int*          deg1   = (int*)  (ws + 72800000);     // [n]
    int*          deg2   = (int*)  (ws + 73000000);     // [n]
    float*        dinv1  = (float*)(ws + 73200000);     // [n]
    float*        dinv2  = (float*)(ws + 73400000);     // [n]
    int*          bhist1 = (int*)  (ws + 73600000);     // [1024]
    int*          bhist2 = (int*)  (ws + 73604096);     // [1024]
    int*          bbase1 = (int*)  (ws + 73608192);     // [B+1]
    int*          bbase2 = (int*)  (ws + 73612288);     // [B+1]
    int*          bcur1  = (int*)  (ws + 73616384);     // [B]
    int*          bcur2  = (int*)  (ws + 73620480);     // [B]

    hipMemsetAsync(deg1, 0, (size_t)n * 4, stream);
    hipMemsetAsync(deg2, 0, (size_t)n * 4, stream);
    hipMemsetAsync(bhist1, 0, 4096, stream);
    hipMemsetAsync(bhist2, 0, 4096, stream);

    k_gemm1<<<(n + 3) / 4, 256, 0, stream>>>(x, w1, hw, n);

    k_histdeg<<<(E1 + 4095) / 4096, 256, 0, stream>>>(ei + E1, deg1, bhist1, E1);
    k_histdeg<<<(E2 + 4095) / 4096, 256, 0, stream>>>(ei2 + E2, deg2, bhist2, E2);
    k_dinv<<<(n + 255) / 256, 256, 0, stream>>>(deg1, dinv1, deg2, dinv2, n);
    k_bscan<<<2, 64, 0, stream>>>(bhist1, bbase1, bcur1, bhist2, bbase2, bcur2, B);

    k_part<<<(E1 + CHUNK - 1) / CHUNK, 256, 0, stream>>>(ei, ei + E1, bcur1, ebuf1, E1);
    k_part<<<(E2 + CHUNK - 1) / CHUNK, 256, 0, stream>>>(ei2, ei2 + E2, bcur2, ebuf2, E2);

    k_agg_l1<<<B, 256, 0, stream>>>(bbase1, ebuf1, dinv1, dinv1, (const float4*)hw,
                                    b1, R1, 0, n);
    k_agg_l1<<<B, 256, 0, stream>>>(bbase2, ebuf2, dinv2, dinv2, (const float4*)hw,
                                    b1, R1, 64, n);
    k_self64<<<(n * 64 + 255) / 256, 256, 0, stream>>>(hw, b1, R1, n);

    k_gemm2<<<(n + 15) / 16, 256, 0, stream>>>(R1, w2, hw, n);  // hw := hw2 [n,16]

    k_agg_l2<<<B, 256, 0, stream>>>(bbase1, ebuf1, dinv1, (const float4*)hw, acc2a, n);
    k_agg_l2<<<B, 256, 0, stream>>>(bbase2, ebuf2, dinv2, (const float4*)hw, acc2b, n);

    k_final<<<(n + 15) / 16, 256, 0, stream>>>(hw, acc2a, acc2b, dinv1, dinv2, b2,
                                               lin_w, lin_b, (float*)d_out, n);
}

// Round 7
// 749.887 us; speedup vs baseline: 3.1901x; 3.1901x over previous
//
#include <hip/hip_runtime.h>
#include <math.h>

// x[50000,128] w1[128,64] b1[64] w2[192,16] b2[16] lin_w[48,16] lin_b[16]
// edge_index[2,800000] edge_index2[2,3000000] (int32, row0=src, row1=dst)
//
// R7: CSR build = R3-proven trio (k_degree/k_scan2/k_bucket, survived
// post-timing graph-replay validation). Aggregation = bf16 gather tables
// (hwb 6.4MB ~L2-resident) with register accumulation. No float atomics.

typedef unsigned short us8 __attribute__((ext_vector_type(8)));

__device__ inline float b2f(unsigned short u) {
    return __uint_as_float(((unsigned int)u) << 16);
}
// round-to-nearest-even f32 -> bf16 (finite values; matches __float2bfloat16)
__device__ inline unsigned short f2b(float f) {
    unsigned int u = __float_as_uint(f);
    u = (u + 0x7FFFu + ((u >> 16) & 1u)) >> 16;
    return (unsigned short)u;
}

// ---------------- GEMM1: hwb = bf16(x @ w1)  ([n,128]@[128,64]) ----------------
__global__ void __launch_bounds__(256)
k_gemm1(const float* __restrict__ x, const float* __restrict__ w1,
        unsigned short* __restrict__ hwb, int n) {
    __shared__ float ws[128 * 64];   // 32 KB
    __shared__ float xs[16 * 128];   // 8 KB
    int t = threadIdx.x;
    for (int i = t; i < 128 * 64; i += 256) ws[i] = w1[i];
    int row0 = blockIdx.x * 16;
    for (int i = t; i < 16 * 128; i += 256) {
        int r = row0 + (i >> 7);
        xs[i] = (r < n) ? x[r * 128 + (i & 127)] : 0.f;
    }
    __syncthreads();
    int c = t & 63, rg = t >> 6;    // 4 rows per thread
    float a0 = 0.f, a1 = 0.f, a2 = 0.f, a3 = 0.f;
    const float* x0 = &xs[(rg * 4 + 0) * 128];
    const float* x1 = &xs[(rg * 4 + 1) * 128];
    const float* x2 = &xs[(rg * 4 + 2) * 128];
    const float* x3 = &xs[(rg * 4 + 3) * 128];
    #pragma unroll 8
    for (int k = 0; k < 128; ++k) {
        float wv = ws[k * 64 + c];
        a0 = fmaf(x0[k], wv, a0);
        a1 = fmaf(x1[k], wv, a1);
        a2 = fmaf(x2[k], wv, a2);
        a3 = fmaf(x3[k], wv, a3);
    }
    int r = row0 + rg * 4;
    if (r + 0 < n) hwb[(r + 0) * 64 + c] = f2b(a0);
    if (r + 1 < n) hwb[(r + 1) * 64 + c] = f2b(a1);
    if (r + 2 < n) hwb[(r + 2) * 64 + c] = f2b(a2);
    if (r + 3 < n) hwb[(r + 3) * 64 + c] = f2b(a3);
}

// ---------------- degree histogram (int atomics) — R3 verbatim ----------------
__global__ void k_degree(const int* __restrict__ dst, int* __restrict__ deg, int E) {
    int i = blockIdx.x * 256 + threadIdx.x;
    if (i < E) atomicAdd(&deg[dst[i]], 1);
}

__global__ void k_dinv(const int* __restrict__ deg1, float* __restrict__ dinv1,
                       const int* __restrict__ deg2, float* __restrict__ dinv2, int n) {
    int i = blockIdx.x * 256 + threadIdx.x;
    if (i >= n) return;
    int d = deg1[i];
    dinv1[i] = (d > 0) ? rsqrtf((float)d) : 0.f;
    d = deg2[i];
    dinv2[i] = (d > 0) ? rsqrtf((float)d) : 0.f;
}

// ------- exclusive prefix scan of deg -> rowstart & cursor — R3 verbatim -------
__global__ void __launch_bounds__(1024)
k_scan2(const int* __restrict__ dA, int* __restrict__ rsA, int* __restrict__ curA,
        const int* __restrict__ dB, int* __restrict__ rsB, int* __restrict__ curB, int n) {
    const int* deg = blockIdx.x ? dB : dA;
    int* rs  = blockIdx.x ? rsB : rsA;
    int* cur = blockIdx.x ? curB : curA;
    __shared__ int wsum[16];
    __shared__ int woff[16];
    __shared__ int chunk_tot;
    __shared__ int carry_s;
    int t = threadIdx.x, lane = t & 63, wid = t >> 6;
    if (t == 0) carry_s = 0;
    __syncthreads();
    for (int base = 0; base < n; base += 1024) {
        int i = base + t;
        int v = (i < n) ? deg[i] : 0;
        int incl = v;
        #pragma unroll
        for (int off = 1; off < 64; off <<= 1) {
            int tv = __shfl_up(incl, off, 64);
            if (lane >= off) incl += tv;
        }
        if (lane == 63) wsum[wid] = incl;
        __syncthreads();
        if (t < 16) {
            int wv = wsum[t];
            int winc = wv;
            #pragma unroll
            for (int off = 1; off < 16; off <<= 1) {
                int tv = __shfl_up(winc, off, 16);
                if (t >= off) winc += tv;
            }
            woff[t] = winc - wv;
            if (t == 15) chunk_tot = winc;
        }
        __syncthreads();
        int excl = incl - v + woff[wid] + carry_s;
        if (i < n) { rs[i] = excl; cur[i] = excl; }
        __syncthreads();
        if (t == 0) carry_s += chunk_tot;
        __syncthreads();
    }
    if (t == 0) rs[n] = carry_s;
}

// ------- bucket: ssrc[pos] = src, pos = cursor[dst]++ — R3 verbatim -------
__global__ void k_bucket(const int* __restrict__ src, const int* __restrict__ dst,
                         int* __restrict__ cursor, int* __restrict__ ssrc, int E) {
    int i = blockIdx.x * 256 + threadIdx.x;
    if (i >= E) return;
    int d = dst[i];
    int pos = atomicAdd(&cursor[d], 1);
    ssrc[pos] = src[i];
}

// ------- layer-1 aggregate: 8 lanes/node, bf16 gather, fused epilogue -> R1b ----
__global__ void k_agg64b(const int* __restrict__ rs, const int* __restrict__ ssrc,
                         const float* __restrict__ dinv,
                         const us8* __restrict__ hwb8, const float* __restrict__ b1,
                         unsigned short* __restrict__ R1b, int col_unit, int n) {
    int tid = blockIdx.x * 256 + threadIdx.x;
    int v = tid >> 3, q = tid & 7;
    if (v >= n) return;
    int beg = rs[v], end = rs[v + 1];
    float a[8] = {0.f, 0.f, 0.f, 0.f, 0.f, 0.f, 0.f, 0.f};
    for (int i = beg; i < end; ++i) {
        int s = ssrc[i];
        float sc = dinv[s];
        us8 h = hwb8[s * 8 + q];
        #pragma unroll
        for (int j = 0; j < 8; ++j) a[j] = fmaf(b2f(h[j]), sc, a[j]);
    }
    float dd = dinv[v];
    us8 o;
    #pragma unroll
    for (int j = 0; j < 8; ++j) {
        float r = fmaf(a[j], dd, b1[q * 8 + j]);
        o[j] = f2b(r > 0.f ? r : 0.f);
    }
    ((us8*)&R1b[v * 192])[col_unit + q] = o;
}

// ------- layer-1 self branch: R1b[:,128:192] = bf16(relu(hw + b1)) ----------
__global__ void k_self64(const us8* __restrict__ hwb8, const float* __restrict__ b1,
                         unsigned short* __restrict__ R1b, int n) {
    int tid = blockIdx.x * 256 + threadIdx.x;
    int v = tid >> 3, q = tid & 7;
    if (v >= n) return;
    us8 h = hwb8[v * 8 + q];
    us8 o;
    #pragma unroll
    for (int j = 0; j < 8; ++j) {
        float r = b2f(h[j]) + b1[q * 8 + j];
        o[j] = f2b(r > 0.f ? r : 0.f);
    }
    ((us8*)&R1b[v * 192])[16 + q] = o;
}

// ---------------- GEMM2: hwb2 = bf16(R1 @ w2)  ([n,192]@[192,16]) ----------------
__global__ void __launch_bounds__(256)
k_gemm2(const unsigned short* __restrict__ R1b, const float* __restrict__ w2,
        unsigned short* __restrict__ hwb2, int n) {
    __shared__ float ws[192 * 16];
    __shared__ float rs[16][193];
    int t = threadIdx.x;
    for (int i = t; i < 192 * 16; i += 256) ws[i] = w2[i];
    int row0 = blockIdx.x * 16;
    for (int i = t; i < 16 * 192; i += 256) {
        int r = i / 192, j = i - r * 192;
        int v = row0 + r;
        rs[r][j] = (v < n) ? b2f(R1b[v * 192 + j]) : 0.f;
    }
    __syncthreads();
    int r = t >> 4, c = t & 15;
    int v = row0 + r;
    if (v >= n) return;
    float acc = 0.f;
    #pragma unroll 8
    for (int j = 0; j < 192; ++j) acc += rs[r][j] * ws[j * 16 + c];
    hwb2[v * 16 + c] = f2b(acc);
}

// ------- layer-2 aggregate: 2 lanes/node, bf16 gather, raw f32 sums ----------
__global__ void k_agg16(const int* __restrict__ rs, const int* __restrict__ ssrc,
                        const float* __restrict__ dinv,
                        const us8* __restrict__ hwb2_8, float* __restrict__ acc2, int n) {
    int tid = blockIdx.x * 256 + threadIdx.x;
    int v = tid >> 1, q = tid & 1;
    if (v >= n) return;
    int beg = rs[v], end = rs[v + 1];
    float a[8] = {0.f, 0.f, 0.f, 0.f, 0.f, 0.f, 0.f, 0.f};
    for (int i = beg; i < end; ++i) {
        int s = ssrc[i];
        float sc = dinv[s];
        us8 h = hwb2_8[s * 2 + q];
        #pragma unroll
        for (int j = 0; j < 8; ++j) a[j] = fmaf(b2f(h[j]), sc, a[j]);
    }
    float4* o = (float4*)&acc2[v * 16 + q * 8];
    o[0] = make_float4(a[0], a[1], a[2], a[3]);
    o[1] = make_float4(a[4], a[5], a[6], a[7]);
}

// ------- final: combine layer-2 branches, linear head, log_softmax ----------
__global__ void k_final(const unsigned short* __restrict__ hwb2,
                        const float* __restrict__ acc2a, const float* __restrict__ acc2b,
                        const float* __restrict__ dinv1, const float* __restrict__ dinv2,
                        const float* __restrict__ b2, const float* __restrict__ lw,
                        const float* __restrict__ lb, float* __restrict__ out, int n) {
    __shared__ float lws[48 * 16];
    __shared__ float r2s[16][49];
    int t = threadIdx.x;
    for (int i = t; i < 48 * 16; i += 256) lws[i] = lw[i];
    int ni = t >> 4, c = t & 15;
    int v = blockIdx.x * 16 + ni;
    if (v < n) {
        float bb = b2[c];
        r2s[ni][c]      = fmaf(dinv1[v], acc2a[v * 16 + c], bb);
        r2s[ni][16 + c] = fmaf(dinv2[v], acc2b[v * 16 + c], bb);
        r2s[ni][32 + c] = b2f(hwb2[v * 16 + c]) + bb;
    }
    __syncthreads();
    if (v >= n) return;
    float o = lb[c];
    #pragma unroll
    for (int j = 0; j < 48; ++j) o += r2s[ni][j] * lws[j * 16 + c];
    float m = o;
    for (int off = 8; off >= 1; off >>= 1) m = fmaxf(m, __shfl_xor(m, off, 16));
    float e = expf(o - m);
    float ssum = e;
    for (int off = 8; off >= 1; off >>= 1) ssum += __shfl_xor(ssum, off, 16);
    out[v * 16 + c] = (o - m) - logf(ssum);
}

extern "C" void kernel_launch(void* const* d_in, const int* in_sizes, int n_in,
                              void* d_out, int out_size, void* d_ws, size_t ws_size,
                              hipStream_t stream) {
    const float* x     = (const float*)d_in[0];
    const float* w1    = (const float*)d_in[1];
    const float* b1    = (const float*)d_in[2];
    const float* w2    = (const float*)d_in[3];
    const float* b2    = (const float*)d_in[4];
    const float* lin_w = (const float*)d_in[5];
    const float* lin_b = (const float*)d_in[6];
    const int*   ei    = (const int*)d_in[7];
    const int*   ei2   = (const int*)d_in[8];

    const int n  = in_sizes[0] / 128;   // 50000
    const int E1 = in_sizes[7] / 2;     // 800000
    const int E2 = in_sizes[8] / 2;     // 3000000

    char* ws = (char*)d_ws;
    unsigned short* hwb   = (unsigned short*)(ws + 0);         // [n,64] bf16
    unsigned short* hwb2  = (unsigned short*)(ws + 6400000);   // [n,16] bf16
    unsigned short* R1b   = (unsigned short*)(ws + 8000000);   // [n,192] bf16
    int*          ssrc1   = (int*)(ws + 27200000);             // [E1]
    int*          ssrc2   = (int*)(ws + 30400000);             // [E2] -> 42,400,000
    float*        acc2a   = (float*)(ws + 42400000);           // [n,16]
    float*        acc2b   = (float*)(ws + 45600000);           // [n,16] -> 48,800,000
    int*          deg1    = (int*)(ws + 48800000);             // [n]
    int*          deg2    = (int*)(ws + 49000000);             // [n]
    float*        dinv1   = (float*)(ws + 49200000);           // [n]
    float*        dinv2   = (float*)(ws + 49400000);           // [n]
    int*          rs1     = (int*)(ws + 49600000);             // [n+1]
    int*          rs2     = (int*)(ws + 49800016);             // [n+1]
    int*          cur1    = (int*)(ws + 50000032);             // [n]
    int*          cur2    = (int*)(ws + 50200032);             // [n]

    hipMemsetAsync(deg1, 0, (size_t)n * 4, stream);
    hipMemsetAsync(deg2, 0, (size_t)n * 4, stream);

    k_gemm1<<<(n + 15) / 16, 256, 0, stream>>>(x, w1, hwb, n);

    k_degree<<<(E1 + 255) / 256, 256, 0, stream>>>(ei + E1, deg1, E1);
    k_degree<<<(E2 + 255) / 256, 256, 0, stream>>>(ei2 + E2, deg2, E2);
    k_dinv<<<(n + 255) / 256, 256, 0, stream>>>(deg1, dinv1, deg2, dinv2, n);
    k_scan2<<<2, 1024, 0, stream>>>(deg1, rs1, cur1, deg2, rs2, cur2, n);
    k_bucket<<<(E1 + 255) / 256, 256, 0, stream>>>(ei, ei + E1, cur1, ssrc1, E1);
    k_bucket<<<(E2 + 255) / 256, 256, 0, stream>>>(ei2, ei2 + E2, cur2, ssrc2, E2);

    k_agg64b<<<(n * 8 + 255) / 256, 256, 0, stream>>>(rs1, ssrc1, dinv1,
                                                      (const us8*)hwb, b1, R1b, 0, n);
    k_agg64b<<<(n * 8 + 255) / 256, 256, 0, stream>>>(rs2, ssrc2, dinv2,
                                                      (const us8*)hwb, b1, R1b, 8, n);
    k_self64<<<(n * 8 + 255) / 256, 256, 0, stream>>>((const us8*)hwb, b1, R1b, n);

    k_gemm2<<<(n + 15) / 16, 256, 0, stream>>>(R1b, w2, hwb2, n);

    k_agg16<<<(n * 2 + 255) / 256, 256, 0, stream>>>(rs1, ssrc1, dinv1,
                                                     (const us8*)hwb2, acc2a, n);
    k_agg16<<<(n * 2 + 255) / 256, 256, 0, stream>>>(rs2, ssrc2, dinv2,
                                                     (const us8*)hwb2, acc2b, n);

    k_final<<<(n + 15) / 16, 256, 0, stream>>>(hwb2, acc2a, acc2b, dinv1, dinv2, b2,
                                               lin_w, lin_b, (float*)d_out, n);
}

// Round 8
// 586.030 us; speedup vs baseline: 4.0821x; 1.2796x over previous
//
#include <hip/hip_runtime.h>
#include <math.h>

// x[50000,128] w1[128,64] b1[64] w2[192,16] b2[16] lin_w[48,16] lin_b[16]
// edge_index[2,800000] edge_index2[2,3000000] (int32, row0=src, row1=dst)
//
// R8: build = R4-proven {k_histdeg,k_bscan,k_part} + minimal k_bucket2
// (LDS cursors seeded from proven global rowstarts; writes stay inside the
// bucket's contiguous window -> no write amplification). Aggregation =
// R7-proven bf16 gather with register accumulation; ssrc as ushort.

#define NPB   64
#define CHUNK 16384

typedef unsigned short us8 __attribute__((ext_vector_type(8)));

__device__ inline float b2f(unsigned short u) {
    return __uint_as_float(((unsigned int)u) << 16);
}
// round-to-nearest-even f32 -> bf16 (finite values; matches __float2bfloat16)
__device__ inline unsigned short f2b(float f) {
    unsigned int u = __float_as_uint(f);
    u = (u + 0x7FFFu + ((u >> 16) & 1u)) >> 16;
    return (unsigned short)u;
}

// ---------------- GEMM1: hwb = bf16(x @ w1)  ([n,128]@[128,64]) ----------------
__global__ void __launch_bounds__(256)
k_gemm1(const float* __restrict__ x, const float* __restrict__ w1,
        unsigned short* __restrict__ hwb, int n) {
    __shared__ float ws[128 * 64];   // 32 KB
    __shared__ float xs[16 * 128];   // 8 KB
    int t = threadIdx.x;
    for (int i = t; i < 128 * 64; i += 256) ws[i] = w1[i];
    int row0 = blockIdx.x * 16;
    for (int i = t; i < 16 * 128; i += 256) {
        int r = row0 + (i >> 7);
        xs[i] = (r < n) ? x[r * 128 + (i & 127)] : 0.f;
    }
    __syncthreads();
    int c = t & 63, rg = t >> 6;    // 4 rows per thread
    float a0 = 0.f, a1 = 0.f, a2 = 0.f, a3 = 0.f;
    const float* x0 = &xs[(rg * 4 + 0) * 128];
    const float* x1 = &xs[(rg * 4 + 1) * 128];
    const float* x2 = &xs[(rg * 4 + 2) * 128];
    const float* x3 = &xs[(rg * 4 + 3) * 128];
    #pragma unroll 8
    for (int k = 0; k < 128; ++k) {
        float wv = ws[k * 64 + c];
        a0 = fmaf(x0[k], wv, a0);
        a1 = fmaf(x1[k], wv, a1);
        a2 = fmaf(x2[k], wv, a2);
        a3 = fmaf(x3[k], wv, a3);
    }
    int r = row0 + rg * 4;
    if (r + 0 < n) hwb[(r + 0) * 64 + c] = f2b(a0);
    if (r + 1 < n) hwb[(r + 1) * 64 + c] = f2b(a1);
    if (r + 2 < n) hwb[(r + 2) * 64 + c] = f2b(a2);
    if (r + 3 < n) hwb[(r + 3) * 64 + c] = f2b(a3);
}

// ------- deg (global atomics) + bucket histogram (LDS-staged) — R4 verbatim -------
__global__ void k_histdeg(const int* __restrict__ dst, int* __restrict__ deg,
                          int* __restrict__ bhist, int E) {
    __shared__ int lh[1024];
    int t = threadIdx.x;
    for (int i = t; i < 1024; i += 256) lh[i] = 0;
    __syncthreads();
    int base = blockIdx.x * 4096;
    int cnt = min(4096, E - base);
    for (int i = t; i < cnt; i += 256) {
        int d = dst[base + i];
        atomicAdd(&deg[d], 1);
        atomicAdd(&lh[d >> 6], 1);
    }
    __syncthreads();
    for (int b = t; b < 1024; b += 256)
        if (lh[b]) atomicAdd(&bhist[b], lh[b]);
}

__global__ void k_dinv(const int* __restrict__ deg1, float* __restrict__ dinv1,
                       const int* __restrict__ deg2, float* __restrict__ dinv2, int n) {
    int i = blockIdx.x * 256 + threadIdx.x;
    if (i >= n) return;
    int d = deg1[i];
    dinv1[i] = (d > 0) ? rsqrtf((float)d) : 0.f;
    d = deg2[i];
    dinv2[i] = (d > 0) ? rsqrtf((float)d) : 0.f;
}

// ------- exclusive prefix scan of deg -> rowstart (+cur, unused) — R3 verbatim -------
__global__ void __launch_bounds__(1024)
k_scan2(const int* __restrict__ dA, int* __restrict__ rsA, int* __restrict__ curA,
        const int* __restrict__ dB, int* __restrict__ rsB, int* __restrict__ curB, int n) {
    const int* deg = blockIdx.x ? dB : dA;
    int* rs  = blockIdx.x ? rsB : rsA;
    int* cur = blockIdx.x ? curB : curA;
    __shared__ int wsum[16];
    __shared__ int woff[16];
    __shared__ int chunk_tot;
    __shared__ int carry_s;
    int t = threadIdx.x, lane = t & 63, wid = t >> 6;
    if (t == 0) carry_s = 0;
    __syncthreads();
    for (int base = 0; base < n; base += 1024) {
        int i = base + t;
        int v = (i < n) ? deg[i] : 0;
        int incl = v;
        #pragma unroll
        for (int off = 1; off < 64; off <<= 1) {
            int tv = __shfl_up(incl, off, 64);
            if (lane >= off) incl += tv;
        }
        if (lane == 63) wsum[wid] = incl;
        __syncthreads();
        if (t < 16) {
            int wv = wsum[t];
            int winc = wv;
            #pragma unroll
            for (int off = 1; off < 16; off <<= 1) {
                int tv = __shfl_up(winc, off, 16);
                if (t >= off) winc += tv;
            }
            woff[t] = winc - wv;
            if (t == 15) chunk_tot = winc;
        }
        __syncthreads();
        int excl = incl - v + woff[wid] + carry_s;
        if (i < n) { rs[i] = excl; cur[i] = excl; }
        __syncthreads();
        if (t == 0) carry_s += chunk_tot;
        __syncthreads();
    }
    if (t == 0) rs[n] = carry_s;
}

// ------- scan bucket histograms -> bbase (exclusive) and bcur — R4 verbatim -------
__global__ void k_bscan(const int* __restrict__ bhA, int* __restrict__ bbA, int* __restrict__ bcA,
                        const int* __restrict__ bhB, int* __restrict__ bbB, int* __restrict__ bcB,
                        int B) {
    const int* bh = blockIdx.x ? bhB : bhA;
    int* bb = blockIdx.x ? bbB : bbA;
    int* bc = blockIdx.x ? bcB : bcA;
    int t = threadIdx.x;
    int carry = 0;
    int nch = (B + 63) >> 6;
    for (int c = 0; c < nch; ++c) {
        int idx = c * 64 + t;
        int v = (idx < B) ? bh[idx] : 0;
        int incl = v;
        #pragma unroll
        for (int off = 1; off < 64; off <<= 1) {
            int tv = __shfl_up(incl, off);
            if (t >= off) incl += tv;
        }
        if (idx < B) { bb[idx] = incl - v + carry; bc[idx] = incl - v + carry; }
        carry += __shfl(incl, 63);
    }
    if (t == 0) bb[B] = carry;
}

// ------- coarse partition: LDS stage, dense packed writes by bucket — R4 verbatim ----
// packed word: src(16b) | dstlocal(6b)<<16 | bucket(10b)<<22 (stripped on write)
__global__ void __launch_bounds__(256)
k_part(const int* __restrict__ src, const int* __restrict__ dst,
       int* __restrict__ bcur, unsigned int* __restrict__ out, int E) {
    __shared__ int lh[1024];
    __shared__ int loff[1024];
    __shared__ int gof[1024];
    __shared__ int lcur[1024];
    __shared__ unsigned int stage[CHUNK];   // 64 KB
    int t = threadIdx.x;
    int base = blockIdx.x * CHUNK;
    int cnt = min(CHUNK, E - base);
    for (int i = t; i < 1024; i += 256) lh[i] = 0;
    __syncthreads();
    for (int i = t; i < cnt; i += 256) atomicAdd(&lh[dst[base + i] >> 6], 1);
    __syncthreads();
    if (t < 64) {
        int carry = 0;
        #pragma unroll
        for (int c = 0; c < 16; ++c) {
            int idx = c * 64 + t;
            int v = lh[idx];
            int incl = v;
            #pragma unroll
            for (int off = 1; off < 64; off <<= 1) {
                int tv = __shfl_up(incl, off);
                if (t >= off) incl += tv;
            }
            loff[idx] = incl - v + carry;
            carry += __shfl(incl, 63);
        }
    }
    __syncthreads();
    for (int b = t; b < 1024; b += 256) {
        int c = lh[b];
        gof[b] = c ? atomicAdd(&bcur[b], c) : 0;
        lcur[b] = loff[b];
    }
    __syncthreads();
    for (int i = t; i < cnt; i += 256) {
        int d = dst[base + i];
        int s = src[base + i];
        int bkt = d >> 6;
        int p = atomicAdd(&lcur[bkt], 1);
        stage[p] = (unsigned int)s | ((unsigned int)(d & 63) << 16) |
                   ((unsigned int)bkt << 22);
    }
    __syncthreads();
    for (int i = t; i < cnt; i += 256) {
        unsigned int e = stage[i];
        int bkt = (int)(e >> 22);
        out[gof[bkt] + (i - loff[bkt])] = e & 0x3FFFFFu;
    }
}

// ------- NEW k_bucket2: per-bucket scatter with LDS cursors from global rs -------
// Writes land in the bucket's contiguous window [rs[64b], rs[64b+64]) -> no amp.
// (rs[64b] == bbase[b]: both are prefix sums of the same degree counts.)
__global__ void __launch_bounds__(256)
k_bucket2(const int* __restrict__ bbase, const unsigned int* __restrict__ ebuf,
          const int* __restrict__ rs, unsigned short* __restrict__ ssrc, int n) {
    __shared__ int lcur[64];
    int t = threadIdx.x, b = blockIdx.x;
    if (t < 64) {
        int node = b * NPB + t;
        lcur[t] = (node < n) ? rs[node] : 0;
    }
    __syncthreads();
    int beg = bbase[b], end = bbase[b + 1];
    for (int i = beg + t; i < end; i += 256) {
        unsigned int e = ebuf[i];
        int p = atomicAdd(&lcur[(e >> 16) & 63u], 1);
        ssrc[p] = (unsigned short)(e & 0xFFFFu);
    }
}

// ------- layer-1 aggregate: 8 lanes/node, bf16 gather, fused epilogue -> R1b ----
__global__ void k_agg64b(const int* __restrict__ rs, const unsigned short* __restrict__ ssrc,
                         const float* __restrict__ dinv,
                         const us8* __restrict__ hwb8, const float* __restrict__ b1,
                         unsigned short* __restrict__ R1b, int col_unit, int n) {
    int tid = blockIdx.x * 256 + threadIdx.x;
    int v = tid >> 3, q = tid & 7;
    if (v >= n) return;
    int beg = rs[v], end = rs[v + 1];
    float a[8] = {0.f, 0.f, 0.f, 0.f, 0.f, 0.f, 0.f, 0.f};
    for (int i = beg; i < end; ++i) {
        int s = ssrc[i];
        float sc = dinv[s];
        us8 h = hwb8[s * 8 + q];
        #pragma unroll
        for (int j = 0; j < 8; ++j) a[j] = fmaf(b2f(h[j]), sc, a[j]);
    }
    float dd = dinv[v];
    us8 o;
    #pragma unroll
    for (int j = 0; j < 8; ++j) {
        float r = fmaf(a[j], dd, b1[q * 8 + j]);
        o[j] = f2b(r > 0.f ? r : 0.f);
    }
    ((us8*)&R1b[v * 192])[col_unit + q] = o;
}

// ------- layer-1 self branch: R1b[:,128:192] = bf16(relu(hw + b1)) ----------
__global__ void k_self64(const us8* __restrict__ hwb8, const float* __restrict__ b1,
                         unsigned short* __restrict__ R1b, int n) {
    int tid = blockIdx.x * 256 + threadIdx.x;
    int v = tid >> 3, q = tid & 7;
    if (v >= n) return;
    us8 h = hwb8[v * 8 + q];
    us8 o;
    #pragma unroll
    for (int j = 0; j < 8; ++j) {
        float r = b2f(h[j]) + b1[q * 8 + j];
        o[j] = f2b(r > 0.f ? r : 0.f);
    }
    ((us8*)&R1b[v * 192])[16 + q] = o;
}

// ---------------- GEMM2: hwb2 = bf16(R1 @ w2)  ([n,192]@[192,16]) ----------------
__global__ void __launch_bounds__(256)
k_gemm2(const unsigned short* __restrict__ R1b, const float* __restrict__ w2,
        unsigned short* __restrict__ hwb2, int n) {
    __shared__ float ws[192 * 16];
    __shared__ float rs[16][193];
    int t = threadIdx.x;
    for (int i = t; i < 192 * 16; i += 256) ws[i] = w2[i];
    int row0 = blockIdx.x * 16;
    for (int i = t; i < 16 * 192; i += 256) {
        int r = i / 192, j = i - r * 192;
        int v = row0 + r;
        rs[r][j] = (v < n) ? b2f(R1b[v * 192 + j]) : 0.f;
    }
    __syncthreads();
    int r = t >> 4, c = t & 15;
    int v = row0 + r;
    if (v >= n) return;
    float acc = 0.f;
    #pragma unroll 8
    for (int j = 0; j < 192; ++j) acc += rs[r][j] * ws[j * 16 + c];
    hwb2[v * 16 + c] = f2b(acc);
}

// ------- layer-2 aggregate: 2 lanes/node, bf16 gather, raw f32 sums ----------
__global__ void k_agg16(const int* __restrict__ rs, const unsigned short* __restrict__ ssrc,
                        const float* __restrict__ dinv,
                        const us8* __restrict__ hwb2_8, float* __restrict__ acc2, int n) {
    int tid = blockIdx.x * 256 + threadIdx.x;
    int v = tid >> 1, q = tid & 1;
    if (v >= n) return;
    int beg = rs[v], end = rs[v + 1];
    float a[8] = {0.f, 0.f, 0.f, 0.f, 0.f, 0.f, 0.f, 0.f};
    for (int i = beg; i < end; ++i) {
        int s = ssrc[i];
        float sc = dinv[s];
        us8 h = hwb2_8[s * 2 + q];
        #pragma unroll
        for (int j = 0; j < 8; ++j) a[j] = fmaf(b2f(h[j]), sc, a[j]);
    }
    float4* o = (float4*)&acc2[v * 16 + q * 8];
    o[0] = make_float4(a[0], a[1], a[2], a[3]);
    o[1] = make_float4(a[4], a[5], a[6], a[7]);
}

// ------- final: combine layer-2 branches, linear head, log_softmax ----------
__global__ void k_final(const unsigned short* __restrict__ hwb2,
                        const float* __restrict__ acc2a, const float* __restrict__ acc2b,
                        const float* __restrict__ dinv1, const float* __restrict__ dinv2,
                        const float* __restrict__ b2, const float* __restrict__ lw,
                        const float* __restrict__ lb, float* __restrict__ out, int n) {
    __shared__ float lws[48 * 16];
    __shared__ float r2s[16][49];
    int t = threadIdx.x;
    for (int i = t; i < 48 * 16; i += 256) lws[i] = lw[i];
    int ni = t >> 4, c = t & 15;
    int v = blockIdx.x * 16 + ni;
    if (v < n) {
        float bb = b2[c];
        r2s[ni][c]      = fmaf(dinv1[v], acc2a[v * 16 + c], bb);
        r2s[ni][16 + c] = fmaf(dinv2[v], acc2b[v * 16 + c], bb);
        r2s[ni][32 + c] = b2f(hwb2[v * 16 + c]) + bb;
    }
    __syncthreads();
    if (v >= n) return;
    float o = lb[c];
    #pragma unroll
    for (int j = 0; j < 48; ++j) o += r2s[ni][j] * lws[j * 16 + c];
    float m = o;
    for (int off = 8; off >= 1; off >>= 1) m = fmaxf(m, __shfl_xor(m, off, 16));
    float e = expf(o - m);
    float ssum = e;
    for (int off = 8; off >= 1; off >>= 1) ssum += __shfl_xor(ssum, off, 16);
    out[v * 16 + c] = (o - m) - logf(ssum);
}

extern "C" void kernel_launch(void* const* d_in, const int* in_sizes, int n_in,
                              void* d_out, int out_size, void* d_ws, size_t ws_size,
                              hipStream_t stream) {
    const float* x     = (const float*)d_in[0];
    const float* w1    = (const float*)d_in[1];
    const float* b1    = (const float*)d_in[2];
    const float* w2    = (const float*)d_in[3];
    const float* b2    = (const float*)d_in[4];
    const float* lin_w = (const float*)d_in[5];
    const float* lin_b = (const float*)d_in[6];
    const int*   ei    = (const int*)d_in[7];
    const int*   ei2   = (const int*)d_in[8];

    const int n  = in_sizes[0] / 128;   // 50000
    const int E1 = in_sizes[7] / 2;     // 800000
    const int E2 = in_sizes[8] / 2;     // 3000000
    const int B  = (n + NPB - 1) / NPB; // 782

    char* ws = (char*)d_ws;
    unsigned short* hwb   = (unsigned short*)(ws + 0);         // [n,64] bf16
    unsigned short* hwb2  = (unsigned short*)(ws + 6400000);   // [n,16] bf16
    unsigned short* R1b   = (unsigned short*)(ws + 8000000);   // [n,192] bf16
    unsigned short* ssrc1 = (unsigned short*)(ws + 27200000);  // [E1] ushort
    unsigned short* ssrc2 = (unsigned short*)(ws + 28800000);  // [E2] ushort -> 34.8M
    unsigned int* ebuf    = (unsigned int*)(ws + 34800000);    // [E2] shared -> 46.8M
    float*        acc2a   = (float*)(ws + 46800000);           // [n,16]
    float*        acc2b   = (float*)(ws + 50000000);           // [n,16] -> 53.2M
    int*          deg1    = (int*)(ws + 53200000);             // [n]
    int*          deg2    = (int*)(ws + 53400000);             // [n]
    float*        dinv1   = (float*)(ws + 53600000);           // [n]
    float*        dinv2   = (float*)(ws + 53800000);           // [n]
    int*          rs1     = (int*)(ws + 54000000);             // [n+1]
    int*          rs2     = (int*)(ws + 54200016);             // [n+1]
    int*          cur1    = (int*)(ws + 54400032);             // [n] (scan2 side-output)
    int*          cur2    = (int*)(ws + 54600032);             // [n]
    int*          bhist1  = (int*)(ws + 54800032);             // [1024]
    int*          bhist2  = (int*)(ws + 54804128);             // [1024]
    int*          bbase1  = (int*)(ws + 54808224);             // [B+1]
    int*          bbase2  = (int*)(ws + 54812320);             // [B+1]
    int*          bcur1   = (int*)(ws + 54816416);             // [B]
    int*          bcur2   = (int*)(ws + 54820512);             // [B]

    hipMemsetAsync(deg1, 0, (size_t)n * 4, stream);
    hipMemsetAsync(deg2, 0, (size_t)n * 4, stream);
    hipMemsetAsync(bhist1, 0, 4096, stream);
    hipMemsetAsync(bhist2, 0, 4096, stream);

    k_gemm1<<<(n + 15) / 16, 256, 0, stream>>>(x, w1, hwb, n);

    k_histdeg<<<(E1 + 4095) / 4096, 256, 0, stream>>>(ei + E1, deg1, bhist1, E1);
    k_histdeg<<<(E2 + 4095) / 4096, 256, 0, stream>>>(ei2 + E2, deg2, bhist2, E2);
    k_dinv<<<(n + 255) / 256, 256, 0, stream>>>(deg1, dinv1, deg2, dinv2, n);
    k_scan2<<<2, 1024, 0, stream>>>(deg1, rs1, cur1, deg2, rs2, cur2, n);
    k_bscan<<<2, 64, 0, stream>>>(bhist1, bbase1, bcur1, bhist2, bbase2, bcur2, B);

    // set 1: coarse partition into ebuf, then windowed scatter to ssrc1
    k_part<<<(E1 + CHUNK - 1) / CHUNK, 256, 0, stream>>>(ei, ei + E1, bcur1, ebuf, E1);
    k_bucket2<<<B, 256, 0, stream>>>(bbase1, ebuf, rs1, ssrc1, n);
    // set 2 (ebuf reused; stream-ordered)
    k_part<<<(E2 + CHUNK - 1) / CHUNK, 256, 0, stream>>>(ei2, ei2 + E2, bcur2, ebuf, E2);
    k_bucket2<<<B, 256, 0, stream>>>(bbase2, ebuf, rs2, ssrc2, n);

    k_agg64b<<<(n * 8 + 255) / 256, 256, 0, stream>>>(rs1, ssrc1, dinv1,
                                                      (const us8*)hwb, b1, R1b, 0, n);
    k_agg64b<<<(n * 8 + 255) / 256, 256, 0, stream>>>(rs2, ssrc2, dinv2,
                                                      (const us8*)hwb, b1, R1b, 8, n);
    k_self64<<<(n * 8 + 255) / 256, 256, 0, stream>>>((const us8*)hwb, b1, R1b, n);

    k_gemm2<<<(n + 15) / 16, 256, 0, stream>>>(R1b, w2, hwb2, n);

    k_agg16<<<(n * 2 + 255) / 256, 256, 0, stream>>>(rs1, ssrc1, dinv1,
                                                     (const us8*)hwb2, acc2a, n);
    k_agg16<<<(n * 2 + 255) / 256, 256, 0, stream>>>(rs2, ssrc2, dinv2,
                                                     (const us8*)hwb2, acc2b, n);

    k_final<<<(n + 15) / 16, 256, 0, stream>>>(hwb2, acc2a, acc2b, dinv1, dinv2, b2,
                                               lin_w, lin_b, (float*)d_out, n);
}

// Round 9
// 438.622 us; speedup vs baseline: 5.4540x; 1.3361x over previous
//
#include <hip/hip_runtime.h>
#include <math.h>

// x[50000,128] w1[128,64] b1[64] w2[192,16] b2[16] lin_w[48,16] lin_b[16]
// edge_index[2,800000] edge_index2[2,3000000] (int32, row0=src, row1=dst)
//
// R9 = R8 minus the last global-atomic scatter: degree is now derived from the
// partitioned ebuf (per-bucket LDS count -> dense writes) instead of 3.8M random
// global atomicAdds (which cost ~96MB of write-through amplification in R8).

#define NPB   64
#define CHUNK 16384

typedef unsigned short us8 __attribute__((ext_vector_type(8)));

__device__ inline float b2f(unsigned short u) {
    return __uint_as_float(((unsigned int)u) << 16);
}
// round-to-nearest-even f32 -> bf16 (finite values; matches __float2bfloat16)
__device__ inline unsigned short f2b(float f) {
    unsigned int u = __float_as_uint(f);
    u = (u + 0x7FFFu + ((u >> 16) & 1u)) >> 16;
    return (unsigned short)u;
}

// ---------------- GEMM1: hwb = bf16(x @ w1)  ([n,128]@[128,64]) ----------------
__global__ void __launch_bounds__(256)
k_gemm1(const float* __restrict__ x, const float* __restrict__ w1,
        unsigned short* __restrict__ hwb, int n) {
    __shared__ float ws[128 * 64];   // 32 KB
    __shared__ float xs[16 * 128];   // 8 KB
    int t = threadIdx.x;
    for (int i = t; i < 128 * 64; i += 256) ws[i] = w1[i];
    int row0 = blockIdx.x * 16;
    for (int i = t; i < 16 * 128; i += 256) {
        int r = row0 + (i >> 7);
        xs[i] = (r < n) ? x[r * 128 + (i & 127)] : 0.f;
    }
    __syncthreads();
    int c = t & 63, rg = t >> 6;    // 4 rows per thread
    float a0 = 0.f, a1 = 0.f, a2 = 0.f, a3 = 0.f;
    const float* x0 = &xs[(rg * 4 + 0) * 128];
    const float* x1 = &xs[(rg * 4 + 1) * 128];
    const float* x2 = &xs[(rg * 4 + 2) * 128];
    const float* x3 = &xs[(rg * 4 + 3) * 128];
    #pragma unroll 8
    for (int k = 0; k < 128; ++k) {
        float wv = ws[k * 64 + c];
        a0 = fmaf(x0[k], wv, a0);
        a1 = fmaf(x1[k], wv, a1);
        a2 = fmaf(x2[k], wv, a2);
        a3 = fmaf(x3[k], wv, a3);
    }
    int r = row0 + rg * 4;
    if (r + 0 < n) hwb[(r + 0) * 64 + c] = f2b(a0);
    if (r + 1 < n) hwb[(r + 1) * 64 + c] = f2b(a1);
    if (r + 2 < n) hwb[(r + 2) * 64 + c] = f2b(a2);
    if (r + 3 < n) hwb[(r + 3) * 64 + c] = f2b(a3);
}

// ------- bucket histogram only (LDS-staged; no per-node deg atomics) -------
__global__ void k_hist(const int* __restrict__ dst, int* __restrict__ bhist, int E) {
    __shared__ int lh[1024];
    int t = threadIdx.x;
    for (int i = t; i < 1024; i += 256) lh[i] = 0;
    __syncthreads();
    int base = blockIdx.x * 4096;
    int cnt = min(4096, E - base);
    for (int i = t; i < cnt; i += 256) atomicAdd(&lh[dst[base + i] >> 6], 1);
    __syncthreads();
    for (int b = t; b < 1024; b += 256)
        if (lh[b]) atomicAdd(&bhist[b], lh[b]);
}

// ------- scan bucket histograms -> bbase (exclusive) and bcur — R4 verbatim -------
__global__ void k_bscan(const int* __restrict__ bhA, int* __restrict__ bbA, int* __restrict__ bcA,
                        const int* __restrict__ bhB, int* __restrict__ bbB, int* __restrict__ bcB,
                        int B) {
    const int* bh = blockIdx.x ? bhB : bhA;
    int* bb = blockIdx.x ? bbB : bbA;
    int* bc = blockIdx.x ? bcB : bcA;
    int t = threadIdx.x;
    int carry = 0;
    int nch = (B + 63) >> 6;
    for (int c = 0; c < nch; ++c) {
        int idx = c * 64 + t;
        int v = (idx < B) ? bh[idx] : 0;
        int incl = v;
        #pragma unroll
        for (int off = 1; off < 64; off <<= 1) {
            int tv = __shfl_up(incl, off);
            if (t >= off) incl += tv;
        }
        if (idx < B) { bb[idx] = incl - v + carry; bc[idx] = incl - v + carry; }
        carry += __shfl(incl, 63);
    }
    if (t == 0) bb[B] = carry;
}

// ------- coarse partition: LDS stage, dense packed writes by bucket — R4 verbatim ----
// packed word: src(16b) | dstlocal(6b)<<16 | bucket(10b)<<22 (stripped on write)
__global__ void __launch_bounds__(256)
k_part(const int* __restrict__ src, const int* __restrict__ dst,
       int* __restrict__ bcur, unsigned int* __restrict__ out, int E) {
    __shared__ int lh[1024];
    __shared__ int loff[1024];
    __shared__ int gof[1024];
    __shared__ int lcur[1024];
    __shared__ unsigned int stage[CHUNK];   // 64 KB
    int t = threadIdx.x;
    int base = blockIdx.x * CHUNK;
    int cnt = min(CHUNK, E - base);
    for (int i = t; i < 1024; i += 256) lh[i] = 0;
    __syncthreads();
    for (int i = t; i < cnt; i += 256) atomicAdd(&lh[dst[base + i] >> 6], 1);
    __syncthreads();
    if (t < 64) {
        int carry = 0;
        #pragma unroll
        for (int c = 0; c < 16; ++c) {
            int idx = c * 64 + t;
            int v = lh[idx];
            int incl = v;
            #pragma unroll
            for (int off = 1; off < 64; off <<= 1) {
                int tv = __shfl_up(incl, off);
                if (t >= off) incl += tv;
            }
            loff[idx] = incl - v + carry;
            carry += __shfl(incl, 63);
        }
    }
    __syncthreads();
    for (int b = t; b < 1024; b += 256) {
        int c = lh[b];
        gof[b] = c ? atomicAdd(&bcur[b], c) : 0;
        lcur[b] = loff[b];
    }
    __syncthreads();
    for (int i = t; i < cnt; i += 256) {
        int d = dst[base + i];
        int s = src[base + i];
        int bkt = d >> 6;
        int p = atomicAdd(&lcur[bkt], 1);
        stage[p] = (unsigned int)s | ((unsigned int)(d & 63) << 16) |
                   ((unsigned int)bkt << 22);
    }
    __syncthreads();
    for (int i = t; i < cnt; i += 256) {
        unsigned int e = stage[i];
        int bkt = (int)(e >> 22);
        out[gof[bkt] + (i - loff[bkt])] = e & 0x3FFFFFu;
    }
}

// ------- NEW k_degbkt: per-bucket degree count from ebuf -> dense deg writes -------
__global__ void __launch_bounds__(256)
k_degbkt(const int* __restrict__ bbase, const unsigned int* __restrict__ ebuf,
         int* __restrict__ deg, int n) {
    __shared__ int cnt[64];
    int t = threadIdx.x, b = blockIdx.x;
    if (t < 64) cnt[t] = 0;
    __syncthreads();
    int beg = bbase[b], end = bbase[b + 1];
    for (int i = beg + t; i < end; i += 256)
        atomicAdd(&cnt[(ebuf[i] >> 16) & 63u], 1);
    __syncthreads();
    if (t < 64) {
        int node = b * NPB + t;
        if (node < n) deg[node] = cnt[t];
    }
}

__global__ void k_dinv(const int* __restrict__ deg1, float* __restrict__ dinv1,
                       const int* __restrict__ deg2, float* __restrict__ dinv2, int n) {
    int i = blockIdx.x * 256 + threadIdx.x;
    if (i >= n) return;
    int d = deg1[i];
    dinv1[i] = (d > 0) ? rsqrtf((float)d) : 0.f;
    d = deg2[i];
    dinv2[i] = (d > 0) ? rsqrtf((float)d) : 0.f;
}

// ------- exclusive prefix scan of deg -> rowstart (+cur, unused) — R3 verbatim -------
__global__ void __launch_bounds__(1024)
k_scan2(const int* __restrict__ dA, int* __restrict__ rsA, int* __restrict__ curA,
        const int* __restrict__ dB, int* __restrict__ rsB, int* __restrict__ curB, int n) {
    const int* deg = blockIdx.x ? dB : dA;
    int* rs  = blockIdx.x ? rsB : rsA;
    int* cur = blockIdx.x ? curB : curA;
    __shared__ int wsum[16];
    __shared__ int woff[16];
    __shared__ int chunk_tot;
    __shared__ int carry_s;
    int t = threadIdx.x, lane = t & 63, wid = t >> 6;
    if (t == 0) carry_s = 0;
    __syncthreads();
    for (int base = 0; base < n; base += 1024) {
        int i = base + t;
        int v = (i < n) ? deg[i] : 0;
        int incl = v;
        #pragma unroll
        for (int off = 1; off < 64; off <<= 1) {
            int tv = __shfl_up(incl, off, 64);
            if (lane >= off) incl += tv;
        }
        if (lane == 63) wsum[wid] = incl;
        __syncthreads();
        if (t < 16) {
            int wv = wsum[t];
            int winc = wv;
            #pragma unroll
            for (int off = 1; off < 16; off <<= 1) {
                int tv = __shfl_up(winc, off, 16);
                if (t >= off) winc += tv;
            }
            woff[t] = winc - wv;
            if (t == 15) chunk_tot = winc;
        }
        __syncthreads();
        int excl = incl - v + woff[wid] + carry_s;
        if (i < n) { rs[i] = excl; cur[i] = excl; }
        __syncthreads();
        if (t == 0) carry_s += chunk_tot;
        __syncthreads();
    }
    if (t == 0) rs[n] = carry_s;
}

// ------- k_bucket2: per-bucket scatter with LDS cursors from global rs (R8-proven) ---
__global__ void __launch_bounds__(256)
k_bucket2(const int* __restrict__ bbase, const unsigned int* __restrict__ ebuf,
          const int* __restrict__ rs, unsigned short* __restrict__ ssrc, int n) {
    __shared__ int lcur[64];
    int t = threadIdx.x, b = blockIdx.x;
    if (t < 64) {
        int node = b * NPB + t;
        lcur[t] = (node < n) ? rs[node] : 0;
    }
    __syncthreads();
    int beg = bbase[b], end = bbase[b + 1];
    for (int i = beg + t; i < end; i += 256) {
        unsigned int e = ebuf[i];
        int p = atomicAdd(&lcur[(e >> 16) & 63u], 1);
        ssrc[p] = (unsigned short)(e & 0xFFFFu);
    }
}

// ------- layer-1 aggregate: 8 lanes/node, bf16 gather, fused epilogue -> R1b ----
__global__ void k_agg64b(const int* __restrict__ rs, const unsigned short* __restrict__ ssrc,
                         const float* __restrict__ dinv,
                         const us8* __restrict__ hwb8, const float* __restrict__ b1,
                         unsigned short* __restrict__ R1b, int col_unit, int n) {
    int tid = blockIdx.x * 256 + threadIdx.x;
    int v = tid >> 3, q = tid & 7;
    if (v >= n) return;
    int beg = rs[v], end = rs[v + 1];
    float a[8] = {0.f, 0.f, 0.f, 0.f, 0.f, 0.f, 0.f, 0.f};
    for (int i = beg; i < end; ++i) {
        int s = ssrc[i];
        float sc = dinv[s];
        us8 h = hwb8[s * 8 + q];
        #pragma unroll
        for (int j = 0; j < 8; ++j) a[j] = fmaf(b2f(h[j]), sc, a[j]);
    }
    float dd = dinv[v];
    us8 o;
    #pragma unroll
    for (int j = 0; j < 8; ++j) {
        float r = fmaf(a[j], dd, b1[q * 8 + j]);
        o[j] = f2b(r > 0.f ? r : 0.f);
    }
    ((us8*)&R1b[v * 192])[col_unit + q] = o;
}

// ------- layer-1 self branch: R1b[:,128:192] = bf16(relu(hw + b1)) ----------
__global__ void k_self64(const us8* __restrict__ hwb8, const float* __restrict__ b1,
                         unsigned short* __restrict__ R1b, int n) {
    int tid = blockIdx.x * 256 + threadIdx.x;
    int v = tid >> 3, q = tid & 7;
    if (v >= n) return;
    us8 h = hwb8[v * 8 + q];
    us8 o;
    #pragma unroll
    for (int j = 0; j < 8; ++j) {
        float r = b2f(h[j]) + b1[q * 8 + j];
        o[j] = f2b(r > 0.f ? r : 0.f);
    }
    ((us8*)&R1b[v * 192])[16 + q] = o;
}

// ---------------- GEMM2: hwb2 = bf16(R1 @ w2)  ([n,192]@[192,16]) ----------------
__global__ void __launch_bounds__(256)
k_gemm2(const unsigned short* __restrict__ R1b, const float* __restrict__ w2,
        unsigned short* __restrict__ hwb2, int n) {
    __shared__ float ws[192 * 16];
    __shared__ float rs[16][193];
    int t = threadIdx.x;
    for (int i = t; i < 192 * 16; i += 256) ws[i] = w2[i];
    int row0 = blockIdx.x * 16;
    for (int i = t; i < 16 * 192; i += 256) {
        int r = i / 192, j = i - r * 192;
        int v = row0 + r;
        rs[r][j] = (v < n) ? b2f(R1b[v * 192 + j]) : 0.f;
    }
    __syncthreads();
    int r = t >> 4, c = t & 15;
    int v = row0 + r;
    if (v >= n) return;
    float acc = 0.f;
    #pragma unroll 8
    for (int j = 0; j < 192; ++j) acc += rs[r][j] * ws[j * 16 + c];
    hwb2[v * 16 + c] = f2b(acc);
}

// ------- layer-2 aggregate: 2 lanes/node, bf16 gather, raw f32 sums ----------
__global__ void k_agg16(const int* __restrict__ rs, const unsigned short* __restrict__ ssrc,
                        const float* __restrict__ dinv,
                        const us8* __restrict__ hwb2_8, float* __restrict__ acc2, int n) {
    int tid = blockIdx.x * 256 + threadIdx.x;
    int v = tid >> 1, q = tid & 1;
    if (v >= n) return;
    int beg = rs[v], end = rs[v + 1];
    float a[8] = {0.f, 0.f, 0.f, 0.f, 0.f, 0.f, 0.f, 0.f};
    for (int i = beg; i < end; ++i) {
        int s = ssrc[i];
        float sc = dinv[s];
        us8 h = hwb2_8[s * 2 + q];
        #pragma unroll
        for (int j = 0; j < 8; ++j) a[j] = fmaf(b2f(h[j]), sc, a[j]);
    }
    float4* o = (float4*)&acc2[v * 16 + q * 8];
    o[0] = make_float4(a[0], a[1], a[2], a[3]);
    o[1] = make_float4(a[4], a[5], a[6], a[7]);
}

// ------- final: combine layer-2 branches, linear head, log_softmax ----------
__global__ void k_final(const unsigned short* __restrict__ hwb2,
                        const float* __restrict__ acc2a, const float* __restrict__ acc2b,
                        const float* __restrict__ dinv1, const float* __restrict__ dinv2,
                        const float* __restrict__ b2, const float* __restrict__ lw,
                        const float* __restrict__ lb, float* __restrict__ out, int n) {
    __shared__ float lws[48 * 16];
    __shared__ float r2s[16][49];
    int t = threadIdx.x;
    for (int i = t; i < 48 * 16; i += 256) lws[i] = lw[i];
    int ni = t >> 4, c = t & 15;
    int v = blockIdx.x * 16 + ni;
    if (v < n) {
        float bb = b2[c];
        r2s[ni][c]      = fmaf(dinv1[v], acc2a[v * 16 + c], bb);
        r2s[ni][16 + c] = fmaf(dinv2[v], acc2b[v * 16 + c], bb);
        r2s[ni][32 + c] = b2f(hwb2[v * 16 + c]) + bb;
    }
    __syncthreads();
    if (v >= n) return;
    float o = lb[c];
    #pragma unroll
    for (int j = 0; j < 48; ++j) o += r2s[ni][j] * lws[j * 16 + c];
    float m = o;
    for (int off = 8; off >= 1; off >>= 1) m = fmaxf(m, __shfl_xor(m, off, 16));
    float e = expf(o - m);
    float ssum = e;
    for (int off = 8; off >= 1; off >>= 1) ssum += __shfl_xor(ssum, off, 16);
    out[v * 16 + c] = (o - m) - logf(ssum);
}

extern "C" void kernel_launch(void* const* d_in, const int* in_sizes, int n_in,
                              void* d_out, int out_size, void* d_ws, size_t ws_size,
                              hipStream_t stream) {
    const float* x     = (const float*)d_in[0];
    const float* w1    = (const float*)d_in[1];
    const float* b1    = (const float*)d_in[2];
    const float* w2    = (const float*)d_in[3];
    const float* b2    = (const float*)d_in[4];
    const float* lin_w = (const float*)d_in[5];
    const float* lin_b = (const float*)d_in[6];
    const int*   ei    = (const int*)d_in[7];
    const int*   ei2   = (const int*)d_in[8];

    const int n  = in_sizes[0] / 128;   // 50000
    const int E1 = in_sizes[7] / 2;     // 800000
    const int E2 = in_sizes[8] / 2;     // 3000000
    const int B  = (n + NPB - 1) / NPB; // 782

    char* ws = (char*)d_ws;
    unsigned short* hwb   = (unsigned short*)(ws + 0);         // [n,64] bf16 -> 6.4M
    unsigned short* hwb2  = (unsigned short*)(ws + 6400000);   // [n,16] bf16 -> 8.0M
    unsigned short* R1b   = (unsigned short*)(ws + 8000000);   // [n,192] bf16 -> 27.2M
    unsigned short* ssrc1 = (unsigned short*)(ws + 27200000);  // [E1] -> 28.8M
    unsigned short* ssrc2 = (unsigned short*)(ws + 28800000);  // [E2] -> 34.8M
    unsigned int* ebuf1   = (unsigned int*)(ws + 34800000);    // [E1] -> 38.0M
    unsigned int* ebuf2   = (unsigned int*)(ws + 38000000);    // [E2] -> 50.0M
    float*        acc2a   = (float*)(ws + 50000000);           // [n,16] -> 53.2M
    float*        acc2b   = (float*)(ws + 53200000);           // [n,16] -> 56.4M
    int*          deg1    = (int*)(ws + 56400000);             // [n]
    int*          deg2    = (int*)(ws + 56600000);             // [n]
    float*        dinv1   = (float*)(ws + 56800000);           // [n]
    float*        dinv2   = (float*)(ws + 57000000);           // [n]
    int*          rs1     = (int*)(ws + 57200000);             // [n+1]
    int*          rs2     = (int*)(ws + 57400016);             // [n+1]
    int*          cur1    = (int*)(ws + 57600032);             // [n] (scan2 side-output)
    int*          cur2    = (int*)(ws + 57800032);             // [n]
    int*          bhist1  = (int*)(ws + 58000032);             // [1024]
    int*          bhist2  = (int*)(ws + 58004128);             // [1024]
    int*          bbase1  = (int*)(ws + 58008224);             // [B+1]
    int*          bbase2  = (int*)(ws + 58012320);             // [B+1]
    int*          bcur1   = (int*)(ws + 58016416);             // [B]
    int*          bcur2   = (int*)(ws + 58020512);             // [B]

    hipMemsetAsync(bhist1, 0, 4096, stream);
    hipMemsetAsync(bhist2, 0, 4096, stream);

    k_gemm1<<<(n + 15) / 16, 256, 0, stream>>>(x, w1, hwb, n);

    k_hist<<<(E1 + 4095) / 4096, 256, 0, stream>>>(ei + E1, bhist1, E1);
    k_hist<<<(E2 + 4095) / 4096, 256, 0, stream>>>(ei2 + E2, bhist2, E2);
    k_bscan<<<2, 64, 0, stream>>>(bhist1, bbase1, bcur1, bhist2, bbase2, bcur2, B);

    k_part<<<(E1 + CHUNK - 1) / CHUNK, 256, 0, stream>>>(ei, ei + E1, bcur1, ebuf1, E1);
    k_part<<<(E2 + CHUNK - 1) / CHUNK, 256, 0, stream>>>(ei2, ei2 + E2, bcur2, ebuf2, E2);

    k_degbkt<<<B, 256, 0, stream>>>(bbase1, ebuf1, deg1, n);
    k_degbkt<<<B, 256, 0, stream>>>(bbase2, ebuf2, deg2, n);
    k_dinv<<<(n + 255) / 256, 256, 0, stream>>>(deg1, dinv1, deg2, dinv2, n);
    k_scan2<<<2, 1024, 0, stream>>>(deg1, rs1, cur1, deg2, rs2, cur2, n);

    k_bucket2<<<B, 256, 0, stream>>>(bbase1, ebuf1, rs1, ssrc1, n);
    k_bucket2<<<B, 256, 0, stream>>>(bbase2, ebuf2, rs2, ssrc2, n);

    k_agg64b<<<(n * 8 + 255) / 256, 256, 0, stream>>>(rs1, ssrc1, dinv1,
                                                      (const us8*)hwb, b1, R1b, 0, n);
    k_agg64b<<<(n * 8 + 255) / 256, 256, 0, stream>>>(rs2, ssrc2, dinv2,
                                                      (const us8*)hwb, b1, R1b, 8, n);
    k_self64<<<(n * 8 + 255) / 256, 256, 0, stream>>>((const us8*)hwb, b1, R1b, n);

    k_gemm2<<<(n + 15) / 16, 256, 0, stream>>>(R1b, w2, hwb2, n);

    k_agg16<<<(n * 2 + 255) / 256, 256, 0, stream>>>(rs1, ssrc1, dinv1,
                                                     (const us8*)hwb2, acc2a, n);
    k_agg16<<<(n * 2 + 255) / 256, 256, 0, stream>>>(rs2, ssrc2, dinv2,
                                                     (const us8*)hwb2, acc2b, n);

    k_final<<<(n + 15) / 16, 256, 0, stream>>>(hwb2, acc2a, acc2b, dinv1, dinv2, b2,
                                               lin_w, lin_b, (float*)d_out, n);
}

// Round 10
// 334.426 us; speedup vs baseline: 7.1533x; 1.3116x over previous
//
#include <hip/hip_runtime.h>
#include <math.h>

// x[50000,128] w1[128,64] b1[64] w2[192,16] b2[16] lin_w[48,16] lin_b[16]
// edge_index[2,800000] edge_index2[2,3000000] (int32, row0=src, row1=dst)
//
// R10 = R9 algorithm with (a) x4-unrolled gather loops (4 independent load
// chains -> MLP; agg kernels were latency-bound: VALUBusy 18%, occ 51%) and
// (b) dispatch fusion: 18 -> 11 kernels (hist/part/degbkt/bucket2/agg pairs
// fused via blockIdx ranges; dinv folded into scan2; E2 blocks first).

#define NPB   64
#define CHUNK 16384

typedef unsigned short us8 __attribute__((ext_vector_type(8)));

__device__ inline float b2f(unsigned short u) {
    return __uint_as_float(((unsigned int)u) << 16);
}
// round-to-nearest-even f32 -> bf16 (finite values; matches __float2bfloat16)
__device__ inline unsigned short f2b(float f) {
    unsigned int u = __float_as_uint(f);
    u = (u + 0x7FFFu + ((u >> 16) & 1u)) >> 16;
    return (unsigned short)u;
}

// ---------------- GEMM1: hwb = bf16(x @ w1)  ([n,128]@[128,64]) ----------------
__global__ void __launch_bounds__(256)
k_gemm1(const float* __restrict__ x, const float* __restrict__ w1,
        unsigned short* __restrict__ hwb, int n) {
    __shared__ float ws[128 * 64];   // 32 KB
    __shared__ float xs[16 * 128];   // 8 KB
    int t = threadIdx.x;
    for (int i = t; i < 128 * 64; i += 256) ws[i] = w1[i];
    int row0 = blockIdx.x * 16;
    for (int i = t; i < 16 * 128; i += 256) {
        int r = row0 + (i >> 7);
        xs[i] = (r < n) ? x[r * 128 + (i & 127)] : 0.f;
    }
    __syncthreads();
    int c = t & 63, rg = t >> 6;    // 4 rows per thread
    float a0 = 0.f, a1 = 0.f, a2 = 0.f, a3 = 0.f;
    const float* x0 = &xs[(rg * 4 + 0) * 128];
    const float* x1 = &xs[(rg * 4 + 1) * 128];
    const float* x2 = &xs[(rg * 4 + 2) * 128];
    const float* x3 = &xs[(rg * 4 + 3) * 128];
    #pragma unroll 8
    for (int k = 0; k < 128; ++k) {
        float wv = ws[k * 64 + c];
        a0 = fmaf(x0[k], wv, a0);
        a1 = fmaf(x1[k], wv, a1);
        a2 = fmaf(x2[k], wv, a2);
        a3 = fmaf(x3[k], wv, a3);
    }
    int r = row0 + rg * 4;
    if (r + 0 < n) hwb[(r + 0) * 64 + c] = f2b(a0);
    if (r + 1 < n) hwb[(r + 1) * 64 + c] = f2b(a1);
    if (r + 2 < n) hwb[(r + 2) * 64 + c] = f2b(a2);
    if (r + 3 < n) hwb[(r + 3) * 64 + c] = f2b(a3);
}

// ------- fused bucket histogram, both edge sets (blockIdx split) -------
__global__ void k_hist2(const int* __restrict__ dstA, int* __restrict__ bhA, int EA, int nbA,
                        const int* __restrict__ dstB, int* __restrict__ bhB, int EB) {
    __shared__ int lh[1024];
    const int* dst; int* bh; int E; int cb;
    if ((int)blockIdx.x < nbA) { dst = dstA; bh = bhA; E = EA; cb = blockIdx.x; }
    else                       { dst = dstB; bh = bhB; E = EB; cb = blockIdx.x - nbA; }
    int t = threadIdx.x;
    for (int i = t; i < 1024; i += 256) lh[i] = 0;
    __syncthreads();
    int base = cb * 4096;
    int cnt = min(4096, E - base);
    for (int i = t; i < cnt; i += 256) atomicAdd(&lh[dst[base + i] >> 6], 1);
    __syncthreads();
    for (int b = t; b < 1024; b += 256)
        if (lh[b]) atomicAdd(&bh[b], lh[b]);
}

// ------- scan bucket histograms -> bbase (exclusive) and bcur — R4 verbatim -------
__global__ void k_bscan(const int* __restrict__ bhA, int* __restrict__ bbA, int* __restrict__ bcA,
                        const int* __restrict__ bhB, int* __restrict__ bbB, int* __restrict__ bcB,
                        int B) {
    const int* bh = blockIdx.x ? bhB : bhA;
    int* bb = blockIdx.x ? bbB : bbA;
    int* bc = blockIdx.x ? bcB : bcA;
    int t = threadIdx.x;
    int carry = 0;
    int nch = (B + 63) >> 6;
    for (int c = 0; c < nch; ++c) {
        int idx = c * 64 + t;
        int v = (idx < B) ? bh[idx] : 0;
        int incl = v;
        #pragma unroll
        for (int off = 1; off < 64; off <<= 1) {
            int tv = __shfl_up(incl, off);
            if (t >= off) incl += tv;
        }
        if (idx < B) { bb[idx] = incl - v + carry; bc[idx] = incl - v + carry; }
        carry += __shfl(incl, 63);
    }
    if (t == 0) bb[B] = carry;
}

// ------- fused coarse partition, both edge sets (blockIdx split) -------
// packed word: src(16b) | dstlocal(6b)<<16 | bucket(10b)<<22 (stripped on write)
__global__ void __launch_bounds__(256)
k_part2(const int* __restrict__ srcA, const int* __restrict__ dstA,
        int* __restrict__ bcurA, unsigned int* __restrict__ outA, int EA, int nbA,
        const int* __restrict__ srcB, const int* __restrict__ dstB,
        int* __restrict__ bcurB, unsigned int* __restrict__ outB, int EB) {
    __shared__ int lh[1024];
    __shared__ int loff[1024];
    __shared__ int gof[1024];
    __shared__ int lcur[1024];
    __shared__ unsigned int stage[CHUNK];   // 64 KB
    const int *src, *dst; int *bcur; unsigned int *out; int E, cb;
    if ((int)blockIdx.x < nbA) { src = srcA; dst = dstA; bcur = bcurA; out = outA; E = EA; cb = blockIdx.x; }
    else                       { src = srcB; dst = dstB; bcur = bcurB; out = outB; E = EB; cb = blockIdx.x - nbA; }
    int t = threadIdx.x;
    int base = cb * CHUNK;
    int cnt = min(CHUNK, E - base);
    for (int i = t; i < 1024; i += 256) lh[i] = 0;
    __syncthreads();
    for (int i = t; i < cnt; i += 256) atomicAdd(&lh[dst[base + i] >> 6], 1);
    __syncthreads();
    if (t < 64) {
        int carry = 0;
        #pragma unroll
        for (int c = 0; c < 16; ++c) {
            int idx = c * 64 + t;
            int v = lh[idx];
            int incl = v;
            #pragma unroll
            for (int off = 1; off < 64; off <<= 1) {
                int tv = __shfl_up(incl, off);
                if (t >= off) incl += tv;
            }
            loff[idx] = incl - v + carry;
            carry += __shfl(incl, 63);
        }
    }
    __syncthreads();
    for (int b = t; b < 1024; b += 256) {
        int c = lh[b];
        gof[b] = c ? atomicAdd(&bcur[b], c) : 0;
        lcur[b] = loff[b];
    }
    __syncthreads();
    for (int i = t; i < cnt; i += 256) {
        int d = dst[base + i];
        int s = src[base + i];
        int bkt = d >> 6;
        int p = atomicAdd(&lcur[bkt], 1);
        stage[p] = (unsigned int)s | ((unsigned int)(d & 63) << 16) |
                   ((unsigned int)bkt << 22);
    }
    __syncthreads();
    for (int i = t; i < cnt; i += 256) {
        unsigned int e = stage[i];
        int bkt = (int)(e >> 22);
        out[gof[bkt] + (i - loff[bkt])] = e & 0x3FFFFFu;
    }
}

// ------- fused per-bucket degree count, both sets -------
__global__ void __launch_bounds__(256)
k_degbkt2(const int* __restrict__ bbaseA, const unsigned int* __restrict__ ebufA,
          int* __restrict__ degA,
          const int* __restrict__ bbaseB, const unsigned int* __restrict__ ebufB,
          int* __restrict__ degB, int B, int n) {
    __shared__ int cnt[64];
    const int* bbase; const unsigned int* ebuf; int* deg; int b;
    if ((int)blockIdx.x < B) { bbase = bbaseA; ebuf = ebufA; deg = degA; b = blockIdx.x; }
    else                     { bbase = bbaseB; ebuf = ebufB; deg = degB; b = blockIdx.x - B; }
    int t = threadIdx.x;
    if (t < 64) cnt[t] = 0;
    __syncthreads();
    int beg = bbase[b], end = bbase[b + 1];
    for (int i = beg + t; i < end; i += 256)
        atomicAdd(&cnt[(ebuf[i] >> 16) & 63u], 1);
    __syncthreads();
    if (t < 64) {
        int node = b * NPB + t;
        if (node < n) deg[node] = cnt[t];
    }
}

// ------- prefix scan of deg -> rowstart; dinv fused in -------
__global__ void __launch_bounds__(1024)
k_scan2(const int* __restrict__ dA, int* __restrict__ rsA, float* __restrict__ dvA,
        const int* __restrict__ dB, int* __restrict__ rsB, float* __restrict__ dvB, int n) {
    const int* deg = blockIdx.x ? dB : dA;
    int* rs   = blockIdx.x ? rsB : rsA;
    float* dv = blockIdx.x ? dvB : dvA;
    __shared__ int wsum[16];
    __shared__ int woff[16];
    __shared__ int chunk_tot;
    __shared__ int carry_s;
    int t = threadIdx.x, lane = t & 63, wid = t >> 6;
    if (t == 0) carry_s = 0;
    __syncthreads();
    for (int base = 0; base < n; base += 1024) {
        int i = base + t;
        int v = (i < n) ? deg[i] : 0;
        int incl = v;
        #pragma unroll
        for (int off = 1; off < 64; off <<= 1) {
            int tv = __shfl_up(incl, off, 64);
            if (lane >= off) incl += tv;
        }
        if (lane == 63) wsum[wid] = incl;
        __syncthreads();
        if (t < 16) {
            int wv = wsum[t];
            int winc = wv;
            #pragma unroll
            for (int off = 1; off < 16; off <<= 1) {
                int tv = __shfl_up(winc, off, 16);
                if (t >= off) winc += tv;
            }
            woff[t] = winc - wv;
            if (t == 15) chunk_tot = winc;
        }
        __syncthreads();
        int excl = incl - v + woff[wid] + carry_s;
        if (i < n) {
            rs[i] = excl;
            dv[i] = (v > 0) ? rsqrtf((float)v) : 0.f;
        }
        __syncthreads();
        if (t == 0) carry_s += chunk_tot;
        __syncthreads();
    }
    if (t == 0) rs[n] = carry_s;
}

// ------- fused per-bucket scatter, both sets (cursors from global rs) -------
__global__ void __launch_bounds__(256)
k_bucket22(const int* __restrict__ bbaseA, const unsigned int* __restrict__ ebufA,
           const int* __restrict__ rsA, unsigned short* __restrict__ ssrcA,
           const int* __restrict__ bbaseB, const unsigned int* __restrict__ ebufB,
           const int* __restrict__ rsB, unsigned short* __restrict__ ssrcB, int B, int n) {
    __shared__ int lcur[64];
    const int *bbase, *rs; const unsigned int* ebuf; unsigned short* ssrc; int b;
    if ((int)blockIdx.x < B) { bbase = bbaseA; ebuf = ebufA; rs = rsA; ssrc = ssrcA; b = blockIdx.x; }
    else                     { bbase = bbaseB; ebuf = ebufB; rs = rsB; ssrc = ssrcB; b = blockIdx.x - B; }
    int t = threadIdx.x;
    if (t < 64) {
        int node = b * NPB + t;
        lcur[t] = (node < n) ? rs[node] : 0;
    }
    __syncthreads();
    int beg = bbase[b], end = bbase[b + 1];
    for (int i = beg + t; i < end; i += 256) {
        unsigned int e = ebuf[i];
        int p = atomicAdd(&lcur[(e >> 16) & 63u], 1);
        ssrc[p] = (unsigned short)(e & 0xFFFFu);
    }
}

// ------- x4-unrolled gather-accumulate body for layer 1 -------
__device__ inline void agg64_body(const int* __restrict__ rs,
                                  const unsigned short* __restrict__ ssrc,
                                  const float* __restrict__ dinv,
                                  const us8* __restrict__ hwb8,
                                  const float* __restrict__ b1,
                                  unsigned short* __restrict__ R1b,
                                  int col_unit, int n, int tid) {
    int v = tid >> 3, q = tid & 7;
    if (v >= n) return;
    int beg = rs[v], end = rs[v + 1];
    float a[8] = {0.f, 0.f, 0.f, 0.f, 0.f, 0.f, 0.f, 0.f};
    int i = beg;
    for (; i + 4 <= end; i += 4) {   // 4 independent load chains -> MLP
        int s0 = ssrc[i + 0], s1 = ssrc[i + 1], s2 = ssrc[i + 2], s3 = ssrc[i + 3];
        float c0 = dinv[s0], c1 = dinv[s1], c2 = dinv[s2], c3 = dinv[s3];
        us8 h0 = hwb8[s0 * 8 + q], h1 = hwb8[s1 * 8 + q];
        us8 h2 = hwb8[s2 * 8 + q], h3 = hwb8[s3 * 8 + q];
        #pragma unroll
        for (int j = 0; j < 8; ++j) {
            a[j] = fmaf(b2f(h0[j]), c0, a[j]);
            a[j] = fmaf(b2f(h1[j]), c1, a[j]);
            a[j] = fmaf(b2f(h2[j]), c2, a[j]);
            a[j] = fmaf(b2f(h3[j]), c3, a[j]);
        }
    }
    for (; i < end; ++i) {
        int s = ssrc[i];
        float sc = dinv[s];
        us8 h = hwb8[s * 8 + q];
        #pragma unroll
        for (int j = 0; j < 8; ++j) a[j] = fmaf(b2f(h[j]), sc, a[j]);
    }
    float dd = dinv[v];
    us8 o;
    #pragma unroll
    for (int j = 0; j < 8; ++j) {
        float r = fmaf(a[j], dd, b1[q * 8 + j]);
        o[j] = f2b(r > 0.f ? r : 0.f);
    }
    ((us8*)&R1b[v * 192])[col_unit + q] = o;
}

// ------- fused layer-1: E2 agg | E1 agg | self (blockIdx ranges; E2 first) -------
__global__ void k_agg1f(const int* __restrict__ rs1, const unsigned short* __restrict__ ssrc1,
                        const float* __restrict__ dinv1,
                        const int* __restrict__ rs2, const unsigned short* __restrict__ ssrc2,
                        const float* __restrict__ dinv2,
                        const us8* __restrict__ hwb8, const float* __restrict__ b1,
                        unsigned short* __restrict__ R1b, int n, int nba) {
    int bid = blockIdx.x;
    if (bid < nba) {                 // edge set 2 (the long pole) starts first
        agg64_body(rs2, ssrc2, dinv2, hwb8, b1, R1b, 8, n, bid * 256 + threadIdx.x);
    } else if (bid < 2 * nba) {      // edge set 1
        agg64_body(rs1, ssrc1, dinv1, hwb8, b1, R1b, 0, n,
                   (bid - nba) * 256 + threadIdx.x);
    } else {                         // self branch
        int tid = (bid - 2 * nba) * 256 + threadIdx.x;
        int v = tid >> 3, q = tid & 7;
        if (v >= n) return;
        us8 h = hwb8[v * 8 + q];
        us8 o;
        #pragma unroll
        for (int j = 0; j < 8; ++j) {
            float r = b2f(h[j]) + b1[q * 8 + j];
            o[j] = f2b(r > 0.f ? r : 0.f);
        }
        ((us8*)&R1b[v * 192])[16 + q] = o;
    }
}

// ---------------- GEMM2: hwb2 = bf16(R1 @ w2)  ([n,192]@[192,16]) ----------------
__global__ void __launch_bounds__(256)
k_gemm2(const unsigned short* __restrict__ R1b, const float* __restrict__ w2,
        unsigned short* __restrict__ hwb2, int n) {
    __shared__ float ws[192 * 16];
    __shared__ float rs[16][193];
    int t = threadIdx.x;
    for (int i = t; i < 192 * 16; i += 256) ws[i] = w2[i];
    int row0 = blockIdx.x * 16;
    for (int i = t; i < 16 * 192; i += 256) {
        int r = i / 192, j = i - r * 192;
        int v = row0 + r;
        rs[r][j] = (v < n) ? b2f(R1b[v * 192 + j]) : 0.f;
    }
    __syncthreads();
    int r = t >> 4, c = t & 15;
    int v = row0 + r;
    if (v >= n) return;
    float acc = 0.f;
    #pragma unroll 8
    for (int j = 0; j < 192; ++j) acc += rs[r][j] * ws[j * 16 + c];
    hwb2[v * 16 + c] = f2b(acc);
}

// ------- x4-unrolled layer-2 gather body -------
__device__ inline void agg16_body(const int* __restrict__ rs,
                                  const unsigned short* __restrict__ ssrc,
                                  const float* __restrict__ dinv,
                                  const us8* __restrict__ hwb2_8,
                                  float* __restrict__ acc2, int n, int tid) {
    int v = tid >> 1, q = tid & 1;
    if (v >= n) return;
    int beg = rs[v], end = rs[v + 1];
    float a[8] = {0.f, 0.f, 0.f, 0.f, 0.f, 0.f, 0.f, 0.f};
    int i = beg;
    for (; i + 4 <= end; i += 4) {
        int s0 = ssrc[i + 0], s1 = ssrc[i + 1], s2 = ssrc[i + 2], s3 = ssrc[i + 3];
        float c0 = dinv[s0], c1 = dinv[s1], c2 = dinv[s2], c3 = dinv[s3];
        us8 h0 = hwb2_8[s0 * 2 + q], h1 = hwb2_8[s1 * 2 + q];
        us8 h2 = hwb2_8[s2 * 2 + q], h3 = hwb2_8[s3 * 2 + q];
        #pragma unroll
        for (int j = 0; j < 8; ++j) {
            a[j] = fmaf(b2f(h0[j]), c0, a[j]);
            a[j] = fmaf(b2f(h1[j]), c1, a[j]);
            a[j] = fmaf(b2f(h2[j]), c2, a[j]);
            a[j] = fmaf(b2f(h3[j]), c3, a[j]);
        }
    }
    for (; i < end; ++i) {
        int s = ssrc[i];
        float sc = dinv[s];
        us8 h = hwb2_8[s * 2 + q];
        #pragma unroll
        for (int j = 0; j < 8; ++j) a[j] = fmaf(b2f(h[j]), sc, a[j]);
    }
    float4* o = (float4*)&acc2[v * 16 + q * 8];
    o[0] = make_float4(a[0], a[1], a[2], a[3]);
    o[1] = make_float4(a[4], a[5], a[6], a[7]);
}

// ------- fused layer-2 aggregate: E2 -> acc2b first, then E1 -> acc2a -------
__global__ void k_agg16f(const int* __restrict__ rs1, const unsigned short* __restrict__ ssrc1,
                         const float* __restrict__ dinv1, float* __restrict__ acc2a,
                         const int* __restrict__ rs2, const unsigned short* __restrict__ ssrc2,
                         const float* __restrict__ dinv2, float* __restrict__ acc2b,
                         const us8* __restrict__ hwb2_8, int n, int nba) {
    int bid = blockIdx.x;
    if (bid < nba)
        agg16_body(rs2, ssrc2, dinv2, hwb2_8, acc2b, n, bid * 256 + threadIdx.x);
    else
        agg16_body(rs1, ssrc1, dinv1, hwb2_8, acc2a, n, (bid - nba) * 256 + threadIdx.x);
}

// ------- final: combine layer-2 branches, linear head, log_softmax ----------
__global__ void k_final(const unsigned short* __restrict__ hwb2,
                        const float* __restrict__ acc2a, const float* __restrict__ acc2b,
                        const float* __restrict__ dinv1, const float* __restrict__ dinv2,
                        const float* __restrict__ b2, const float* __restrict__ lw,
                        const float* __restrict__ lb, float* __restrict__ out, int n) {
    __shared__ float lws[48 * 16];
    __shared__ float r2s[16][49];
    int t = threadIdx.x;
    for (int i = t; i < 48 * 16; i += 256) lws[i] = lw[i];
    int ni = t >> 4, c = t & 15;
    int v = blockIdx.x * 16 + ni;
    if (v < n) {
        float bb = b2[c];
        r2s[ni][c]      = fmaf(dinv1[v], acc2a[v * 16 + c], bb);
        r2s[ni][16 + c] = fmaf(dinv2[v], acc2b[v * 16 + c], bb);
        r2s[ni][32 + c] = b2f(hwb2[v * 16 + c]) + bb;
    }
    __syncthreads();
    if (v >= n) return;
    float o = lb[c];
    #pragma unroll
    for (int j = 0; j < 48; ++j) o += r2s[ni][j] * lws[j * 16 + c];
    float m = o;
    for (int off = 8; off >= 1; off >>= 1) m = fmaxf(m, __shfl_xor(m, off, 16));
    float e = expf(o - m);
    float ssum = e;
    for (int off = 8; off >= 1; off >>= 1) ssum += __shfl_xor(ssum, off, 16);
    out[v * 16 + c] = (o - m) - logf(ssum);
}

extern "C" void kernel_launch(void* const* d_in, const int* in_sizes, int n_in,
                              void* d_out, int out_size, void* d_ws, size_t ws_size,
                              hipStream_t stream) {
    const float* x     = (const float*)d_in[0];
    const float* w1    = (const float*)d_in[1];
    const float* b1    = (const float*)d_in[2];
    const float* w2    = (const float*)d_in[3];
    const float* b2    = (const float*)d_in[4];
    const float* lin_w = (const float*)d_in[5];
    const float* lin_b = (const float*)d_in[6];
    const int*   ei    = (const int*)d_in[7];
    const int*   ei2   = (const int*)d_in[8];

    const int n  = in_sizes[0] / 128;   // 50000
    const int E1 = in_sizes[7] / 2;     // 800000
    const int E2 = in_sizes[8] / 2;     // 3000000
    const int B  = (n + NPB - 1) / NPB; // 782

    char* ws = (char*)d_ws;
    unsigned short* hwb   = (unsigned short*)(ws + 0);         // [n,64] bf16 -> 6.4M
    unsigned short* hwb2  = (unsigned short*)(ws + 6400000);   // [n,16] bf16 -> 8.0M
    unsigned short* R1b   = (unsigned short*)(ws + 8000000);   // [n,192] bf16 -> 27.2M
    unsigned short* ssrc1 = (unsigned short*)(ws + 27200000);  // [E1] -> 28.8M
    unsigned short* ssrc2 = (unsigned short*)(ws + 28800000);  // [E2] -> 34.8M
    unsigned int* ebuf1   = (unsigned int*)(ws + 34800000);    // [E1] -> 38.0M
    unsigned int* ebuf2   = (unsigned int*)(ws + 38000000);    // [E2] -> 50.0M
    float*        acc2a   = (float*)(ws + 50000000);           // [n,16] -> 53.2M
    float*        acc2b   = (float*)(ws + 53200000);           // [n,16] -> 56.4M
    int*          deg1    = (int*)(ws + 56400000);             // [n]
    int*          deg2    = (int*)(ws + 56600000);             // [n]
    float*        dinv1   = (float*)(ws + 56800000);           // [n]
    float*        dinv2   = (float*)(ws + 57000000);           // [n]
    int*          rs1     = (int*)(ws + 57200000);             // [n+1]
    int*          rs2     = (int*)(ws + 57400016);             // [n+1]
    int*          bhist1  = (int*)(ws + 58000032);             // [1024]
    int*          bhist2  = (int*)(ws + 58004128);             // [1024] (contiguous)
    int*          bbase1  = (int*)(ws + 58008224);             // [B+1]
    int*          bbase2  = (int*)(ws + 58012320);             // [B+1]
    int*          bcur1   = (int*)(ws + 58016416);             // [B]
    int*          bcur2   = (int*)(ws + 58020512);             // [B]

    hipMemsetAsync(bhist1, 0, 8192, stream);   // bhist1+bhist2, contiguous

    k_gemm1<<<(n + 15) / 16, 256, 0, stream>>>(x, w1, hwb, n);

    const int nbh1 = (E1 + 4095) / 4096, nbh2 = (E2 + 4095) / 4096;
    k_hist2<<<nbh1 + nbh2, 256, 0, stream>>>(ei + E1, bhist1, E1, nbh1,
                                             ei2 + E2, bhist2, E2);
    k_bscan<<<2, 64, 0, stream>>>(bhist1, bbase1, bcur1, bhist2, bbase2, bcur2, B);

    const int nbp1 = (E1 + CHUNK - 1) / CHUNK, nbp2 = (E2 + CHUNK - 1) / CHUNK;
    k_part2<<<nbp1 + nbp2, 256, 0, stream>>>(ei, ei + E1, bcur1, ebuf1, E1, nbp1,
                                             ei2, ei2 + E2, bcur2, ebuf2, E2);

    k_degbkt2<<<2 * B, 256, 0, stream>>>(bbase1, ebuf1, deg1, bbase2, ebuf2, deg2, B, n);
    k_scan2<<<2, 1024, 0, stream>>>(deg1, rs1, dinv1, deg2, rs2, dinv2, n);
    k_bucket22<<<2 * B, 256, 0, stream>>>(bbase1, ebuf1, rs1, ssrc1,
                                          bbase2, ebuf2, rs2, ssrc2, B, n);

    const int nba = (n * 8 + 255) / 256;
    k_agg1f<<<3 * nba, 256, 0, stream>>>(rs1, ssrc1, dinv1, rs2, ssrc2, dinv2,
                                         (const us8*)hwb, b1, R1b, n, nba);

    k_gemm2<<<(n + 15) / 16, 256, 0, stream>>>(R1b, w2, hwb2, n);

    const int nb16 = (n * 2 + 255) / 256;
    k_agg16f<<<2 * nb16, 256, 0, stream>>>(rs1, ssrc1, dinv1, acc2a,
                                           rs2, ssrc2, dinv2, acc2b,
                                           (const us8*)hwb2, n, nb16);

    k_final<<<(n + 15) / 16, 256, 0, stream>>>(hwb2, acc2a, acc2b, dinv1, dinv2, b2,
                                               lin_w, lin_b, (float*)d_out, n);
}

// Round 11
// 320.962 us; speedup vs baseline: 7.4534x; 1.0420x over previous
//
#include <hip/hip_runtime.h>
#include <math.h>

// x[50000,128] w1[128,64] b1[64] w2[192,16] b2[16] lin_w[48,16] lin_b[16]
// edge_index[2,800000] edge_index2[2,3000000] (int32, row0=src, row1=dst)
//
// R11 = R10 with two occupancy/contention constants tuned:
//  - k_part2 CHUNK 16384->8192: LDS 80KB->48KB => 1->3 blocks/CU (was the top
//    kernel at 6.9% occupancy, latency-bound)
//  - k_hist2 per-block chunk 4096->16384: 4x fewer blocks => 750K->238K global
//    atomics on the 1024-entry bucket histograms

#define NPB    64
#define CHUNK  8192
#define HCHUNK 16384

typedef unsigned short us8 __attribute__((ext_vector_type(8)));

__device__ inline float b2f(unsigned short u) {
    return __uint_as_float(((unsigned int)u) << 16);
}
// round-to-nearest-even f32 -> bf16 (finite values; matches __float2bfloat16)
__device__ inline unsigned short f2b(float f) {
    unsigned int u = __float_as_uint(f);
    u = (u + 0x7FFFu + ((u >> 16) & 1u)) >> 16;
    return (unsigned short)u;
}

// ---------------- GEMM1: hwb = bf16(x @ w1)  ([n,128]@[128,64]) ----------------
__global__ void __launch_bounds__(256)
k_gemm1(const float* __restrict__ x, const float* __restrict__ w1,
        unsigned short* __restrict__ hwb, int n) {
    __shared__ float ws[128 * 64];   // 32 KB
    __shared__ float xs[16 * 128];   // 8 KB
    int t = threadIdx.x;
    for (int i = t; i < 128 * 64; i += 256) ws[i] = w1[i];
    int row0 = blockIdx.x * 16;
    for (int i = t; i < 16 * 128; i += 256) {
        int r = row0 + (i >> 7);
        xs[i] = (r < n) ? x[r * 128 + (i & 127)] : 0.f;
    }
    __syncthreads();
    int c = t & 63, rg = t >> 6;    // 4 rows per thread
    float a0 = 0.f, a1 = 0.f, a2 = 0.f, a3 = 0.f;
    const float* x0 = &xs[(rg * 4 + 0) * 128];
    const float* x1 = &xs[(rg * 4 + 1) * 128];
    const float* x2 = &xs[(rg * 4 + 2) * 128];
    const float* x3 = &xs[(rg * 4 + 3) * 128];
    #pragma unroll 8
    for (int k = 0; k < 128; ++k) {
        float wv = ws[k * 64 + c];
        a0 = fmaf(x0[k], wv, a0);
        a1 = fmaf(x1[k], wv, a1);
        a2 = fmaf(x2[k], wv, a2);
        a3 = fmaf(x3[k], wv, a3);
    }
    int r = row0 + rg * 4;
    if (r + 0 < n) hwb[(r + 0) * 64 + c] = f2b(a0);
    if (r + 1 < n) hwb[(r + 1) * 64 + c] = f2b(a1);
    if (r + 2 < n) hwb[(r + 2) * 64 + c] = f2b(a2);
    if (r + 3 < n) hwb[(r + 3) * 64 + c] = f2b(a3);
}

// ------- fused bucket histogram, both edge sets (blockIdx split) -------
__global__ void k_hist2(const int* __restrict__ dstA, int* __restrict__ bhA, int EA, int nbA,
                        const int* __restrict__ dstB, int* __restrict__ bhB, int EB) {
    __shared__ int lh[1024];
    const int* dst; int* bh; int E; int cb;
    if ((int)blockIdx.x < nbA) { dst = dstA; bh = bhA; E = EA; cb = blockIdx.x; }
    else                       { dst = dstB; bh = bhB; E = EB; cb = blockIdx.x - nbA; }
    int t = threadIdx.x;
    for (int i = t; i < 1024; i += 256) lh[i] = 0;
    __syncthreads();
    int base = cb * HCHUNK;
    int cnt = min(HCHUNK, E - base);
    for (int i = t; i < cnt; i += 256) atomicAdd(&lh[dst[base + i] >> 6], 1);
    __syncthreads();
    for (int b = t; b < 1024; b += 256)
        if (lh[b]) atomicAdd(&bh[b], lh[b]);
}

// ------- scan bucket histograms -> bbase (exclusive) and bcur -------
__global__ void k_bscan(const int* __restrict__ bhA, int* __restrict__ bbA, int* __restrict__ bcA,
                        const int* __restrict__ bhB, int* __restrict__ bbB, int* __restrict__ bcB,
                        int B) {
    const int* bh = blockIdx.x ? bhB : bhA;
    int* bb = blockIdx.x ? bbB : bbA;
    int* bc = blockIdx.x ? bcB : bcA;
    int t = threadIdx.x;
    int carry = 0;
    int nch = (B + 63) >> 6;
    for (int c = 0; c < nch; ++c) {
        int idx = c * 64 + t;
        int v = (idx < B) ? bh[idx] : 0;
        int incl = v;
        #pragma unroll
        for (int off = 1; off < 64; off <<= 1) {
            int tv = __shfl_up(incl, off);
            if (t >= off) incl += tv;
        }
        if (idx < B) { bb[idx] = incl - v + carry; bc[idx] = incl - v + carry; }
        carry += __shfl(incl, 63);
    }
    if (t == 0) bb[B] = carry;
}

// ------- fused coarse partition, both edge sets (blockIdx split) -------
// packed word: src(16b) | dstlocal(6b)<<16 | bucket(10b)<<22 (stripped on write)
__global__ void __launch_bounds__(256)
k_part2(const int* __restrict__ srcA, const int* __restrict__ dstA,
        int* __restrict__ bcurA, unsigned int* __restrict__ outA, int EA, int nbA,
        const int* __restrict__ srcB, const int* __restrict__ dstB,
        int* __restrict__ bcurB, unsigned int* __restrict__ outB, int EB) {
    __shared__ int lh[1024];
    __shared__ int loff[1024];
    __shared__ int gof[1024];
    __shared__ int lcur[1024];
    __shared__ unsigned int stage[CHUNK];   // 32 KB -> 48 KB total -> 3 blocks/CU
    const int *src, *dst; int *bcur; unsigned int *out; int E, cb;
    if ((int)blockIdx.x < nbA) { src = srcA; dst = dstA; bcur = bcurA; out = outA; E = EA; cb = blockIdx.x; }
    else                       { src = srcB; dst = dstB; bcur = bcurB; out = outB; E = EB; cb = blockIdx.x - nbA; }
    int t = threadIdx.x;
    int base = cb * CHUNK;
    int cnt = min(CHUNK, E - base);
    for (int i = t; i < 1024; i += 256) lh[i] = 0;
    __syncthreads();
    for (int i = t; i < cnt; i += 256) atomicAdd(&lh[dst[base + i] >> 6], 1);
    __syncthreads();
    if (t < 64) {
        int carry = 0;
        #pragma unroll
        for (int c = 0; c < 16; ++c) {
            int idx = c * 64 + t;
            int v = lh[idx];
            int incl = v;
            #pragma unroll
            for (int off = 1; off < 64; off <<= 1) {
                int tv = __shfl_up(incl, off);
                if (t >= off) incl += tv;
            }
            loff[idx] = incl - v + carry;
            carry += __shfl(incl, 63);
        }
    }
    __syncthreads();
    for (int b = t; b < 1024; b += 256) {
        int c = lh[b];
        gof[b] = c ? atomicAdd(&bcur[b], c) : 0;
        lcur[b] = loff[b];
    }
    __syncthreads();
    for (int i = t; i < cnt; i += 256) {
        int d = dst[base + i];
        int s = src[base + i];
        int bkt = d >> 6;
        int p = atomicAdd(&lcur[bkt], 1);
        stage[p] = (unsigned int)s | ((unsigned int)(d & 63) << 16) |
                   ((unsigned int)bkt << 22);
    }
    __syncthreads();
    for (int i = t; i < cnt; i += 256) {
        unsigned int e = stage[i];
        int bkt = (int)(e >> 22);
        out[gof[bkt] + (i - loff[bkt])] = e & 0x3FFFFFu;
    }
}

// ------- fused per-bucket degree count, both sets -------
__global__ void __launch_bounds__(256)
k_degbkt2(const int* __restrict__ bbaseA, const unsigned int* __restrict__ ebufA,
          int* __restrict__ degA,
          const int* __restrict__ bbaseB, const unsigned int* __restrict__ ebufB,
          int* __restrict__ degB, int B, int n) {
    __shared__ int cnt[64];
    const int* bbase; const unsigned int* ebuf; int* deg; int b;
    if ((int)blockIdx.x < B) { bbase = bbaseA; ebuf = ebufA; deg = degA; b = blockIdx.x; }
    else                     { bbase = bbaseB; ebuf = ebufB; deg = degB; b = blockIdx.x - B; }
    int t = threadIdx.x;
    if (t < 64) cnt[t] = 0;
    __syncthreads();
    int beg = bbase[b], end = bbase[b + 1];
    for (int i = beg + t; i < end; i += 256)
        atomicAdd(&cnt[(ebuf[i] >> 16) & 63u], 1);
    __syncthreads();
    if (t < 64) {
        int node = b * NPB + t;
        if (node < n) deg[node] = cnt[t];
    }
}

// ------- prefix scan of deg -> rowstart; dinv fused in -------
__global__ void __launch_bounds__(1024)
k_scan2(const int* __restrict__ dA, int* __restrict__ rsA, float* __restrict__ dvA,
        const int* __restrict__ dB, int* __restrict__ rsB, float* __restrict__ dvB, int n) {
    const int* deg = blockIdx.x ? dB : dA;
    int* rs   = blockIdx.x ? rsB : rsA;
    float* dv = blockIdx.x ? dvB : dvA;
    __shared__ int wsum[16];
    __shared__ int woff[16];
    __shared__ int chunk_tot;
    __shared__ int carry_s;
    int t = threadIdx.x, lane = t & 63, wid = t >> 6;
    if (t == 0) carry_s = 0;
    __syncthreads();
    for (int base = 0; base < n; base += 1024) {
        int i = base + t;
        int v = (i < n) ? deg[i] : 0;
        int incl = v;
        #pragma unroll
        for (int off = 1; off < 64; off <<= 1) {
            int tv = __shfl_up(incl, off, 64);
            if (lane >= off) incl += tv;
        }
        if (lane == 63) wsum[wid] = incl;
        __syncthreads();
        if (t < 16) {
            int wv = wsum[t];
            int winc = wv;
            #pragma unroll
            for (int off = 1; off < 16; off <<= 1) {
                int tv = __shfl_up(winc, off, 16);
                if (t >= off) winc += tv;
            }
            woff[t] = winc - wv;
            if (t == 15) chunk_tot = winc;
        }
        __syncthreads();
        int excl = incl - v + woff[wid] + carry_s;
        if (i < n) {
            rs[i] = excl;
            dv[i] = (v > 0) ? rsqrtf((float)v) : 0.f;
        }
        __syncthreads();
        if (t == 0) carry_s += chunk_tot;
        __syncthreads();
    }
    if (t == 0) rs[n] = carry_s;
}

// ------- fused per-bucket scatter, both sets (cursors from global rs) -------
__global__ void __launch_bounds__(256)
k_bucket22(const int* __restrict__ bbaseA, const unsigned int* __restrict__ ebufA,
           const int* __restrict__ rsA, unsigned short* __restrict__ ssrcA,
           const int* __restrict__ bbaseB, const unsigned int* __restrict__ ebufB,
           const int* __restrict__ rsB, unsigned short* __restrict__ ssrcB, int B, int n) {
    __shared__ int lcur[64];
    const int *bbase, *rs; const unsigned int* ebuf; unsigned short* ssrc; int b;
    if ((int)blockIdx.x < B) { bbase = bbaseA; ebuf = ebufA; rs = rsA; ssrc = ssrcA; b = blockIdx.x; }
    else                     { bbase = bbaseB; ebuf = ebufB; rs = rsB; ssrc = ssrcB; b = blockIdx.x - B; }
    int t = threadIdx.x;
    if (t < 64) {
        int node = b * NPB + t;
        lcur[t] = (node < n) ? rs[node] : 0;
    }
    __syncthreads();
    int beg = bbase[b], end = bbase[b + 1];
    for (int i = beg + t; i < end; i += 256) {
        unsigned int e = ebuf[i];
        int p = atomicAdd(&lcur[(e >> 16) & 63u], 1);
        ssrc[p] = (unsigned short)(e & 0xFFFFu);
    }
}

// ------- x4-unrolled gather-accumulate body for layer 1 -------
__device__ inline void agg64_body(const int* __restrict__ rs,
                                  const unsigned short* __restrict__ ssrc,
                                  const float* __restrict__ dinv,
                                  const us8* __restrict__ hwb8,
                                  const float* __restrict__ b1,
                                  unsigned short* __restrict__ R1b,
                                  int col_unit, int n, int tid) {
    int v = tid >> 3, q = tid & 7;
    if (v >= n) return;
    int beg = rs[v], end = rs[v + 1];
    float a[8] = {0.f, 0.f, 0.f, 0.f, 0.f, 0.f, 0.f, 0.f};
    int i = beg;
    for (; i + 4 <= end; i += 4) {   // 4 independent load chains -> MLP
        int s0 = ssrc[i + 0], s1 = ssrc[i + 1], s2 = ssrc[i + 2], s3 = ssrc[i + 3];
        float c0 = dinv[s0], c1 = dinv[s1], c2 = dinv[s2], c3 = dinv[s3];
        us8 h0 = hwb8[s0 * 8 + q], h1 = hwb8[s1 * 8 + q];
        us8 h2 = hwb8[s2 * 8 + q], h3 = hwb8[s3 * 8 + q];
        #pragma unroll
        for (int j = 0; j < 8; ++j) {
            a[j] = fmaf(b2f(h0[j]), c0, a[j]);
            a[j] = fmaf(b2f(h1[j]), c1, a[j]);
            a[j] = fmaf(b2f(h2[j]), c2, a[j]);
            a[j] = fmaf(b2f(h3[j]), c3, a[j]);
        }
    }
    for (; i < end; ++i) {
        int s = ssrc[i];
        float sc = dinv[s];
        us8 h = hwb8[s * 8 + q];
        #pragma unroll
        for (int j = 0; j < 8; ++j) a[j] = fmaf(b2f(h[j]), sc, a[j]);
    }
    float dd = dinv[v];
    us8 o;
    #pragma unroll
    for (int j = 0; j < 8; ++j) {
        float r = fmaf(a[j], dd, b1[q * 8 + j]);
        o[j] = f2b(r > 0.f ? r : 0.f);
    }
    ((us8*)&R1b[v * 192])[col_unit + q] = o;
}

// ------- fused layer-1: E2 agg | E1 agg | self (blockIdx ranges; E2 first) -------
__global__ void k_agg1f(const int* __restrict__ rs1, const unsigned short* __restrict__ ssrc1,
                        const float* __restrict__ dinv1,
                        const int* __restrict__ rs2, const unsigned short* __restrict__ ssrc2,
                        const float* __restrict__ dinv2,
                        const us8* __restrict__ hwb8, const float* __restrict__ b1,
                        unsigned short* __restrict__ R1b, int n, int nba) {
    int bid = blockIdx.x;
    if (bid < nba) {                 // edge set 2 (the long pole) starts first
        agg64_body(rs2, ssrc2, dinv2, hwb8, b1, R1b, 8, n, bid * 256 + threadIdx.x);
    } else if (bid < 2 * nba) {      // edge set 1
        agg64_body(rs1, ssrc1, dinv1, hwb8, b1, R1b, 0, n,
                   (bid - nba) * 256 + threadIdx.x);
    } else {                         // self branch
        int tid = (bid - 2 * nba) * 256 + threadIdx.x;
        int v = tid >> 3, q = tid & 7;
        if (v >= n) return;
        us8 h = hwb8[v * 8 + q];
        us8 o;
        #pragma unroll
        for (int j = 0; j < 8; ++j) {
            float r = b2f(h[j]) + b1[q * 8 + j];
            o[j] = f2b(r > 0.f ? r : 0.f);
        }
        ((us8*)&R1b[v * 192])[16 + q] = o;
    }
}

// ---------------- GEMM2: hwb2 = bf16(R1 @ w2)  ([n,192]@[192,16]) ----------------
__global__ void __launch_bounds__(256)
k_gemm2(const unsigned short* __restrict__ R1b, const float* __restrict__ w2,
        unsigned short* __restrict__ hwb2, int n) {
    __shared__ float ws[192 * 16];
    __shared__ float rs[16][193];
    int t = threadIdx.x;
    for (int i = t; i < 192 * 16; i += 256) ws[i] = w2[i];
    int row0 = blockIdx.x * 16;
    for (int i = t; i < 16 * 192; i += 256) {
        int r = i / 192, j = i - r * 192;
        int v = row0 + r;
        rs[r][j] = (v < n) ? b2f(R1b[v * 192 + j]) : 0.f;
    }
    __syncthreads();
    int r = t >> 4, c = t & 15;
    int v = row0 + r;
    if (v >= n) return;
    float acc = 0.f;
    #pragma unroll 8
    for (int j = 0; j < 192; ++j) acc += rs[r][j] * ws[j * 16 + c];
    hwb2[v * 16 + c] = f2b(acc);
}

// ------- x4-unrolled layer-2 gather body -------
__device__ inline void agg16_body(const int* __restrict__ rs,
                                  const unsigned short* __restrict__ ssrc,
                                  const float* __restrict__ dinv,
                                  const us8* __restrict__ hwb2_8,
                                  float* __restrict__ acc2, int n, int tid) {
    int v = tid >> 1, q = tid & 1;
    if (v >= n) return;
    int beg = rs[v], end = rs[v + 1];
    float a[8] = {0.f, 0.f, 0.f, 0.f, 0.f, 0.f, 0.f, 0.f};
    int i = beg;
    for (; i + 4 <= end; i += 4) {
        int s0 = ssrc[i + 0], s1 = ssrc[i + 1], s2 = ssrc[i + 2], s3 = ssrc[i + 3];
        float c0 = dinv[s0], c1 = dinv[s1], c2 = dinv[s2], c3 = dinv[s3];
        us8 h0 = hwb2_8[s0 * 2 + q], h1 = hwb2_8[s1 * 2 + q];
        us8 h2 = hwb2_8[s2 * 2 + q], h3 = hwb2_8[s3 * 2 + q];
        #pragma unroll
        for (int j = 0; j < 8; ++j) {
            a[j] = fmaf(b2f(h0[j]), c0, a[j]);
            a[j] = fmaf(b2f(h1[j]), c1, a[j]);
            a[j] = fmaf(b2f(h2[j]), c2, a[j]);
            a[j] = fmaf(b2f(h3[j]), c3, a[j]);
        }
    }
    for (; i < end; ++i) {
        int s = ssrc[i];
        float sc = dinv[s];
        us8 h = hwb2_8[s * 2 + q];
        #pragma unroll
        for (int j = 0; j < 8; ++j) a[j] = fmaf(b2f(h[j]), sc, a[j]);
    }
    float4* o = (float4*)&acc2[v * 16 + q * 8];
    o[0] = make_float4(a[0], a[1], a[2], a[3]);
    o[1] = make_float4(a[4], a[5], a[6], a[7]);
}

// ------- fused layer-2 aggregate: E2 -> acc2b first, then E1 -> acc2a -------
__global__ void k_agg16f(const int* __restrict__ rs1, const unsigned short* __restrict__ ssrc1,
                         const float* __restrict__ dinv1, float* __restrict__ acc2a,
                         const int* __restrict__ rs2, const unsigned short* __restrict__ ssrc2,
                         const float* __restrict__ dinv2, float* __restrict__ acc2b,
                         const us8* __restrict__ hwb2_8, int n, int nba) {
    int bid = blockIdx.x;
    if (bid < nba)
        agg16_body(rs2, ssrc2, dinv2, hwb2_8, acc2b, n, bid * 256 + threadIdx.x);
    else
        agg16_body(rs1, ssrc1, dinv1, hwb2_8, acc2a, n, (bid - nba) * 256 + threadIdx.x);
}

// ------- final: combine layer-2 branches, linear head, log_softmax ----------
__global__ void k_final(const unsigned short* __restrict__ hwb2,
                        const float* __restrict__ acc2a, const float* __restrict__ acc2b,
                        const float* __restrict__ dinv1, const float* __restrict__ dinv2,
                        const float* __restrict__ b2, const float* __restrict__ lw,
                        const float* __restrict__ lb, float* __restrict__ out, int n) {
    __shared__ float lws[48 * 16];
    __shared__ float r2s[16][49];
    int t = threadIdx.x;
    for (int i = t; i < 48 * 16; i += 256) lws[i] = lw[i];
    int ni = t >> 4, c = t & 15;
    int v = blockIdx.x * 16 + ni;
    if (v < n) {
        float bb = b2[c];
        r2s[ni][c]      = fmaf(dinv1[v], acc2a[v * 16 + c], bb);
        r2s[ni][16 + c] = fmaf(dinv2[v], acc2b[v * 16 + c], bb);
        r2s[ni][32 + c] = b2f(hwb2[v * 16 + c]) + bb;
    }
    __syncthreads();
    if (v >= n) return;
    float o = lb[c];
    #pragma unroll
    for (int j = 0; j < 48; ++j) o += r2s[ni][j] * lws[j * 16 + c];
    float m = o;
    for (int off = 8; off >= 1; off >>= 1) m = fmaxf(m, __shfl_xor(m, off, 16));
    float e = expf(o - m);
    float ssum = e;
    for (int off = 8; off >= 1; off >>= 1) ssum += __shfl_xor(ssum, off, 16);
    out[v * 16 + c] = (o - m) - logf(ssum);
}

extern "C" void kernel_launch(void* const* d_in, const int* in_sizes, int n_in,
                              void* d_out, int out_size, void* d_ws, size_t ws_size,
                              hipStream_t stream) {
    const float* x     = (const float*)d_in[0];
    const float* w1    = (const float*)d_in[1];
    const float* b1    = (const float*)d_in[2];
    const float* w2    = (const float*)d_in[3];
    const float* b2    = (const float*)d_in[4];
    const float* lin_w = (const float*)d_in[5];
    const float* lin_b = (const float*)d_in[6];
    const int*   ei    = (const int*)d_in[7];
    const int*   ei2   = (const int*)d_in[8];

    const int n  = in_sizes[0] / 128;   // 50000
    const int E1 = in_sizes[7] / 2;     // 800000
    const int E2 = in_sizes[8] / 2;     // 3000000
    const int B  = (n + NPB - 1) / NPB; // 782

    char* ws = (char*)d_ws;
    unsigned short* hwb   = (unsigned short*)(ws + 0);         // [n,64] bf16 -> 6.4M
    unsigned short* hwb2  = (unsigned short*)(ws + 6400000);   // [n,16] bf16 -> 8.0M
    unsigned short* R1b   = (unsigned short*)(ws + 8000000);   // [n,192] bf16 -> 27.2M
    unsigned short* ssrc1 = (unsigned short*)(ws + 27200000);  // [E1] -> 28.8M
    unsigned short* ssrc2 = (unsigned short*)(ws + 28800000);  // [E2] -> 34.8M
    unsigned int* ebuf1   = (unsigned int*)(ws + 34800000);    // [E1] -> 38.0M
    unsigned int* ebuf2   = (unsigned int*)(ws + 38000000);    // [E2] -> 50.0M
    float*        acc2a   = (float*)(ws + 50000000);           // [n,16] -> 53.2M
    float*        acc2b   = (float*)(ws + 53200000);           // [n,16] -> 56.4M
    int*          deg1    = (int*)(ws + 56400000);             // [n]
    int*          deg2    = (int*)(ws + 56600000);             // [n]
    float*        dinv1   = (float*)(ws + 56800000);           // [n]
    float*        dinv2   = (float*)(ws + 57000000);           // [n]
    int*          rs1     = (int*)(ws + 57200000);             // [n+1]
    int*          rs2     = (int*)(ws + 57400016);             // [n+1]
    int*          bhist1  = (int*)(ws + 58000032);             // [1024]
    int*          bhist2  = (int*)(ws + 58004128);             // [1024] (contiguous)
    int*          bbase1  = (int*)(ws + 58008224);             // [B+1]
    int*          bbase2  = (int*)(ws + 58012320);             // [B+1]
    int*          bcur1   = (int*)(ws + 58016416);             // [B]
    int*          bcur2   = (int*)(ws + 58020512);             // [B]

    hipMemsetAsync(bhist1, 0, 8192, stream);   // bhist1+bhist2, contiguous

    k_gemm1<<<(n + 15) / 16, 256, 0, stream>>>(x, w1, hwb, n);

    const int nbh1 = (E1 + HCHUNK - 1) / HCHUNK, nbh2 = (E2 + HCHUNK - 1) / HCHUNK;
    k_hist2<<<nbh1 + nbh2, 256, 0, stream>>>(ei + E1, bhist1, E1, nbh1,
                                             ei2 + E2, bhist2, E2);
    k_bscan<<<2, 64, 0, stream>>>(bhist1, bbase1, bcur1, bhist2, bbase2, bcur2, B);

    const int nbp1 = (E1 + CHUNK - 1) / CHUNK, nbp2 = (E2 + CHUNK - 1) / CHUNK;
    k_part2<<<nbp1 + nbp2, 256, 0, stream>>>(ei, ei + E1, bcur1, ebuf1, E1, nbp1,
                                             ei2, ei2 + E2, bcur2, ebuf2, E2);

    k_degbkt2<<<2 * B, 256, 0, stream>>>(bbase1, ebuf1, deg1, bbase2, ebuf2, deg2, B, n);
    k_scan2<<<2, 1024, 0, stream>>>(deg1, rs1, dinv1, deg2, rs2, dinv2, n);
    k_bucket22<<<2 * B, 256, 0, stream>>>(bbase1, ebuf1, rs1, ssrc1,
                                          bbase2, ebuf2, rs2, ssrc2, B, n);

    const int nba = (n * 8 + 255) / 256;
    k_agg1f<<<3 * nba, 256, 0, stream>>>(rs1, ssrc1, dinv1, rs2, ssrc2, dinv2,
                                         (const us8*)hwb, b1, R1b, n, nba);

    k_gemm2<<<(n + 15) / 16, 256, 0, stream>>>(R1b, w2, hwb2, n);

    const int nb16 = (n * 2 + 255) / 256;
    k_agg16f<<<2 * nb16, 256, 0, stream>>>(rs1, ssrc1, dinv1, acc2a,
                                           rs2, ssrc2, dinv2, acc2b,
                                           (const us8*)hwb2, n, nb16);

    k_final<<<(n + 15) / 16, 256, 0, stream>>>(hwb2, acc2a, acc2b, dinv1, dinv2, b2,
                                               lin_w, lin_b, (float*)d_out, n);
}

// Round 12
// 311.238 us; speedup vs baseline: 7.6862x; 1.0312x over previous
//
#include <hip/hip_runtime.h>
#include <math.h>

// x[50000,128] w1[128,64] b1[64] w2[192,16] b2[16] lin_w[48,16] lin_b[16]
// edge_index[2,800000] edge_index2[2,3000000] (int32, row0=src, row1=dst)
//
// R12 = R11 with (a) layer-1 gather table split into two 3.2MB halves
// (hwbA/hwbB), aggregation in two sequential passes so each pass's table is
// L2-resident per XCD (R11: 6.4MB table vs 4MB L2 -> 133MB FETCH, L2-capacity
// bound); (b) x8 unroll in layer-1 body; (c) scan2 folded into degbkt
// (rs = bbase[b] + in-bucket scan, dinv = rsqrt(cnt)) -- one kernel fewer.

#define NPB    64
#define CHUNK  8192
#define HCHUNK 16384

typedef unsigned short us8 __attribute__((ext_vector_type(8)));

__device__ inline float b2f(unsigned short u) {
    return __uint_as_float(((unsigned int)u) << 16);
}
// round-to-nearest-even f32 -> bf16 (finite values; matches __float2bfloat16)
__device__ inline unsigned short f2b(float f) {
    unsigned int u = __float_as_uint(f);
    u = (u + 0x7FFFu + ((u >> 16) & 1u)) >> 16;
    return (unsigned short)u;
}

// ------ GEMM1: hwbA = bf16(x@w1)[:, :32], hwbB = bf16(x@w1)[:, 32:] ------
__global__ void __launch_bounds__(256)
k_gemm1(const float* __restrict__ x, const float* __restrict__ w1,
        unsigned short* __restrict__ hwbA, unsigned short* __restrict__ hwbB, int n) {
    __shared__ float ws[128 * 64];   // 32 KB
    __shared__ float xs[16 * 128];   // 8 KB
    int t = threadIdx.x;
    for (int i = t; i < 128 * 64; i += 256) ws[i] = w1[i];
    int row0 = blockIdx.x * 16;
    for (int i = t; i < 16 * 128; i += 256) {
        int r = row0 + (i >> 7);
        xs[i] = (r < n) ? x[r * 128 + (i & 127)] : 0.f;
    }
    __syncthreads();
    int c = t & 63, rg = t >> 6;    // 4 rows per thread
    float a0 = 0.f, a1 = 0.f, a2 = 0.f, a3 = 0.f;
    const float* x0 = &xs[(rg * 4 + 0) * 128];
    const float* x1 = &xs[(rg * 4 + 1) * 128];
    const float* x2 = &xs[(rg * 4 + 2) * 128];
    const float* x3 = &xs[(rg * 4 + 3) * 128];
    #pragma unroll 8
    for (int k = 0; k < 128; ++k) {
        float wv = ws[k * 64 + c];
        a0 = fmaf(x0[k], wv, a0);
        a1 = fmaf(x1[k], wv, a1);
        a2 = fmaf(x2[k], wv, a2);
        a3 = fmaf(x3[k], wv, a3);
    }
    int r = row0 + rg * 4;
    unsigned short* tbl = (c < 32) ? hwbA : hwbB;
    int cc = c & 31;
    if (r + 0 < n) tbl[(r + 0) * 32 + cc] = f2b(a0);
    if (r + 1 < n) tbl[(r + 1) * 32 + cc] = f2b(a1);
    if (r + 2 < n) tbl[(r + 2) * 32 + cc] = f2b(a2);
    if (r + 3 < n) tbl[(r + 3) * 32 + cc] = f2b(a3);
}

// ------- fused bucket histogram, both edge sets (blockIdx split) -------
__global__ void k_hist2(const int* __restrict__ dstA, int* __restrict__ bhA, int EA, int nbA,
                        const int* __restrict__ dstB, int* __restrict__ bhB, int EB) {
    __shared__ int lh[1024];
    const int* dst; int* bh; int E; int cb;
    if ((int)blockIdx.x < nbA) { dst = dstA; bh = bhA; E = EA; cb = blockIdx.x; }
    else                       { dst = dstB; bh = bhB; E = EB; cb = blockIdx.x - nbA; }
    int t = threadIdx.x;
    for (int i = t; i < 1024; i += 256) lh[i] = 0;
    __syncthreads();
    int base = cb * HCHUNK;
    int cnt = min(HCHUNK, E - base);
    for (int i = t; i < cnt; i += 256) atomicAdd(&lh[dst[base + i] >> 6], 1);
    __syncthreads();
    for (int b = t; b < 1024; b += 256)
        if (lh[b]) atomicAdd(&bh[b], lh[b]);
}

// ------- scan bucket histograms -> bbase (exclusive) and bcur -------
__global__ void k_bscan(const int* __restrict__ bhA, int* __restrict__ bbA, int* __restrict__ bcA,
                        const int* __restrict__ bhB, int* __restrict__ bbB, int* __restrict__ bcB,
                        int B) {
    const int* bh = blockIdx.x ? bhB : bhA;
    int* bb = blockIdx.x ? bbB : bbA;
    int* bc = blockIdx.x ? bcB : bcA;
    int t = threadIdx.x;
    int carry = 0;
    int nch = (B + 63) >> 6;
    for (int c = 0; c < nch; ++c) {
        int idx = c * 64 + t;
        int v = (idx < B) ? bh[idx] : 0;
        int incl = v;
        #pragma unroll
        for (int off = 1; off < 64; off <<= 1) {
            int tv = __shfl_up(incl, off);
            if (t >= off) incl += tv;
        }
        if (idx < B) { bb[idx] = incl - v + carry; bc[idx] = incl - v + carry; }
        carry += __shfl(incl, 63);
    }
    if (t == 0) bb[B] = carry;
}

// ------- fused coarse partition, both edge sets (blockIdx split) -------
// packed word: src(16b) | dstlocal(6b)<<16 | bucket(10b)<<22 (stripped on write)
__global__ void __launch_bounds__(256)
k_part2(const int* __restrict__ srcA, const int* __restrict__ dstA,
        int* __restrict__ bcurA, unsigned int* __restrict__ outA, int EA, int nbA,
        const int* __restrict__ srcB, const int* __restrict__ dstB,
        int* __restrict__ bcurB, unsigned int* __restrict__ outB, int EB) {
    __shared__ int lh[1024];
    __shared__ int loff[1024];
    __shared__ int gof[1024];
    __shared__ int lcur[1024];
    __shared__ unsigned int stage[CHUNK];   // 32 KB -> 48 KB total -> 3 blocks/CU
    const int *src, *dst; int *bcur; unsigned int *out; int E, cb;
    if ((int)blockIdx.x < nbA) { src = srcA; dst = dstA; bcur = bcurA; out = outA; E = EA; cb = blockIdx.x; }
    else                       { src = srcB; dst = dstB; bcur = bcurB; out = outB; E = EB; cb = blockIdx.x - nbA; }
    int t = threadIdx.x;
    int base = cb * CHUNK;
    int cnt = min(CHUNK, E - base);
    for (int i = t; i < 1024; i += 256) lh[i] = 0;
    __syncthreads();
    for (int i = t; i < cnt; i += 256) atomicAdd(&lh[dst[base + i] >> 6], 1);
    __syncthreads();
    if (t < 64) {
        int carry = 0;
        #pragma unroll
        for (int c = 0; c < 16; ++c) {
            int idx = c * 64 + t;
            int v = lh[idx];
            int incl = v;
            #pragma unroll
            for (int off = 1; off < 64; off <<= 1) {
                int tv = __shfl_up(incl, off);
                if (t >= off) incl += tv;
            }
            loff[idx] = incl - v + carry;
            carry += __shfl(incl, 63);
        }
    }
    __syncthreads();
    for (int b = t; b < 1024; b += 256) {
        int c = lh[b];
        gof[b] = c ? atomicAdd(&bcur[b], c) : 0;
        lcur[b] = loff[b];
    }
    __syncthreads();
    for (int i = t; i < cnt; i += 256) {
        int d = dst[base + i];
        int s = src[base + i];
        int bkt = d >> 6;
        int p = atomicAdd(&lcur[bkt], 1);
        stage[p] = (unsigned int)s | ((unsigned int)(d & 63) << 16) |
                   ((unsigned int)bkt << 22);
    }
    __syncthreads();
    for (int i = t; i < cnt; i += 256) {
        unsigned int e = stage[i];
        int bkt = (int)(e >> 22);
        out[gof[bkt] + (i - loff[bkt])] = e & 0x3FFFFFu;
    }
}

// ------- per-bucket degree count + rowstart + dinv (scan2 folded in) -------
// rs[node] = bbase[b] + exclusive-scan of in-bucket counts; race-free: each
// block writes only its own 64 nodes. Block B-1 of each set writes rs[n]=E.
__global__ void __launch_bounds__(256)
k_degrs2(const int* __restrict__ bbaseA, const unsigned int* __restrict__ ebufA,
         int* __restrict__ rsA, float* __restrict__ dvA, int EA,
         const int* __restrict__ bbaseB, const unsigned int* __restrict__ ebufB,
         int* __restrict__ rsB, float* __restrict__ dvB, int EB, int B, int n) {
    __shared__ int cnt[64];
    const int* bbase; const unsigned int* ebuf; int* rs; float* dv; int b, Etot;
    if ((int)blockIdx.x < B) { bbase = bbaseA; ebuf = ebufA; rs = rsA; dv = dvA; b = blockIdx.x; Etot = EA; }
    else                     { bbase = bbaseB; ebuf = ebufB; rs = rsB; dv = dvB; b = blockIdx.x - B; Etot = EB; }
    int t = threadIdx.x;
    if (t < 64) cnt[t] = 0;
    __syncthreads();
    int beg = bbase[b], end = bbase[b + 1];
    for (int i = beg + t; i < end; i += 256)
        atomicAdd(&cnt[(ebuf[i] >> 16) & 63u], 1);
    __syncthreads();
    if (t < 64) {
        int v = cnt[t];
        int incl = v;
        #pragma unroll
        for (int off = 1; off < 64; off <<= 1) {
            int tv = __shfl_up(incl, off);
            if (t >= off) incl += tv;
        }
        int node = b * NPB + t;
        if (node < n) {
            rs[node] = beg + incl - v;
            dv[node] = (v > 0) ? rsqrtf((float)v) : 0.f;
        }
    }
    if (t == 0 && b == B - 1) rs[n] = Etot;
}

// ------- fused per-bucket scatter, both sets (cursors from global rs) -------
__global__ void __launch_bounds__(256)
k_bucket22(const int* __restrict__ bbaseA, const unsigned int* __restrict__ ebufA,
           const int* __restrict__ rsA, unsigned short* __restrict__ ssrcA,
           const int* __restrict__ bbaseB, const unsigned int* __restrict__ ebufB,
           const int* __restrict__ rsB, unsigned short* __restrict__ ssrcB, int B, int n) {
    __shared__ int lcur[64];
    const int *bbase, *rs; const unsigned int* ebuf; unsigned short* ssrc; int b;
    if ((int)blockIdx.x < B) { bbase = bbaseA; ebuf = ebufA; rs = rsA; ssrc = ssrcA; b = blockIdx.x; }
    else                     { bbase = bbaseB; ebuf = ebufB; rs = rsB; ssrc = ssrcB; b = blockIdx.x - B; }
    int t = threadIdx.x;
    if (t < 64) {
        int node = b * NPB + t;
        lcur[t] = (node < n) ? rs[node] : 0;
    }
    __syncthreads();
    int beg = bbase[b], end = bbase[b + 1];
    for (int i = beg + t; i < end; i += 256) {
        unsigned int e = ebuf[i];
        int p = atomicAdd(&lcur[(e >> 16) & 63u], 1);
        ssrc[p] = (unsigned short)(e & 0xFFFFu);
    }
}

// ------- x8-unrolled half-width (32-feat) gather body; tbl is [n][4] us8 -------
__device__ inline void agg32_body(const int* __restrict__ rs,
                                  const unsigned short* __restrict__ ssrc,
                                  const float* __restrict__ dinv,
                                  const us8* __restrict__ tbl,
                                  const float* __restrict__ b1h,
                                  unsigned short* __restrict__ R1b,
                                  int col_unit, int n, int tid) {
    int v = tid >> 2, q = tid & 3;
    if (v >= n) return;
    int beg = rs[v], end = rs[v + 1];
    float a[8] = {0.f, 0.f, 0.f, 0.f, 0.f, 0.f, 0.f, 0.f};
    int i = beg;
    for (; i + 8 <= end; i += 8) {   // 8 independent load chains -> MLP
        int s0 = ssrc[i + 0], s1 = ssrc[i + 1], s2 = ssrc[i + 2], s3 = ssrc[i + 3];
        int s4 = ssrc[i + 4], s5 = ssrc[i + 5], s6 = ssrc[i + 6], s7 = ssrc[i + 7];
        float c0 = dinv[s0], c1 = dinv[s1], c2 = dinv[s2], c3 = dinv[s3];
        float c4 = dinv[s4], c5 = dinv[s5], c6 = dinv[s6], c7 = dinv[s7];
        us8 h0 = tbl[s0 * 4 + q], h1 = tbl[s1 * 4 + q];
        us8 h2 = tbl[s2 * 4 + q], h3 = tbl[s3 * 4 + q];
        us8 h4 = tbl[s4 * 4 + q], h5 = tbl[s5 * 4 + q];
        us8 h6 = tbl[s6 * 4 + q], h7 = tbl[s7 * 4 + q];
        #pragma unroll
        for (int j = 0; j < 8; ++j) {
            a[j] = fmaf(b2f(h0[j]), c0, a[j]);
            a[j] = fmaf(b2f(h1[j]), c1, a[j]);
            a[j] = fmaf(b2f(h2[j]), c2, a[j]);
            a[j] = fmaf(b2f(h3[j]), c3, a[j]);
            a[j] = fmaf(b2f(h4[j]), c4, a[j]);
            a[j] = fmaf(b2f(h5[j]), c5, a[j]);
            a[j] = fmaf(b2f(h6[j]), c6, a[j]);
            a[j] = fmaf(b2f(h7[j]), c7, a[j]);
        }
    }
    for (; i < end; ++i) {
        int s = ssrc[i];
        float sc = dinv[s];
        us8 h = tbl[s * 4 + q];
        #pragma unroll
        for (int j = 0; j < 8; ++j) a[j] = fmaf(b2f(h[j]), sc, a[j]);
    }
    float dd = dinv[v];
    us8 o;
    #pragma unroll
    for (int j = 0; j < 8; ++j) {
        float r = fmaf(a[j], dd, b1h[q * 8 + j]);
        o[j] = f2b(r > 0.f ? r : 0.f);
    }
    ((us8*)&R1b[v * 192])[col_unit + q] = o;
}

// ------- layer-1 pass over ONE 32-feat half: E2 agg | E1 agg | self -------
// col units: set1 -> 0/4, set2 -> 8/12, self -> 16/20 (+baseUnit selects half)
__global__ void k_agg1p(const int* __restrict__ rs1, const unsigned short* __restrict__ ssrc1,
                        const float* __restrict__ dinv1,
                        const int* __restrict__ rs2, const unsigned short* __restrict__ ssrc2,
                        const float* __restrict__ dinv2,
                        const us8* __restrict__ tbl, const float* __restrict__ b1h,
                        unsigned short* __restrict__ R1b, int n, int nba, int baseUnit) {
    int bid = blockIdx.x;
    if (bid < nba) {                 // edge set 2 (the long pole) starts first
        agg32_body(rs2, ssrc2, dinv2, tbl, b1h, R1b, 8 + baseUnit, n,
                   bid * 256 + threadIdx.x);
    } else if (bid < 2 * nba) {      // edge set 1
        agg32_body(rs1, ssrc1, dinv1, tbl, b1h, R1b, 0 + baseUnit, n,
                   (bid - nba) * 256 + threadIdx.x);
    } else {                         // self branch
        int tid = (bid - 2 * nba) * 256 + threadIdx.x;
        int v = tid >> 2, q = tid & 3;
        if (v >= n) return;
        us8 h = tbl[v * 4 + q];
        us8 o;
        #pragma unroll
        for (int j = 0; j < 8; ++j) {
            float r = b2f(h[j]) + b1h[q * 8 + j];
            o[j] = f2b(r > 0.f ? r : 0.f);
        }
        ((us8*)&R1b[v * 192])[16 + baseUnit + q] = o;
    }
}

// ---------------- GEMM2: hwb2 = bf16(R1 @ w2)  ([n,192]@[192,16]) ----------------
__global__ void __launch_bounds__(256)
k_gemm2(const unsigned short* __restrict__ R1b, const float* __restrict__ w2,
        unsigned short* __restrict__ hwb2, int n) {
    __shared__ float ws[192 * 16];
    __shared__ float rs[16][193];
    int t = threadIdx.x;
    for (int i = t; i < 192 * 16; i += 256) ws[i] = w2[i];
    int row0 = blockIdx.x * 16;
    for (int i = t; i < 16 * 192; i += 256) {
        int r = i / 192, j = i - r * 192;
        int v = row0 + r;
        rs[r][j] = (v < n) ? b2f(R1b[v * 192 + j]) : 0.f;
    }
    __syncthreads();
    int r = t >> 4, c = t & 15;
    int v = row0 + r;
    if (v >= n) return;
    float acc = 0.f;
    #pragma unroll 8
    for (int j = 0; j < 192; ++j) acc += rs[r][j] * ws[j * 16 + c];
    hwb2[v * 16 + c] = f2b(acc);
}

// ------- x4-unrolled layer-2 gather body (hwb2 = 1.6MB, already L2-fit) -------
__device__ inline void agg16_body(const int* __restrict__ rs,
                                  const unsigned short* __restrict__ ssrc,
                                  const float* __restrict__ dinv,
                                  const us8* __restrict__ hwb2_8,
                                  float* __restrict__ acc2, int n, int tid) {
    int v = tid >> 1, q = tid & 1;
    if (v >= n) return;
    int beg = rs[v], end = rs[v + 1];
    float a[8] = {0.f, 0.f, 0.f, 0.f, 0.f, 0.f, 0.f, 0.f};
    int i = beg;
    for (; i + 4 <= end; i += 4) {
        int s0 = ssrc[i + 0], s1 = ssrc[i + 1], s2 = ssrc[i + 2], s3 = ssrc[i + 3];
        float c0 = dinv[s0], c1 = dinv[s1], c2 = dinv[s2], c3 = dinv[s3];
        us8 h0 = hwb2_8[s0 * 2 + q], h1 = hwb2_8[s1 * 2 + q];
        us8 h2 = hwb2_8[s2 * 2 + q], h3 = hwb2_8[s3 * 2 + q];
        #pragma unroll
        for (int j = 0; j < 8; ++j) {
            a[j] = fmaf(b2f(h0[j]), c0, a[j]);
            a[j] = fmaf(b2f(h1[j]), c1, a[j]);
            a[j] = fmaf(b2f(h2[j]), c2, a[j]);
            a[j] = fmaf(b2f(h3[j]), c3, a[j]);
        }
    }
    for (; i < end; ++i) {
        int s = ssrc[i];
        float sc = dinv[s];
        us8 h = hwb2_8[s * 2 + q];
        #pragma unroll
        for (int j = 0; j < 8; ++j) a[j] = fmaf(b2f(h[j]), sc, a[j]);
    }
    float4* o = (float4*)&acc2[v * 16 + q * 8];
    o[0] = make_float4(a[0], a[1], a[2], a[3]);
    o[1] = make_float4(a[4], a[5], a[6], a[7]);
}

// ------- fused layer-2 aggregate: E2 -> acc2b first, then E1 -> acc2a -------
__global__ void k_agg16f(const int* __restrict__ rs1, const unsigned short* __restrict__ ssrc1,
                         const float* __restrict__ dinv1, float* __restrict__ acc2a,
                         const int* __restrict__ rs2, const unsigned short* __restrict__ ssrc2,
                         const float* __restrict__ dinv2, float* __restrict__ acc2b,
                         const us8* __restrict__ hwb2_8, int n, int nba) {
    int bid = blockIdx.x;
    if (bid < nba)
        agg16_body(rs2, ssrc2, dinv2, hwb2_8, acc2b, n, bid * 256 + threadIdx.x);
    else
        agg16_body(rs1, ssrc1, dinv1, hwb2_8, acc2a, n, (bid - nba) * 256 + threadIdx.x);
}

// ------- final: combine layer-2 branches, linear head, log_softmax ----------
__global__ void k_final(const unsigned short* __restrict__ hwb2,
                        const float* __restrict__ acc2a, const float* __restrict__ acc2b,
                        const float* __restrict__ dinv1, const float* __restrict__ dinv2,
                        const float* __restrict__ b2, const float* __restrict__ lw,
                        const float* __restrict__ lb, float* __restrict__ out, int n) {
    __shared__ float lws[48 * 16];
    __shared__ float r2s[16][49];
    int t = threadIdx.x;
    for (int i = t; i < 48 * 16; i += 256) lws[i] = lw[i];
    int ni = t >> 4, c = t & 15;
    int v = blockIdx.x * 16 + ni;
    if (v < n) {
        float bb = b2[c];
        r2s[ni][c]      = fmaf(dinv1[v], acc2a[v * 16 + c], bb);
        r2s[ni][16 + c] = fmaf(dinv2[v], acc2b[v * 16 + c], bb);
        r2s[ni][32 + c] = b2f(hwb2[v * 16 + c]) + bb;
    }
    __syncthreads();
    if (v >= n) return;
    float o = lb[c];
    #pragma unroll
    for (int j = 0; j < 48; ++j) o += r2s[ni][j] * lws[j * 16 + c];
    float m = o;
    for (int off = 8; off >= 1; off >>= 1) m = fmaxf(m, __shfl_xor(m, off, 16));
    float e = expf(o - m);
    float ssum = e;
    for (int off = 8; off >= 1; off >>= 1) ssum += __shfl_xor(ssum, off, 16);
    out[v * 16 + c] = (o - m) - logf(ssum);
}

extern "C" void kernel_launch(void* const* d_in, const int* in_sizes, int n_in,
                              void* d_out, int out_size, void* d_ws, size_t ws_size,
                              hipStream_t stream) {
    const float* x     = (const float*)d_in[0];
    const float* w1    = (const float*)d_in[1];
    const float* b1    = (const float*)d_in[2];
    const float* w2    = (const float*)d_in[3];
    const float* b2    = (const float*)d_in[4];
    const float* lin_w = (const float*)d_in[5];
    const float* lin_b = (const float*)d_in[6];
    const int*   ei    = (const int*)d_in[7];
    const int*   ei2   = (const int*)d_in[8];

    const int n  = in_sizes[0] / 128;   // 50000
    const int E1 = in_sizes[7] / 2;     // 800000
    const int E2 = in_sizes[8] / 2;     // 3000000
    const int B  = (n + NPB - 1) / NPB; // 782

    char* ws = (char*)d_ws;
    unsigned short* hwbA  = (unsigned short*)(ws + 0);         // [n,32] bf16 -> 3.2M
    unsigned short* hwbB  = (unsigned short*)(ws + 3200000);   // [n,32] bf16 -> 6.4M
    unsigned short* hwb2  = (unsigned short*)(ws + 6400000);   // [n,16] bf16 -> 8.0M
    unsigned short* R1b   = (unsigned short*)(ws + 8000000);   // [n,192] bf16 -> 27.2M
    unsigned short* ssrc1 = (unsigned short*)(ws + 27200000);  // [E1] -> 28.8M
    unsigned short* ssrc2 = (unsigned short*)(ws + 28800000);  // [E2] -> 34.8M
    unsigned int* ebuf1   = (unsigned int*)(ws + 34800000);    // [E1] -> 38.0M
    unsigned int* ebuf2   = (unsigned int*)(ws + 38000000);    // [E2] -> 50.0M
    float*        acc2a   = (float*)(ws + 50000000);           // [n,16] -> 53.2M
    float*        acc2b   = (float*)(ws + 53200000);           // [n,16] -> 56.4M
    float*        dinv1   = (float*)(ws + 56800000);           // [n]
    float*        dinv2   = (float*)(ws + 57000000);           // [n]
    int*          rs1     = (int*)(ws + 57200000);             // [n+1]
    int*          rs2     = (int*)(ws + 57400016);             // [n+1]
    int*          bhist1  = (int*)(ws + 58000032);             // [1024]
    int*          bhist2  = (int*)(ws + 58004128);             // [1024] (contiguous)
    int*          bbase1  = (int*)(ws + 58008224);             // [B+1]
    int*          bbase2  = (int*)(ws + 58012320);             // [B+1]
    int*          bcur1   = (int*)(ws + 58016416);             // [B]
    int*          bcur2   = (int*)(ws + 58020512);             // [B]

    hipMemsetAsync(bhist1, 0, 8192, stream);   // bhist1+bhist2, contiguous

    k_gemm1<<<(n + 15) / 16, 256, 0, stream>>>(x, w1, hwbA, hwbB, n);

    const int nbh1 = (E1 + HCHUNK - 1) / HCHUNK, nbh2 = (E2 + HCHUNK - 1) / HCHUNK;
    k_hist2<<<nbh1 + nbh2, 256, 0, stream>>>(ei + E1, bhist1, E1, nbh1,
                                             ei2 + E2, bhist2, E2);
    k_bscan<<<2, 64, 0, stream>>>(bhist1, bbase1, bcur1, bhist2, bbase2, bcur2, B);

    const int nbp1 = (E1 + CHUNK - 1) / CHUNK, nbp2 = (E2 + CHUNK - 1) / CHUNK;
    k_part2<<<nbp1 + nbp2, 256, 0, stream>>>(ei, ei + E1, bcur1, ebuf1, E1, nbp1,
                                             ei2, ei2 + E2, bcur2, ebuf2, E2);

    k_degrs2<<<2 * B, 256, 0, stream>>>(bbase1, ebuf1, rs1, dinv1, E1,
                                        bbase2, ebuf2, rs2, dinv2, E2, B, n);
    k_bucket22<<<2 * B, 256, 0, stream>>>(bbase1, ebuf1, rs1, ssrc1,
                                          bbase2, ebuf2, rs2, ssrc2, B, n);

    const int nba = (n * 4 + 255) / 256;
    // pass A: feats [0,32) from hwbA (3.2MB, L2-resident); pass B: [32,64)
    k_agg1p<<<3 * nba, 256, 0, stream>>>(rs1, ssrc1, dinv1, rs2, ssrc2, dinv2,
                                         (const us8*)hwbA, b1, R1b, n, nba, 0);
    k_agg1p<<<3 * nba, 256, 0, stream>>>(rs1, ssrc1, dinv1, rs2, ssrc2, dinv2,
                                         (const us8*)hwbB, b1 + 32, R1b, n, nba, 4);

    k_gemm2<<<(n + 15) / 16, 256, 0, stream>>>(R1b, w2, hwb2, n);

    const int nb16 = (n * 2 + 255) / 256;
    k_agg16f<<<2 * nb16, 256, 0, stream>>>(rs1, ssrc1, dinv1, acc2a,
                                           rs2, ssrc2, dinv2, acc2b,
                                           (const us8*)hwb2, n, nb16);

    k_final<<<(n + 15) / 16, 256, 0, stream>>>(hwb2, acc2a, acc2b, dinv1, dinv2, b2,
                                               lin_w, lin_b, (float*)d_out, n);
}

// Round 13
// 307.463 us; speedup vs baseline: 7.7806x; 1.0123x over previous
//
#include <hip/hip_runtime.h>
#include <math.h>

// x[50000,128] w1[128,64] b1[64] w2[192,16] b2[16] lin_w[48,16] lin_b[16]
// edge_index[2,800000] edge_index2[2,3000000] (int32, row0=src, row1=dst)
//
// R13 = R12 with (a) part2 CHUNK 4096 (32KB LDS -> 5 blocks/CU; was 13.8% occ),
// (b) gemm1+hist2 fused into one launch (independent work, hist hides under
// gemm), (c) degrs2+bucket22 fused into k_csr2 (same per-block mapping; one
// ebuf pass instead of two), (d) agg16 unroll x8.

#define NPB    64
#define CHUNK  4096
#define HCHUNK 16384

typedef unsigned short us8 __attribute__((ext_vector_type(8)));

__device__ inline float b2f(unsigned short u) {
    return __uint_as_float(((unsigned int)u) << 16);
}
// round-to-nearest-even f32 -> bf16 (finite values; matches __float2bfloat16)
__device__ inline unsigned short f2b(float f) {
    unsigned int u = __float_as_uint(f);
    u = (u + 0x7FFFu + ((u >> 16) & 1u)) >> 16;
    return (unsigned short)u;
}

// ------ fused GEMM1 + bucket-histograms (blockIdx ranges) ------
// blocks [0,nbg): hwbA/hwbB = bf16(x@w1) halves; [nbg,nbg+nbh1): hist set1;
// [nbg+nbh1, nbg+nbh1+nbh2): hist set2. 40KB shared union.
__global__ void __launch_bounds__(256)
k_g1h(const float* __restrict__ x, const float* __restrict__ w1,
      unsigned short* __restrict__ hwbA, unsigned short* __restrict__ hwbB, int n, int nbg,
      const int* __restrict__ dst1, int* __restrict__ bh1, int E1, int nbh1,
      const int* __restrict__ dst2, int* __restrict__ bh2, int E2) {
    __shared__ float smem[128 * 64 + 16 * 128];   // 40 KB
    int bid = blockIdx.x;
    int t = threadIdx.x;
    if (bid < nbg) {
        // ---- GEMM1 body ----
        float* ws = smem;                 // [128*64]
        float* xs = smem + 128 * 64;      // [16*128]
        for (int i = t; i < 128 * 64; i += 256) ws[i] = w1[i];
        int row0 = bid * 16;
        for (int i = t; i < 16 * 128; i += 256) {
            int r = row0 + (i >> 7);
            xs[i] = (r < n) ? x[r * 128 + (i & 127)] : 0.f;
        }
        __syncthreads();
        int c = t & 63, rg = t >> 6;
        float a0 = 0.f, a1 = 0.f, a2 = 0.f, a3 = 0.f;
        const float* x0 = &xs[(rg * 4 + 0) * 128];
        const float* x1 = &xs[(rg * 4 + 1) * 128];
        const float* x2 = &xs[(rg * 4 + 2) * 128];
        const float* x3 = &xs[(rg * 4 + 3) * 128];
        #pragma unroll 8
        for (int k = 0; k < 128; ++k) {
            float wv = ws[k * 64 + c];
            a0 = fmaf(x0[k], wv, a0);
            a1 = fmaf(x1[k], wv, a1);
            a2 = fmaf(x2[k], wv, a2);
            a3 = fmaf(x3[k], wv, a3);
        }
        int r = row0 + rg * 4;
        unsigned short* tbl = (c < 32) ? hwbA : hwbB;
        int cc = c & 31;
        if (r + 0 < n) tbl[(r + 0) * 32 + cc] = f2b(a0);
        if (r + 1 < n) tbl[(r + 1) * 32 + cc] = f2b(a1);
        if (r + 2 < n) tbl[(r + 2) * 32 + cc] = f2b(a2);
        if (r + 3 < n) tbl[(r + 3) * 32 + cc] = f2b(a3);
    } else {
        // ---- histogram body ----
        int* lh = (int*)smem;             // [1024]
        const int* dst; int* bh; int E; int cb;
        int hb = bid - nbg;
        if (hb < nbh1) { dst = dst1; bh = bh1; E = E1; cb = hb; }
        else           { dst = dst2; bh = bh2; E = E2; cb = hb - nbh1; }
        for (int i = t; i < 1024; i += 256) lh[i] = 0;
        __syncthreads();
        int base = cb * HCHUNK;
        int cnt = min(HCHUNK, E - base);
        for (int i = t; i < cnt; i += 256) atomicAdd(&lh[dst[base + i] >> 6], 1);
        __syncthreads();
        for (int b = t; b < 1024; b += 256)
            if (lh[b]) atomicAdd(&bh[b], lh[b]);
    }
}

// ------- scan bucket histograms -> bbase (exclusive) and bcur -------
__global__ void k_bscan(const int* __restrict__ bhA, int* __restrict__ bbA, int* __restrict__ bcA,
                        const int* __restrict__ bhB, int* __restrict__ bbB, int* __restrict__ bcB,
                        int B) {
    const int* bh = blockIdx.x ? bhB : bhA;
    int* bb = blockIdx.x ? bbB : bbA;
    int* bc = blockIdx.x ? bcB : bcA;
    int t = threadIdx.x;
    int carry = 0;
    int nch = (B + 63) >> 6;
    for (int c = 0; c < nch; ++c) {
        int idx = c * 64 + t;
        int v = (idx < B) ? bh[idx] : 0;
        int incl = v;
        #pragma unroll
        for (int off = 1; off < 64; off <<= 1) {
            int tv = __shfl_up(incl, off);
            if (t >= off) incl += tv;
        }
        if (idx < B) { bb[idx] = incl - v + carry; bc[idx] = incl - v + carry; }
        carry += __shfl(incl, 63);
    }
    if (t == 0) bb[B] = carry;
}

// ------- fused coarse partition, both edge sets (blockIdx split) -------
// packed word: src(16b) | dstlocal(6b)<<16 | bucket(10b)<<22 (stripped on write)
__global__ void __launch_bounds__(256)
k_part2(const int* __restrict__ srcA, const int* __restrict__ dstA,
        int* __restrict__ bcurA, unsigned int* __restrict__ outA, int EA, int nbA,
        const int* __restrict__ srcB, const int* __restrict__ dstB,
        int* __restrict__ bcurB, unsigned int* __restrict__ outB, int EB) {
    __shared__ int lh[1024];
    __shared__ int loff[1024];
    __shared__ int gof[1024];
    __shared__ int lcur[1024];
    __shared__ unsigned int stage[CHUNK];   // 16 KB -> 32 KB total -> 5 blocks/CU
    const int *src, *dst; int *bcur; unsigned int *out; int E, cb;
    if ((int)blockIdx.x < nbA) { src = srcA; dst = dstA; bcur = bcurA; out = outA; E = EA; cb = blockIdx.x; }
    else                       { src = srcB; dst = dstB; bcur = bcurB; out = outB; E = EB; cb = blockIdx.x - nbA; }
    int t = threadIdx.x;
    int base = cb * CHUNK;
    int cnt = min(CHUNK, E - base);
    for (int i = t; i < 1024; i += 256) lh[i] = 0;
    __syncthreads();
    for (int i = t; i < cnt; i += 256) atomicAdd(&lh[dst[base + i] >> 6], 1);
    __syncthreads();
    if (t < 64) {
        int carry = 0;
        #pragma unroll
        for (int c = 0; c < 16; ++c) {
            int idx = c * 64 + t;
            int v = lh[idx];
            int incl = v;
            #pragma unroll
            for (int off = 1; off < 64; off <<= 1) {
                int tv = __shfl_up(incl, off);
                if (t >= off) incl += tv;
            }
            loff[idx] = incl - v + carry;
            carry += __shfl(incl, 63);
        }
    }
    __syncthreads();
    for (int b = t; b < 1024; b += 256) {
        int c = lh[b];
        gof[b] = c ? atomicAdd(&bcur[b], c) : 0;
        lcur[b] = loff[b];
    }
    __syncthreads();
    for (int i = t; i < cnt; i += 256) {
        int d = dst[base + i];
        int s = src[base + i];
        int bkt = d >> 6;
        int p = atomicAdd(&lcur[bkt], 1);
        stage[p] = (unsigned int)s | ((unsigned int)(d & 63) << 16) |
                   ((unsigned int)bkt << 22);
    }
    __syncthreads();
    for (int i = t; i < cnt; i += 256) {
        unsigned int e = stage[i];
        int bkt = (int)(e >> 22);
        out[gof[bkt] + (i - loff[bkt])] = e & 0x3FFFFFu;
    }
}

// ------- fused CSR build: deg count + scan -> rs/dinv, then in-window scatter ----
// (degrs2 + bucket22 merged: block b writes/uses only nodes [b*64, b*64+64).)
__global__ void __launch_bounds__(256)
k_csr2(const int* __restrict__ bbaseA, const unsigned int* __restrict__ ebufA,
       int* __restrict__ rsA, float* __restrict__ dvA, unsigned short* __restrict__ ssrcA, int EA,
       const int* __restrict__ bbaseB, const unsigned int* __restrict__ ebufB,
       int* __restrict__ rsB, float* __restrict__ dvB, unsigned short* __restrict__ ssrcB, int EB,
       int B, int n) {
    __shared__ int cnt[64];
    __shared__ int lcur[64];
    const int* bbase; const unsigned int* ebuf; int* rs; float* dv;
    unsigned short* ssrc; int b, Etot;
    if ((int)blockIdx.x < B) { bbase = bbaseA; ebuf = ebufA; rs = rsA; dv = dvA; ssrc = ssrcA; b = blockIdx.x; Etot = EA; }
    else                     { bbase = bbaseB; ebuf = ebufB; rs = rsB; dv = dvB; ssrc = ssrcB; b = blockIdx.x - B; Etot = EB; }
    int t = threadIdx.x;
    if (t < 64) cnt[t] = 0;
    __syncthreads();
    int beg = bbase[b], end = bbase[b + 1];
    for (int i = beg + t; i < end; i += 256)
        atomicAdd(&cnt[(ebuf[i] >> 16) & 63u], 1);
    __syncthreads();
    if (t < 64) {
        int v = cnt[t];
        int incl = v;
        #pragma unroll
        for (int off = 1; off < 64; off <<= 1) {
            int tv = __shfl_up(incl, off);
            if (t >= off) incl += tv;
        }
        int start = beg + incl - v;
        lcur[t] = start;
        int node = b * NPB + t;
        if (node < n) {
            rs[node] = start;
            dv[node] = (v > 0) ? rsqrtf((float)v) : 0.f;
        }
    }
    __syncthreads();
    for (int i = beg + t; i < end; i += 256) {
        unsigned int e = ebuf[i];
        int p = atomicAdd(&lcur[(e >> 16) & 63u], 1);
        ssrc[p] = (unsigned short)(e & 0xFFFFu);
    }
    if (t == 0 && b == B - 1) rs[n] = Etot;
}

// ------- x8-unrolled half-width (32-feat) gather body; tbl is [n][4] us8 -------
__device__ inline void agg32_body(const int* __restrict__ rs,
                                  const unsigned short* __restrict__ ssrc,
                                  const float* __restrict__ dinv,
                                  const us8* __restrict__ tbl,
                                  const float* __restrict__ b1h,
                                  unsigned short* __restrict__ R1b,
                                  int col_unit, int n, int tid) {
    int v = tid >> 2, q = tid & 3;
    if (v >= n) return;
    int beg = rs[v], end = rs[v + 1];
    float a[8] = {0.f, 0.f, 0.f, 0.f, 0.f, 0.f, 0.f, 0.f};
    int i = beg;
    for (; i + 8 <= end; i += 8) {   // 8 independent load chains -> MLP
        int s0 = ssrc[i + 0], s1 = ssrc[i + 1], s2 = ssrc[i + 2], s3 = ssrc[i + 3];
        int s4 = ssrc[i + 4], s5 = ssrc[i + 5], s6 = ssrc[i + 6], s7 = ssrc[i + 7];
        float c0 = dinv[s0], c1 = dinv[s1], c2 = dinv[s2], c3 = dinv[s3];
        float c4 = dinv[s4], c5 = dinv[s5], c6 = dinv[s6], c7 = dinv[s7];
        us8 h0 = tbl[s0 * 4 + q], h1 = tbl[s1 * 4 + q];
        us8 h2 = tbl[s2 * 4 + q], h3 = tbl[s3 * 4 + q];
        us8 h4 = tbl[s4 * 4 + q], h5 = tbl[s5 * 4 + q];
        us8 h6 = tbl[s6 * 4 + q], h7 = tbl[s7 * 4 + q];
        #pragma unroll
        for (int j = 0; j < 8; ++j) {
            a[j] = fmaf(b2f(h0[j]), c0, a[j]);
            a[j] = fmaf(b2f(h1[j]), c1, a[j]);
            a[j] = fmaf(b2f(h2[j]), c2, a[j]);
            a[j] = fmaf(b2f(h3[j]), c3, a[j]);
            a[j] = fmaf(b2f(h4[j]), c4, a[j]);
            a[j] = fmaf(b2f(h5[j]), c5, a[j]);
            a[j] = fmaf(b2f(h6[j]), c6, a[j]);
            a[j] = fmaf(b2f(h7[j]), c7, a[j]);
        }
    }
    for (; i < end; ++i) {
        int s = ssrc[i];
        float sc = dinv[s];
        us8 h = tbl[s * 4 + q];
        #pragma unroll
        for (int j = 0; j < 8; ++j) a[j] = fmaf(b2f(h[j]), sc, a[j]);
    }
    float dd = dinv[v];
    us8 o;
    #pragma unroll
    for (int j = 0; j < 8; ++j) {
        float r = fmaf(a[j], dd, b1h[q * 8 + j]);
        o[j] = f2b(r > 0.f ? r : 0.f);
    }
    ((us8*)&R1b[v * 192])[col_unit + q] = o;
}

// ------- layer-1 pass over ONE 32-feat half: E2 agg | E1 agg | self -------
__global__ void k_agg1p(const int* __restrict__ rs1, const unsigned short* __restrict__ ssrc1,
                        const float* __restrict__ dinv1,
                        const int* __restrict__ rs2, const unsigned short* __restrict__ ssrc2,
                        const float* __restrict__ dinv2,
                        const us8* __restrict__ tbl, const float* __restrict__ b1h,
                        unsigned short* __restrict__ R1b, int n, int nba, int baseUnit) {
    int bid = blockIdx.x;
    if (bid < nba) {                 // edge set 2 (the long pole) starts first
        agg32_body(rs2, ssrc2, dinv2, tbl, b1h, R1b, 8 + baseUnit, n,
                   bid * 256 + threadIdx.x);
    } else if (bid < 2 * nba) {      // edge set 1
        agg32_body(rs1, ssrc1, dinv1, tbl, b1h, R1b, 0 + baseUnit, n,
                   (bid - nba) * 256 + threadIdx.x);
    } else {                         // self branch
        int tid = (bid - 2 * nba) * 256 + threadIdx.x;
        int v = tid >> 2, q = tid & 3;
        if (v >= n) return;
        us8 h = tbl[v * 4 + q];
        us8 o;
        #pragma unroll
        for (int j = 0; j < 8; ++j) {
            float r = b2f(h[j]) + b1h[q * 8 + j];
            o[j] = f2b(r > 0.f ? r : 0.f);
        }
        ((us8*)&R1b[v * 192])[16 + baseUnit + q] = o;
    }
}

// ---------------- GEMM2: hwb2 = bf16(R1 @ w2)  ([n,192]@[192,16]) ----------------
__global__ void __launch_bounds__(256)
k_gemm2(const unsigned short* __restrict__ R1b, const float* __restrict__ w2,
        unsigned short* __restrict__ hwb2, int n) {
    __shared__ float ws[192 * 16];
    __shared__ float rs[16][193];
    int t = threadIdx.x;
    for (int i = t; i < 192 * 16; i += 256) ws[i] = w2[i];
    int row0 = blockIdx.x * 16;
    for (int i = t; i < 16 * 192; i += 256) {
        int r = i / 192, j = i - r * 192;
        int v = row0 + r;
        rs[r][j] = (v < n) ? b2f(R1b[v * 192 + j]) : 0.f;
    }
    __syncthreads();
    int r = t >> 4, c = t & 15;
    int v = row0 + r;
    if (v >= n) return;
    float acc = 0.f;
    #pragma unroll 8
    for (int j = 0; j < 192; ++j) acc += rs[r][j] * ws[j * 16 + c];
    hwb2[v * 16 + c] = f2b(acc);
}

// ------- x8-unrolled layer-2 gather body (hwb2 = 1.6MB, L2-fit) -------
__device__ inline void agg16_body(const int* __restrict__ rs,
                                  const unsigned short* __restrict__ ssrc,
                                  const float* __restrict__ dinv,
                                  const us8* __restrict__ hwb2_8,
                                  float* __restrict__ acc2, int n, int tid) {
    int v = tid >> 1, q = tid & 1;
    if (v >= n) return;
    int beg = rs[v], end = rs[v + 1];
    float a[8] = {0.f, 0.f, 0.f, 0.f, 0.f, 0.f, 0.f, 0.f};
    int i = beg;
    for (; i + 8 <= end; i += 8) {
        int s0 = ssrc[i + 0], s1 = ssrc[i + 1], s2 = ssrc[i + 2], s3 = ssrc[i + 3];
        int s4 = ssrc[i + 4], s5 = ssrc[i + 5], s6 = ssrc[i + 6], s7 = ssrc[i + 7];
        float c0 = dinv[s0], c1 = dinv[s1], c2 = dinv[s2], c3 = dinv[s3];
        float c4 = dinv[s4], c5 = dinv[s5], c6 = dinv[s6], c7 = dinv[s7];
        us8 h0 = hwb2_8[s0 * 2 + q], h1 = hwb2_8[s1 * 2 + q];
        us8 h2 = hwb2_8[s2 * 2 + q], h3 = hwb2_8[s3 * 2 + q];
        us8 h4 = hwb2_8[s4 * 2 + q], h5 = hwb2_8[s5 * 2 + q];
        us8 h6 = hwb2_8[s6 * 2 + q], h7 = hwb2_8[s7 * 2 + q];
        #pragma unroll
        for (int j = 0; j < 8; ++j) {
            a[j] = fmaf(b2f(h0[j]), c0, a[j]);
            a[j] = fmaf(b2f(h1[j]), c1, a[j]);
            a[j] = fmaf(b2f(h2[j]), c2, a[j]);
            a[j] = fmaf(b2f(h3[j]), c3, a[j]);
            a[j] = fmaf(b2f(h4[j]), c4, a[j]);
            a[j] = fmaf(b2f(h5[j]), c5, a[j]);
            a[j] = fmaf(b2f(h6[j]), c6, a[j]);
            a[j] = fmaf(b2f(h7[j]), c7, a[j]);
        }
    }
    for (; i < end; ++i) {
        int s = ssrc[i];
        float sc = dinv[s];
        us8 h = hwb2_8[s * 2 + q];
        #pragma unroll
        for (int j = 0; j < 8; ++j) a[j] = fmaf(b2f(h[j]), sc, a[j]);
    }
    float4* o = (float4*)&acc2[v * 16 + q * 8];
    o[0] = make_float4(a[0], a[1], a[2], a[3]);
    o[1] = make_float4(a[4], a[5], a[6], a[7]);
}

// ------- fused layer-2 aggregate: E2 -> acc2b first, then E1 -> acc2a -------
__global__ void k_agg16f(const int* __restrict__ rs1, const unsigned short* __restrict__ ssrc1,
                         const float* __restrict__ dinv1, float* __restrict__ acc2a,
                         const int* __restrict__ rs2, const unsigned short* __restrict__ ssrc2,
                         const float* __restrict__ dinv2, float* __restrict__ acc2b,
                         const us8* __restrict__ hwb2_8, int n, int nba) {
    int bid = blockIdx.x;
    if (bid < nba)
        agg16_body(rs2, ssrc2, dinv2, hwb2_8, acc2b, n, bid * 256 + threadIdx.x);
    else
        agg16_body(rs1, ssrc1, dinv1, hwb2_8, acc2a, n, (bid - nba) * 256 + threadIdx.x);
}

// ------- final: combine layer-2 branches, linear head, log_softmax ----------
__global__ void k_final(const unsigned short* __restrict__ hwb2,
                        const float* __restrict__ acc2a, const float* __restrict__ acc2b,
                        const float* __restrict__ dinv1, const float* __restrict__ dinv2,
                        const float* __restrict__ b2, const float* __restrict__ lw,
                        const float* __restrict__ lb, float* __restrict__ out, int n) {
    __shared__ float lws[48 * 16];
    __shared__ float r2s[16][49];
    int t = threadIdx.x;
    for (int i = t; i < 48 * 16; i += 256) lws[i] = lw[i];
    int ni = t >> 4, c = t & 15;
    int v = blockIdx.x * 16 + ni;
    if (v < n) {
        float bb = b2[c];
        r2s[ni][c]      = fmaf(dinv1[v], acc2a[v * 16 + c], bb);
        r2s[ni][16 + c] = fmaf(dinv2[v], acc2b[v * 16 + c], bb);
        r2s[ni][32 + c] = b2f(hwb2[v * 16 + c]) + bb;
    }
    __syncthreads();
    if (v >= n) return;
    float o = lb[c];
    #pragma unroll
    for (int j = 0; j < 48; ++j) o += r2s[ni][j] * lws[j * 16 + c];
    float m = o;
    for (int off = 8; off >= 1; off >>= 1) m = fmaxf(m, __shfl_xor(m, off, 16));
    float e = expf(o - m);
    float ssum = e;
    for (int off = 8; off >= 1; off >>= 1) ssum += __shfl_xor(ssum, off, 16);
    out[v * 16 + c] = (o - m) - logf(ssum);
}

extern "C" void kernel_launch(void* const* d_in, const int* in_sizes, int n_in,
                              void* d_out, int out_size, void* d_ws, size_t ws_size,
                              hipStream_t stream) {
    const float* x     = (const float*)d_in[0];
    const float* w1    = (const float*)d_in[1];
    const float* b1    = (const float*)d_in[2];
    const float* w2    = (const float*)d_in[3];
    const float* b2    = (const float*)d_in[4];
    const float* lin_w = (const float*)d_in[5];
    const float* lin_b = (const float*)d_in[6];
    const int*   ei    = (const int*)d_in[7];
    const int*   ei2   = (const int*)d_in[8];

    const int n  = in_sizes[0] / 128;   // 50000
    const int E1 = in_sizes[7] / 2;     // 800000
    const int E2 = in_sizes[8] / 2;     // 3000000
    const int B  = (n + NPB - 1) / NPB; // 782

    char* ws = (char*)d_ws;
    unsigned short* hwbA  = (unsigned short*)(ws + 0);         // [n,32] bf16 -> 3.2M
    unsigned short* hwbB  = (unsigned short*)(ws + 3200000);   // [n,32] bf16 -> 6.4M
    unsigned short* hwb2  = (unsigned short*)(ws + 6400000);   // [n,16] bf16 -> 8.0M
    unsigned short* R1b   = (unsigned short*)(ws + 8000000);   // [n,192] bf16 -> 27.2M
    unsigned short* ssrc1 = (unsigned short*)(ws + 27200000);  // [E1] -> 28.8M
    unsigned short* ssrc2 = (unsigned short*)(ws + 28800000);  // [E2] -> 34.8M
    unsigned int* ebuf1   = (unsigned int*)(ws + 34800000);    // [E1] -> 38.0M
    unsigned int* ebuf2   = (unsigned int*)(ws + 38000000);    // [E2] -> 50.0M
    float*        acc2a   = (float*)(ws + 50000000);           // [n,16] -> 53.2M
    float*        acc2b   = (float*)(ws + 53200000);           // [n,16] -> 56.4M
    float*        dinv1   = (float*)(ws + 56800000);           // [n]
    float*        dinv2   = (float*)(ws + 57000000);           // [n]
    int*          rs1     = (int*)(ws + 57200000);             // [n+1]
    int*          rs2     = (int*)(ws + 57400016);             // [n+1]
    int*          bhist1  = (int*)(ws + 58000032);             // [1024]
    int*          bhist2  = (int*)(ws + 58004128);             // [1024] (contiguous)
    int*          bbase1  = (int*)(ws + 58008224);             // [B+1]
    int*          bbase2  = (int*)(ws + 58012320);             // [B+1]
    int*          bcur1   = (int*)(ws + 58016416);             // [B]
    int*          bcur2   = (int*)(ws + 58020512);             // [B]

    hipMemsetAsync(bhist1, 0, 8192, stream);   // bhist1+bhist2, contiguous

    const int nbg  = (n + 15) / 16;
    const int nbh1 = (E1 + HCHUNK - 1) / HCHUNK, nbh2 = (E2 + HCHUNK - 1) / HCHUNK;
    k_g1h<<<nbg + nbh1 + nbh2, 256, 0, stream>>>(x, w1, hwbA, hwbB, n, nbg,
                                                 ei + E1, bhist1, E1, nbh1,
                                                 ei2 + E2, bhist2, E2);
    k_bscan<<<2, 64, 0, stream>>>(bhist1, bbase1, bcur1, bhist2, bbase2, bcur2, B);

    const int nbp1 = (E1 + CHUNK - 1) / CHUNK, nbp2 = (E2 + CHUNK - 1) / CHUNK;
    k_part2<<<nbp1 + nbp2, 256, 0, stream>>>(ei, ei + E1, bcur1, ebuf1, E1, nbp1,
                                             ei2, ei2 + E2, bcur2, ebuf2, E2);

    k_csr2<<<2 * B, 256, 0, stream>>>(bbase1, ebuf1, rs1, dinv1, ssrc1, E1,
                                      bbase2, ebuf2, rs2, dinv2, ssrc2, E2, B, n);

    const int nba = (n * 4 + 255) / 256;
    // pass A: feats [0,32) from hwbA (3.2MB, L2-resident); pass B: [32,64)
    k_agg1p<<<3 * nba, 256, 0, stream>>>(rs1, ssrc1, dinv1, rs2, ssrc2, dinv2,
                                         (const us8*)hwbA, b1, R1b, n, nba, 0);
    k_agg1p<<<3 * nba, 256, 0, stream>>>(rs1, ssrc1, dinv1, rs2, ssrc2, dinv2,
                                         (const us8*)hwbB, b1 + 32, R1b, n, nba, 4);

    k_gemm2<<<(n + 15) / 16, 256, 0, stream>>>(R1b, w2, hwb2, n);

    const int nb16 = (n * 2 + 255) / 256;
    k_agg16f<<<2 * nb16, 256, 0, stream>>>(rs1, ssrc1, dinv1, acc2a,
                                           rs2, ssrc2, dinv2, acc2b,
                                           (const us8*)hwb2, n, nb16);

    k_final<<<(n + 15) / 16, 256, 0, stream>>>(hwb2, acc2a, acc2b, dinv1, dinv2, b2,
                                               lin_w, lin_b, (float*)d_out, n);
}

// Round 14
// 259.811 us; speedup vs baseline: 9.2076x; 1.1834x over previous
//
#include <hip/hip_runtime.h>
#include <math.h>

// x[50000,128] w1[128,64] b1[64] w2[192,16] b2[16] lin_w[48,16] lin_b[16]
// edge_index[2,800000] edge_index2[2,3000000] (int32, row0=src, row1=dst)
//
// R14: (a) gemm1 rewritten as 4x4-register-tiled 64x64 block with float4 LDS
// reads (R13's was LDS-BW-bound at 5B/FMA; now 2B/FMA, 1/4 the LDS instrs);
// (b) hist2 unfused again (R13 fusion regressed); (c) part2 CHUNK back to
// 8192 (R12-measured best); (d) layer-1 agg back to ONE pass over a single
// [n,64] bf16 table with x8 unroll (split-table two-pass was net worse).

#define NPB    64
#define CHUNK  8192
#define HCHUNK 16384

typedef unsigned short us8 __attribute__((ext_vector_type(8)));

__device__ inline float b2f(unsigned short u) {
    return __uint_as_float(((unsigned int)u) << 16);
}
// round-to-nearest-even f32 -> bf16 (finite values; matches __float2bfloat16)
__device__ inline unsigned short f2b(float f) {
    unsigned int u = __float_as_uint(f);
    u = (u + 0x7FFFu + ((u >> 16) & 1u)) >> 16;
    return (unsigned short)u;
}

// ---- GEMM1: hwb = bf16(x @ w1), 64 rows/block, 4x4 tile/thread ----
__global__ void __launch_bounds__(256)
k_gemm1(const float* __restrict__ x, const float* __restrict__ w1,
        unsigned short* __restrict__ hwb, int n) {
    __shared__ float ws[128 * 64];   // 32 KB, [k][c]
    __shared__ float xs[64 * 128];   // 32 KB, [r][k]
    int t = threadIdx.x;
    int row0 = blockIdx.x * 64;
    // stage w1 (float4)
    for (int i = t; i < 128 * 16; i += 256)
        ((float4*)ws)[i] = ((const float4*)w1)[i];
    // stage x rows (float4)
    for (int i = t; i < 64 * 32; i += 256) {
        int r = row0 + (i >> 5);
        ((float4*)xs)[i] = (r < n) ? ((const float4*)x)[r * 32 + (i & 31)]
                                   : make_float4(0.f, 0.f, 0.f, 0.f);
    }
    __syncthreads();
    int tr = t >> 4, tc = t & 15;    // 16x16 thread grid: 4 rows x 4 cols each
    float acc[4][4] = {};
    #pragma unroll 4
    for (int k4 = 0; k4 < 32; ++k4) {
        float4 wv0 = *(const float4*)&ws[(k4 * 4 + 0) * 64 + tc * 4];
        float4 wv1 = *(const float4*)&ws[(k4 * 4 + 1) * 64 + tc * 4];
        float4 wv2 = *(const float4*)&ws[(k4 * 4 + 2) * 64 + tc * 4];
        float4 wv3 = *(const float4*)&ws[(k4 * 4 + 3) * 64 + tc * 4];
        #pragma unroll
        for (int r = 0; r < 4; ++r) {
            float4 xv = *(const float4*)&xs[(tr * 4 + r) * 128 + k4 * 4];
            acc[r][0] = fmaf(xv.x, wv0.x, acc[r][0]);
            acc[r][1] = fmaf(xv.x, wv0.y, acc[r][1]);
            acc[r][2] = fmaf(xv.x, wv0.z, acc[r][2]);
            acc[r][3] = fmaf(xv.x, wv0.w, acc[r][3]);
            acc[r][0] = fmaf(xv.y, wv1.x, acc[r][0]);
            acc[r][1] = fmaf(xv.y, wv1.y, acc[r][1]);
            acc[r][2] = fmaf(xv.y, wv1.z, acc[r][2]);
            acc[r][3] = fmaf(xv.y, wv1.w, acc[r][3]);
            acc[r][0] = fmaf(xv.z, wv2.x, acc[r][0]);
            acc[r][1] = fmaf(xv.z, wv2.y, acc[r][1]);
            acc[r][2] = fmaf(xv.z, wv2.z, acc[r][2]);
            acc[r][3] = fmaf(xv.z, wv2.w, acc[r][3]);
            acc[r][0] = fmaf(xv.w, wv3.x, acc[r][0]);
            acc[r][1] = fmaf(xv.w, wv3.y, acc[r][1]);
            acc[r][2] = fmaf(xv.w, wv3.z, acc[r][2]);
            acc[r][3] = fmaf(xv.w, wv3.w, acc[r][3]);
        }
    }
    #pragma unroll
    for (int r = 0; r < 4; ++r) {
        int rr = row0 + tr * 4 + r;
        if (rr < n) {
            ushort4 o;
            o.x = f2b(acc[r][0]); o.y = f2b(acc[r][1]);
            o.z = f2b(acc[r][2]); o.w = f2b(acc[r][3]);
            *(ushort4*)&hwb[rr * 64 + tc * 4] = o;
        }
    }
}

// ------- fused bucket histogram, both edge sets (blockIdx split) -------
__global__ void k_hist2(const int* __restrict__ dstA, int* __restrict__ bhA, int EA, int nbA,
                        const int* __restrict__ dstB, int* __restrict__ bhB, int EB) {
    __shared__ int lh[1024];
    const int* dst; int* bh; int E; int cb;
    if ((int)blockIdx.x < nbA) { dst = dstA; bh = bhA; E = EA; cb = blockIdx.x; }
    else                       { dst = dstB; bh = bhB; E = EB; cb = blockIdx.x - nbA; }
    int t = threadIdx.x;
    for (int i = t; i < 1024; i += 256) lh[i] = 0;
    __syncthreads();
    int base = cb * HCHUNK;
    int cnt = min(HCHUNK, E - base);
    for (int i = t; i < cnt; i += 256) atomicAdd(&lh[dst[base + i] >> 6], 1);
    __syncthreads();
    for (int b = t; b < 1024; b += 256)
        if (lh[b]) atomicAdd(&bh[b], lh[b]);
}

// ------- scan bucket histograms -> bbase (exclusive) and bcur -------
__global__ void k_bscan(const int* __restrict__ bhA, int* __restrict__ bbA, int* __restrict__ bcA,
                        const int* __restrict__ bhB, int* __restrict__ bbB, int* __restrict__ bcB,
                        int B) {
    const int* bh = blockIdx.x ? bhB : bhA;
    int* bb = blockIdx.x ? bbB : bbA;
    int* bc = blockIdx.x ? bcB : bcA;
    int t = threadIdx.x;
    int carry = 0;
    int nch = (B + 63) >> 6;
    for (int c = 0; c < nch; ++c) {
        int idx = c * 64 + t;
        int v = (idx < B) ? bh[idx] : 0;
        int incl = v;
        #pragma unroll
        for (int off = 1; off < 64; off <<= 1) {
            int tv = __shfl_up(incl, off);
            if (t >= off) incl += tv;
        }
        if (idx < B) { bb[idx] = incl - v + carry; bc[idx] = incl - v + carry; }
        carry += __shfl(incl, 63);
    }
    if (t == 0) bb[B] = carry;
}

// ------- fused coarse partition, both edge sets (blockIdx split) -------
// packed word: src(16b) | dstlocal(6b)<<16 | bucket(10b)<<22 (stripped on write)
__global__ void __launch_bounds__(256)
k_part2(const int* __restrict__ srcA, const int* __restrict__ dstA,
        int* __restrict__ bcurA, unsigned int* __restrict__ outA, int EA, int nbA,
        const int* __restrict__ srcB, const int* __restrict__ dstB,
        int* __restrict__ bcurB, unsigned int* __restrict__ outB, int EB) {
    __shared__ int lh[1024];
    __shared__ int loff[1024];
    __shared__ int gof[1024];
    __shared__ int lcur[1024];
    __shared__ unsigned int stage[CHUNK];   // 32 KB -> 48 KB total -> 3 blocks/CU
    const int *src, *dst; int *bcur; unsigned int *out; int E, cb;
    if ((int)blockIdx.x < nbA) { src = srcA; dst = dstA; bcur = bcurA; out = outA; E = EA; cb = blockIdx.x; }
    else                       { src = srcB; dst = dstB; bcur = bcurB; out = outB; E = EB; cb = blockIdx.x - nbA; }
    int t = threadIdx.x;
    int base = cb * CHUNK;
    int cnt = min(CHUNK, E - base);
    for (int i = t; i < 1024; i += 256) lh[i] = 0;
    __syncthreads();
    for (int i = t; i < cnt; i += 256) atomicAdd(&lh[dst[base + i] >> 6], 1);
    __syncthreads();
    if (t < 64) {
        int carry = 0;
        #pragma unroll
        for (int c = 0; c < 16; ++c) {
            int idx = c * 64 + t;
            int v = lh[idx];
            int incl = v;
            #pragma unroll
            for (int off = 1; off < 64; off <<= 1) {
                int tv = __shfl_up(incl, off);
                if (t >= off) incl += tv;
            }
            loff[idx] = incl - v + carry;
            carry += __shfl(incl, 63);
        }
    }
    __syncthreads();
    for (int b = t; b < 1024; b += 256) {
        int c = lh[b];
        gof[b] = c ? atomicAdd(&bcur[b], c) : 0;
        lcur[b] = loff[b];
    }
    __syncthreads();
    for (int i = t; i < cnt; i += 256) {
        int d = dst[base + i];
        int s = src[base + i];
        int bkt = d >> 6;
        int p = atomicAdd(&lcur[bkt], 1);
        stage[p] = (unsigned int)s | ((unsigned int)(d & 63) << 16) |
                   ((unsigned int)bkt << 22);
    }
    __syncthreads();
    for (int i = t; i < cnt; i += 256) {
        unsigned int e = stage[i];
        int bkt = (int)(e >> 22);
        out[gof[bkt] + (i - loff[bkt])] = e & 0x3FFFFFu;
    }
}

// ------- fused CSR build: deg count + scan -> rs/dinv, then in-window scatter ----
__global__ void __launch_bounds__(256)
k_csr2(const int* __restrict__ bbaseA, const unsigned int* __restrict__ ebufA,
       int* __restrict__ rsA, float* __restrict__ dvA, unsigned short* __restrict__ ssrcA, int EA,
       const int* __restrict__ bbaseB, const unsigned int* __restrict__ ebufB,
       int* __restrict__ rsB, float* __restrict__ dvB, unsigned short* __restrict__ ssrcB, int EB,
       int B, int n) {
    __shared__ int cnt[64];
    __shared__ int lcur[64];
    const int* bbase; const unsigned int* ebuf; int* rs; float* dv;
    unsigned short* ssrc; int b, Etot;
    if ((int)blockIdx.x < B) { bbase = bbaseA; ebuf = ebufA; rs = rsA; dv = dvA; ssrc = ssrcA; b = blockIdx.x; Etot = EA; }
    else                     { bbase = bbaseB; ebuf = ebufB; rs = rsB; dv = dvB; ssrc = ssrcB; b = blockIdx.x - B; Etot = EB; }
    int t = threadIdx.x;
    if (t < 64) cnt[t] = 0;
    __syncthreads();
    int beg = bbase[b], end = bbase[b + 1];
    for (int i = beg + t; i < end; i += 256)
        atomicAdd(&cnt[(ebuf[i] >> 16) & 63u], 1);
    __syncthreads();
    if (t < 64) {
        int v = cnt[t];
        int incl = v;
        #pragma unroll
        for (int off = 1; off < 64; off <<= 1) {
            int tv = __shfl_up(incl, off);
            if (t >= off) incl += tv;
        }
        int start = beg + incl - v;
        lcur[t] = start;
        int node = b * NPB + t;
        if (node < n) {
            rs[node] = start;
            dv[node] = (v > 0) ? rsqrtf((float)v) : 0.f;
        }
    }
    __syncthreads();
    for (int i = beg + t; i < end; i += 256) {
        unsigned int e = ebuf[i];
        int p = atomicAdd(&lcur[(e >> 16) & 63u], 1);
        ssrc[p] = (unsigned short)(e & 0xFFFFu);
    }
    if (t == 0 && b == B - 1) rs[n] = Etot;
}

// ------- x8-unrolled full-width (64-feat) gather body; hwb8 is [n][8] us8 -------
__device__ inline void agg64_body(const int* __restrict__ rs,
                                  const unsigned short* __restrict__ ssrc,
                                  const float* __restrict__ dinv,
                                  const us8* __restrict__ hwb8,
                                  const float* __restrict__ b1,
                                  unsigned short* __restrict__ R1b,
                                  int col_unit, int n, int tid) {
    int v = tid >> 3, q = tid & 7;
    if (v >= n) return;
    int beg = rs[v], end = rs[v + 1];
    float a[8] = {0.f, 0.f, 0.f, 0.f, 0.f, 0.f, 0.f, 0.f};
    int i = beg;
    for (; i + 8 <= end; i += 8) {   // 8 independent load chains -> MLP
        int s0 = ssrc[i + 0], s1 = ssrc[i + 1], s2 = ssrc[i + 2], s3 = ssrc[i + 3];
        int s4 = ssrc[i + 4], s5 = ssrc[i + 5], s6 = ssrc[i + 6], s7 = ssrc[i + 7];
        float c0 = dinv[s0], c1 = dinv[s1], c2 = dinv[s2], c3 = dinv[s3];
        float c4 = dinv[s4], c5 = dinv[s5], c6 = dinv[s6], c7 = dinv[s7];
        us8 h0 = hwb8[s0 * 8 + q], h1 = hwb8[s1 * 8 + q];
        us8 h2 = hwb8[s2 * 8 + q], h3 = hwb8[s3 * 8 + q];
        us8 h4 = hwb8[s4 * 8 + q], h5 = hwb8[s5 * 8 + q];
        us8 h6 = hwb8[s6 * 8 + q], h7 = hwb8[s7 * 8 + q];
        #pragma unroll
        for (int j = 0; j < 8; ++j) {
            a[j] = fmaf(b2f(h0[j]), c0, a[j]);
            a[j] = fmaf(b2f(h1[j]), c1, a[j]);
            a[j] = fmaf(b2f(h2[j]), c2, a[j]);
            a[j] = fmaf(b2f(h3[j]), c3, a[j]);
            a[j] = fmaf(b2f(h4[j]), c4, a[j]);
            a[j] = fmaf(b2f(h5[j]), c5, a[j]);
            a[j] = fmaf(b2f(h6[j]), c6, a[j]);
            a[j] = fmaf(b2f(h7[j]), c7, a[j]);
        }
    }
    for (; i < end; ++i) {
        int s = ssrc[i];
        float sc = dinv[s];
        us8 h = hwb8[s * 8 + q];
        #pragma unroll
        for (int j = 0; j < 8; ++j) a[j] = fmaf(b2f(h[j]), sc, a[j]);
    }
    float dd = dinv[v];
    us8 o;
    #pragma unroll
    for (int j = 0; j < 8; ++j) {
        float r = fmaf(a[j], dd, b1[q * 8 + j]);
        o[j] = f2b(r > 0.f ? r : 0.f);
    }
    ((us8*)&R1b[v * 192])[col_unit + q] = o;
}

// ------- fused layer-1: E2 agg | E1 agg | self (blockIdx ranges; E2 first) -------
__global__ void k_agg1f(const int* __restrict__ rs1, const unsigned short* __restrict__ ssrc1,
                        const float* __restrict__ dinv1,
                        const int* __restrict__ rs2, const unsigned short* __restrict__ ssrc2,
                        const float* __restrict__ dinv2,
                        const us8* __restrict__ hwb8, const float* __restrict__ b1,
                        unsigned short* __restrict__ R1b, int n, int nba) {
    int bid = blockIdx.x;
    if (bid < nba) {                 // edge set 2 (the long pole) starts first
        agg64_body(rs2, ssrc2, dinv2, hwb8, b1, R1b, 8, n, bid * 256 + threadIdx.x);
    } else if (bid < 2 * nba) {      // edge set 1
        agg64_body(rs1, ssrc1, dinv1, hwb8, b1, R1b, 0, n,
                   (bid - nba) * 256 + threadIdx.x);
    } else {                         // self branch
        int tid = (bid - 2 * nba) * 256 + threadIdx.x;
        int v = tid >> 3, q = tid & 7;
        if (v >= n) return;
        us8 h = hwb8[v * 8 + q];
        us8 o;
        #pragma unroll
        for (int j = 0; j < 8; ++j) {
            float r = b2f(h[j]) + b1[q * 8 + j];
            o[j] = f2b(r > 0.f ? r : 0.f);
        }
        ((us8*)&R1b[v * 192])[16 + q] = o;
    }
}

// ---------------- GEMM2: hwb2 = bf16(R1 @ w2)  ([n,192]@[192,16]) ----------------
__global__ void __launch_bounds__(256)
k_gemm2(const unsigned short* __restrict__ R1b, const float* __restrict__ w2,
        unsigned short* __restrict__ hwb2, int n) {
    __shared__ float ws[192 * 16];
    __shared__ float rs[16][193];
    int t = threadIdx.x;
    for (int i = t; i < 192 * 16; i += 256) ws[i] = w2[i];
    int row0 = blockIdx.x * 16;
    for (int i = t; i < 16 * 192; i += 256) {
        int r = i / 192, j = i - r * 192;
        int v = row0 + r;
        rs[r][j] = (v < n) ? b2f(R1b[v * 192 + j]) : 0.f;
    }
    __syncthreads();
    int r = t >> 4, c = t & 15;
    int v = row0 + r;
    if (v >= n) return;
    float acc = 0.f;
    #pragma unroll 8
    for (int j = 0; j < 192; ++j) acc += rs[r][j] * ws[j * 16 + c];
    hwb2[v * 16 + c] = f2b(acc);
}

// ------- x8-unrolled layer-2 gather body (hwb2 = 1.6MB, L2-fit) -------
__device__ inline void agg16_body(const int* __restrict__ rs,
                                  const unsigned short* __restrict__ ssrc,
                                  const float* __restrict__ dinv,
                                  const us8* __restrict__ hwb2_8,
                                  float* __restrict__ acc2, int n, int tid) {
    int v = tid >> 1, q = tid & 1;
    if (v >= n) return;
    int beg = rs[v], end = rs[v + 1];
    float a[8] = {0.f, 0.f, 0.f, 0.f, 0.f, 0.f, 0.f, 0.f};
    int i = beg;
    for (; i + 8 <= end; i += 8) {
        int s0 = ssrc[i + 0], s1 = ssrc[i + 1], s2 = ssrc[i + 2], s3 = ssrc[i + 3];
        int s4 = ssrc[i + 4], s5 = ssrc[i + 5], s6 = ssrc[i + 6], s7 = ssrc[i + 7];
        float c0 = dinv[s0], c1 = dinv[s1], c2 = dinv[s2], c3 = dinv[s3];
        float c4 = dinv[s4], c5 = dinv[s5], c6 = dinv[s6], c7 = dinv[s7];
        us8 h0 = hwb2_8[s0 * 2 + q], h1 = hwb2_8[s1 * 2 + q];
        us8 h2 = hwb2_8[s2 * 2 + q], h3 = hwb2_8[s3 * 2 + q];
        us8 h4 = hwb2_8[s4 * 2 + q], h5 = hwb2_8[s5 * 2 + q];
        us8 h6 = hwb2_8[s6 * 2 + q], h7 = hwb2_8[s7 * 2 + q];
        #pragma unroll
        for (int j = 0; j < 8; ++j) {
            a[j] = fmaf(b2f(h0[j]), c0, a[j]);
            a[j] = fmaf(b2f(h1[j]), c1, a[j]);
            a[j] = fmaf(b2f(h2[j]), c2, a[j]);
            a[j] = fmaf(b2f(h3[j]), c3, a[j]);
            a[j] = fmaf(b2f(h4[j]), c4, a[j]);
            a[j] = fmaf(b2f(h5[j]), c5, a[j]);
            a[j] = fmaf(b2f(h6[j]), c6, a[j]);
            a[j] = fmaf(b2f(h7[j]), c7, a[j]);
        }
    }
    for (; i < end; ++i) {
        int s = ssrc[i];
        float sc = dinv[s];
        us8 h = hwb2_8[s * 2 + q];
        #pragma unroll
        for (int j = 0; j < 8; ++j) a[j] = fmaf(b2f(h[j]), sc, a[j]);
    }
    float4* o = (float4*)&acc2[v * 16 + q * 8];
    o[0] = make_float4(a[0], a[1], a[2], a[3]);
    o[1] = make_float4(a[4], a[5], a[6], a[7]);
}

// ------- fused layer-2 aggregate: E2 -> acc2b first, then E1 -> acc2a -------
__global__ void k_agg16f(const int* __restrict__ rs1, const unsigned short* __restrict__ ssrc1,
                         const float* __restrict__ dinv1, float* __restrict__ acc2a,
                         const int* __restrict__ rs2, const unsigned short* __restrict__ ssrc2,
                         const float* __restrict__ dinv2, float* __restrict__ acc2b,
                         const us8* __restrict__ hwb2_8, int n, int nba) {
    int bid = blockIdx.x;
    if (bid < nba)
        agg16_body(rs2, ssrc2, dinv2, hwb2_8, acc2b, n, bid * 256 + threadIdx.x);
    else
        agg16_body(rs1, ssrc1, dinv1, hwb2_8, acc2a, n, (bid - nba) * 256 + threadIdx.x);
}

// ------- final: combine layer-2 branches, linear head, log_softmax ----------
__global__ void k_final(const unsigned short* __restrict__ hwb2,
                        const float* __restrict__ acc2a, const float* __restrict__ acc2b,
                        const float* __restrict__ dinv1, const float* __restrict__ dinv2,
                        const float* __restrict__ b2, const float* __restrict__ lw,
                        const float* __restrict__ lb, float* __restrict__ out, int n) {
    __shared__ float lws[48 * 16];
    __shared__ float r2s[16][49];
    int t = threadIdx.x;
    for (int i = t; i < 48 * 16; i += 256) lws[i] = lw[i];
    int ni = t >> 4, c = t & 15;
    int v = blockIdx.x * 16 + ni;
    if (v < n) {
        float bb = b2[c];
        r2s[ni][c]      = fmaf(dinv1[v], acc2a[v * 16 + c], bb);
        r2s[ni][16 + c] = fmaf(dinv2[v], acc2b[v * 16 + c], bb);
        r2s[ni][32 + c] = b2f(hwb2[v * 16 + c]) + bb;
    }
    __syncthreads();
    if (v >= n) return;
    float o = lb[c];
    #pragma unroll
    for (int j = 0; j < 48; ++j) o += r2s[ni][j] * lws[j * 16 + c];
    float m = o;
    for (int off = 8; off >= 1; off >>= 1) m = fmaxf(m, __shfl_xor(m, off, 16));
    float e = expf(o - m);
    float ssum = e;
    for (int off = 8; off >= 1; off >>= 1) ssum += __shfl_xor(ssum, off, 16);
    out[v * 16 + c] = (o - m) - logf(ssum);
}

extern "C" void kernel_launch(void* const* d_in, const int* in_sizes, int n_in,
                              void* d_out, int out_size, void* d_ws, size_t ws_size,
                              hipStream_t stream) {
    const float* x     = (const float*)d_in[0];
    const float* w1    = (const float*)d_in[1];
    const float* b1    = (const float*)d_in[2];
    const float* w2    = (const float*)d_in[3];
    const float* b2    = (const float*)d_in[4];
    const float* lin_w = (const float*)d_in[5];
    const float* lin_b = (const float*)d_in[6];
    const int*   ei    = (const int*)d_in[7];
    const int*   ei2   = (const int*)d_in[8];

    const int n  = in_sizes[0] / 128;   // 50000
    const int E1 = in_sizes[7] / 2;     // 800000
    const int E2 = in_sizes[8] / 2;     // 3000000
    const int B  = (n + NPB - 1) / NPB; // 782

    char* ws = (char*)d_ws;
    unsigned short* hwb   = (unsigned short*)(ws + 0);         // [n,64] bf16 -> 6.4M
    unsigned short* hwb2  = (unsigned short*)(ws + 6400000);   // [n,16] bf16 -> 8.0M
    unsigned short* R1b   = (unsigned short*)(ws + 8000000);   // [n,192] bf16 -> 27.2M
    unsigned short* ssrc1 = (unsigned short*)(ws + 27200000);  // [E1] -> 28.8M
    unsigned short* ssrc2 = (unsigned short*)(ws + 28800000);  // [E2] -> 34.8M
    unsigned int* ebuf1   = (unsigned int*)(ws + 34800000);    // [E1] -> 38.0M
    unsigned int* ebuf2   = (unsigned int*)(ws + 38000000);    // [E2] -> 50.0M
    float*        acc2a   = (float*)(ws + 50000000);           // [n,16] -> 53.2M
    float*        acc2b   = (float*)(ws + 53200000);           // [n,16] -> 56.4M
    float*        dinv1   = (float*)(ws + 56800000);           // [n]
    float*        dinv2   = (float*)(ws + 57000000);           // [n]
    int*          rs1     = (int*)(ws + 57200000);             // [n+1]
    int*          rs2     = (int*)(ws + 57400016);             // [n+1]
    int*          bhist1  = (int*)(ws + 58000032);             // [1024]
    int*          bhist2  = (int*)(ws + 58004128);             // [1024] (contiguous)
    int*          bbase1  = (int*)(ws + 58008224);             // [B+1]
    int*          bbase2  = (int*)(ws + 58012320);             // [B+1]
    int*          bcur1   = (int*)(ws + 58016416);             // [B]
    int*          bcur2   = (int*)(ws + 58020512);             // [B]

    hipMemsetAsync(bhist1, 0, 8192, stream);   // bhist1+bhist2, contiguous

    k_gemm1<<<(n + 63) / 64, 256, 0, stream>>>(x, w1, hwb, n);

    const int nbh1 = (E1 + HCHUNK - 1) / HCHUNK, nbh2 = (E2 + HCHUNK - 1) / HCHUNK;
    k_hist2<<<nbh1 + nbh2, 256, 0, stream>>>(ei + E1, bhist1, E1, nbh1,
                                             ei2 + E2, bhist2, E2);
    k_bscan<<<2, 64, 0, stream>>>(bhist1, bbase1, bcur1, bhist2, bbase2, bcur2, B);

    const int nbp1 = (E1 + CHUNK - 1) / CHUNK, nbp2 = (E2 + CHUNK - 1) / CHUNK;
    k_part2<<<nbp1 + nbp2, 256, 0, stream>>>(ei, ei + E1, bcur1, ebuf1, E1, nbp1,
                                             ei2, ei2 + E2, bcur2, ebuf2, E2);

    k_csr2<<<2 * B, 256, 0, stream>>>(bbase1, ebuf1, rs1, dinv1, ssrc1, E1,
                                      bbase2, ebuf2, rs2, dinv2, ssrc2, E2, B, n);

    const int nba = (n * 8 + 255) / 256;
    k_agg1f<<<3 * nba, 256, 0, stream>>>(rs1, ssrc1, dinv1, rs2, ssrc2, dinv2,
                                         (const us8*)hwb, b1, R1b, n, nba);

    k_gemm2<<<(n + 15) / 16, 256, 0, stream>>>(R1b, w2, hwb2, n);

    const int nb16 = (n * 2 + 255) / 256;
    k_agg16f<<<2 * nb16, 256, 0, stream>>>(rs1, ssrc1, dinv1, acc2a,
                                           rs2, ssrc2, dinv2, acc2b,
                                           (const us8*)hwb2, n, nb16);

    k_final<<<(n + 15) / 16, 256, 0, stream>>>(hwb2, acc2a, acc2b, dinv1, dinv2, b2,
                                               lin_w, lin_b, (float*)d_out, n);
}

// Round 15
// 253.373 us; speedup vs baseline: 9.4416x; 1.0254x over previous
//
#include <hip/hip_runtime.h>
#include <math.h>

// x[50000,128] w1[128,64] b1[64] w2[192,16] b2[16] lin_w[48,16] lin_b[16]
// edge_index[2,800000] edge_index2[2,3000000] (int32, row0=src, row1=dst)
//
// R15 = R14 with (a) agg1f ssrc loads vectorized (us8 = 8 indices / 16B load,
// alignment-peeled), (b) part2 at 1024 threads + CHUNK 16384 (80KB LDS -> 2
// blocks/CU = 32 waves/CU, 2.7x the latency hiding; full-line output runs),
// (c) agg16f+final fused into k_l2f (LDS accumulators, no acc2 round-trip).

#define NPB    64
#define CHUNK  16384
#define HCHUNK 16384

typedef unsigned short us8 __attribute__((ext_vector_type(8)));

__device__ inline float b2f(unsigned short u) {
    return __uint_as_float(((unsigned int)u) << 16);
}
// round-to-nearest-even f32 -> bf16 (finite values; matches __float2bfloat16)
__device__ inline unsigned short f2b(float f) {
    unsigned int u = __float_as_uint(f);
    u = (u + 0x7FFFu + ((u >> 16) & 1u)) >> 16;
    return (unsigned short)u;
}

// ---- GEMM1: hwb = bf16(x @ w1), 64 rows/block, 4x4 tile/thread ----
__global__ void __launch_bounds__(256)
k_gemm1(const float* __restrict__ x, const float* __restrict__ w1,
        unsigned short* __restrict__ hwb, int n) {
    __shared__ float ws[128 * 64];   // 32 KB, [k][c]
    __shared__ float xs[64 * 128];   // 32 KB, [r][k]
    int t = threadIdx.x;
    int row0 = blockIdx.x * 64;
    for (int i = t; i < 128 * 16; i += 256)
        ((float4*)ws)[i] = ((const float4*)w1)[i];
    for (int i = t; i < 64 * 32; i += 256) {
        int r = row0 + (i >> 5);
        ((float4*)xs)[i] = (r < n) ? ((const float4*)x)[r * 32 + (i & 31)]
                                   : make_float4(0.f, 0.f, 0.f, 0.f);
    }
    __syncthreads();
    int tr = t >> 4, tc = t & 15;
    float acc[4][4] = {};
    #pragma unroll 4
    for (int k4 = 0; k4 < 32; ++k4) {
        float4 wv0 = *(const float4*)&ws[(k4 * 4 + 0) * 64 + tc * 4];
        float4 wv1 = *(const float4*)&ws[(k4 * 4 + 1) * 64 + tc * 4];
        float4 wv2 = *(const float4*)&ws[(k4 * 4 + 2) * 64 + tc * 4];
        float4 wv3 = *(const float4*)&ws[(k4 * 4 + 3) * 64 + tc * 4];
        #pragma unroll
        for (int r = 0; r < 4; ++r) {
            float4 xv = *(const float4*)&xs[(tr * 4 + r) * 128 + k4 * 4];
            acc[r][0] = fmaf(xv.x, wv0.x, acc[r][0]);
            acc[r][1] = fmaf(xv.x, wv0.y, acc[r][1]);
            acc[r][2] = fmaf(xv.x, wv0.z, acc[r][2]);
            acc[r][3] = fmaf(xv.x, wv0.w, acc[r][3]);
            acc[r][0] = fmaf(xv.y, wv1.x, acc[r][0]);
            acc[r][1] = fmaf(xv.y, wv1.y, acc[r][1]);
            acc[r][2] = fmaf(xv.y, wv1.z, acc[r][2]);
            acc[r][3] = fmaf(xv.y, wv1.w, acc[r][3]);
            acc[r][0] = fmaf(xv.z, wv2.x, acc[r][0]);
            acc[r][1] = fmaf(xv.z, wv2.y, acc[r][1]);
            acc[r][2] = fmaf(xv.z, wv2.z, acc[r][2]);
            acc[r][3] = fmaf(xv.z, wv2.w, acc[r][3]);
            acc[r][0] = fmaf(xv.w, wv3.x, acc[r][0]);
            acc[r][1] = fmaf(xv.w, wv3.y, acc[r][1]);
            acc[r][2] = fmaf(xv.w, wv3.z, acc[r][2]);
            acc[r][3] = fmaf(xv.w, wv3.w, acc[r][3]);
        }
    }
    #pragma unroll
    for (int r = 0; r < 4; ++r) {
        int rr = row0 + tr * 4 + r;
        if (rr < n) {
            ushort4 o;
            o.x = f2b(acc[r][0]); o.y = f2b(acc[r][1]);
            o.z = f2b(acc[r][2]); o.w = f2b(acc[r][3]);
            *(ushort4*)&hwb[rr * 64 + tc * 4] = o;
        }
    }
}

// ------- fused bucket histogram, both edge sets (blockIdx split) -------
__global__ void k_hist2(const int* __restrict__ dstA, int* __restrict__ bhA, int EA, int nbA,
                        const int* __restrict__ dstB, int* __restrict__ bhB, int EB) {
    __shared__ int lh[1024];
    const int* dst; int* bh; int E; int cb;
    if ((int)blockIdx.x < nbA) { dst = dstA; bh = bhA; E = EA; cb = blockIdx.x; }
    else                       { dst = dstB; bh = bhB; E = EB; cb = blockIdx.x - nbA; }
    int t = threadIdx.x;
    for (int i = t; i < 1024; i += 256) lh[i] = 0;
    __syncthreads();
    int base = cb * HCHUNK;
    int cnt = min(HCHUNK, E - base);
    for (int i = t; i < cnt; i += 256) atomicAdd(&lh[dst[base + i] >> 6], 1);
    __syncthreads();
    for (int b = t; b < 1024; b += 256)
        if (lh[b]) atomicAdd(&bh[b], lh[b]);
}

// ------- scan bucket histograms -> bbase (exclusive) and bcur -------
__global__ void k_bscan(const int* __restrict__ bhA, int* __restrict__ bbA, int* __restrict__ bcA,
                        const int* __restrict__ bhB, int* __restrict__ bbB, int* __restrict__ bcB,
                        int B) {
    const int* bh = blockIdx.x ? bhB : bhA;
    int* bb = blockIdx.x ? bbB : bbA;
    int* bc = blockIdx.x ? bcB : bcA;
    int t = threadIdx.x;
    int carry = 0;
    int nch = (B + 63) >> 6;
    for (int c = 0; c < nch; ++c) {
        int idx = c * 64 + t;
        int v = (idx < B) ? bh[idx] : 0;
        int incl = v;
        #pragma unroll
        for (int off = 1; off < 64; off <<= 1) {
            int tv = __shfl_up(incl, off);
            if (t >= off) incl += tv;
        }
        if (idx < B) { bb[idx] = incl - v + carry; bc[idx] = incl - v + carry; }
        carry += __shfl(incl, 63);
    }
    if (t == 0) bb[B] = carry;
}

// ------- fused coarse partition, 1024 threads, both edge sets -------
// packed word: src(16b) | dstlocal(6b)<<16 | bucket(10b)<<22 (stripped on write)
// LDS = 16KB control + 64KB stage = 80KB -> 2 blocks/CU (32 waves/CU).
__global__ void __launch_bounds__(1024)
k_part2(const int* __restrict__ srcA, const int* __restrict__ dstA,
        int* __restrict__ bcurA, unsigned int* __restrict__ outA, int EA, int nbA,
        const int* __restrict__ srcB, const int* __restrict__ dstB,
        int* __restrict__ bcurB, unsigned int* __restrict__ outB, int EB) {
    __shared__ int lh[1024];
    __shared__ int loff[1024];
    __shared__ int gof[1024];
    __shared__ int lcur[1024];
    __shared__ unsigned int stage[CHUNK];   // 64 KB
    const int *src, *dst; int *bcur; unsigned int *out; int E, cb;
    if ((int)blockIdx.x < nbA) { src = srcA; dst = dstA; bcur = bcurA; out = outA; E = EA; cb = blockIdx.x; }
    else                       { src = srcB; dst = dstB; bcur = bcurB; out = outB; E = EB; cb = blockIdx.x - nbA; }
    int t = threadIdx.x;
    int base = cb * CHUNK;
    int cnt = min(CHUNK, E - base);
    lh[t] = 0;
    __syncthreads();
    for (int i = t; i < cnt; i += 1024) atomicAdd(&lh[dst[base + i] >> 6], 1);
    __syncthreads();
    // 1024-entry exclusive scan: wave scans + cross-wave scan (gof as scratch)
    int vdeg = lh[t];
    int incl = vdeg;
    #pragma unroll
    for (int off = 1; off < 64; off <<= 1) {
        int tv = __shfl_up(incl, off);
        if ((t & 63) >= off) incl += tv;
    }
    if ((t & 63) == 63) gof[t >> 6] = incl;   // wave sums -> gof[0..15]
    __syncthreads();
    if (t < 16) {
        int wv = gof[t];
        int winc = wv;
        #pragma unroll
        for (int off = 1; off < 16; off <<= 1) {
            int tv = __shfl_up(winc, off, 16);
            if (t >= off) winc += tv;
        }
        gof[16 + t] = winc - wv;              // wave exclusive offsets
    }
    __syncthreads();
    int excl = incl - vdeg + gof[16 + (t >> 6)];
    loff[t] = excl;
    lcur[t] = excl;
    __syncthreads();                          // all gof reads done
    gof[t] = vdeg ? atomicAdd(&bcur[t], vdeg) : 0;
    __syncthreads();
    for (int i = t; i < cnt; i += 1024) {
        int d = dst[base + i];
        int s = src[base + i];
        int bkt = d >> 6;
        int p = atomicAdd(&lcur[bkt], 1);
        stage[p] = (unsigned int)s | ((unsigned int)(d & 63) << 16) |
                   ((unsigned int)bkt << 22);
    }
    __syncthreads();
    for (int i = t; i < cnt; i += 1024) {
        unsigned int e = stage[i];
        int bkt = (int)(e >> 22);
        out[gof[bkt] + (i - loff[bkt])] = e & 0x3FFFFFu;
    }
}

// ------- fused CSR build: deg count + scan -> rs/dinv, then in-window scatter ----
__global__ void __launch_bounds__(256)
k_csr2(const int* __restrict__ bbaseA, const unsigned int* __restrict__ ebufA,
       int* __restrict__ rsA, float* __restrict__ dvA, unsigned short* __restrict__ ssrcA, int EA,
       const int* __restrict__ bbaseB, const unsigned int* __restrict__ ebufB,
       int* __restrict__ rsB, float* __restrict__ dvB, unsigned short* __restrict__ ssrcB, int EB,
       int B, int n) {
    __shared__ int cnt[64];
    __shared__ int lcur[64];
    const int* bbase; const unsigned int* ebuf; int* rs; float* dv;
    unsigned short* ssrc; int b, Etot;
    if ((int)blockIdx.x < B) { bbase = bbaseA; ebuf = ebufA; rs = rsA; dv = dvA; ssrc = ssrcA; b = blockIdx.x; Etot = EA; }
    else                     { bbase = bbaseB; ebuf = ebufB; rs = rsB; dv = dvB; ssrc = ssrcB; b = blockIdx.x - B; Etot = EB; }
    int t = threadIdx.x;
    if (t < 64) cnt[t] = 0;
    __syncthreads();
    int beg = bbase[b], end = bbase[b + 1];
    for (int i = beg + t; i < end; i += 256)
        atomicAdd(&cnt[(ebuf[i] >> 16) & 63u], 1);
    __syncthreads();
    if (t < 64) {
        int v = cnt[t];
        int incl = v;
        #pragma unroll
        for (int off = 1; off < 64; off <<= 1) {
            int tv = __shfl_up(incl, off);
            if (t >= off) incl += tv;
        }
        int start = beg + incl - v;
        lcur[t] = start;
        int node = b * NPB + t;
        if (node < n) {
            rs[node] = start;
            dv[node] = (v > 0) ? rsqrtf((float)v) : 0.f;
        }
    }
    __syncthreads();
    for (int i = beg + t; i < end; i += 256) {
        unsigned int e = ebuf[i];
        int p = atomicAdd(&lcur[(e >> 16) & 63u], 1);
        ssrc[p] = (unsigned short)(e & 0xFFFFu);
    }
    if (t == 0 && b == B - 1) rs[n] = Etot;
}

// ------- x8-unrolled 64-feat gather body; vectorized (us8) index loads -------
__device__ inline void agg64_body(const int* __restrict__ rs,
                                  const unsigned short* __restrict__ ssrc,
                                  const float* __restrict__ dinv,
                                  const us8* __restrict__ hwb8,
                                  const float* __restrict__ b1,
                                  unsigned short* __restrict__ R1b,
                                  int col_unit, int n, int tid) {
    int v = tid >> 3, q = tid & 7;
    if (v >= n) return;
    int beg = rs[v], end = rs[v + 1];
    float a[8] = {0.f, 0.f, 0.f, 0.f, 0.f, 0.f, 0.f, 0.f};
    int i = beg;
    int al = (beg + 7) & ~7;
    int stop = (al < end) ? al : end;
    for (; i < stop; ++i) {            // peel to 16B alignment
        int s = ssrc[i];
        float sc = dinv[s];
        us8 h = hwb8[s * 8 + q];
        #pragma unroll
        for (int j = 0; j < 8; ++j) a[j] = fmaf(b2f(h[j]), sc, a[j]);
    }
    for (; i + 8 <= end; i += 8) {     // 8 indices in ONE 16B load
        us8 sv = *(const us8*)(ssrc + i);
        int s0 = sv[0], s1 = sv[1], s2 = sv[2], s3 = sv[3];
        int s4 = sv[4], s5 = sv[5], s6 = sv[6], s7 = sv[7];
        float c0 = dinv[s0], c1 = dinv[s1], c2 = dinv[s2], c3 = dinv[s3];
        float c4 = dinv[s4], c5 = dinv[s5], c6 = dinv[s6], c7 = dinv[s7];
        us8 h0 = hwb8[s0 * 8 + q], h1 = hwb8[s1 * 8 + q];
        us8 h2 = hwb8[s2 * 8 + q], h3 = hwb8[s3 * 8 + q];
        us8 h4 = hwb8[s4 * 8 + q], h5 = hwb8[s5 * 8 + q];
        us8 h6 = hwb8[s6 * 8 + q], h7 = hwb8[s7 * 8 + q];
        #pragma unroll
        for (int j = 0; j < 8; ++j) {
            a[j] = fmaf(b2f(h0[j]), c0, a[j]);
            a[j] = fmaf(b2f(h1[j]), c1, a[j]);
            a[j] = fmaf(b2f(h2[j]), c2, a[j]);
            a[j] = fmaf(b2f(h3[j]), c3, a[j]);
            a[j] = fmaf(b2f(h4[j]), c4, a[j]);
            a[j] = fmaf(b2f(h5[j]), c5, a[j]);
            a[j] = fmaf(b2f(h6[j]), c6, a[j]);
            a[j] = fmaf(b2f(h7[j]), c7, a[j]);
        }
    }
    for (; i < end; ++i) {
        int s = ssrc[i];
        float sc = dinv[s];
        us8 h = hwb8[s * 8 + q];
        #pragma unroll
        for (int j = 0; j < 8; ++j) a[j] = fmaf(b2f(h[j]), sc, a[j]);
    }
    float dd = dinv[v];
    us8 o;
    #pragma unroll
    for (int j = 0; j < 8; ++j) {
        float r = fmaf(a[j], dd, b1[q * 8 + j]);
        o[j] = f2b(r > 0.f ? r : 0.f);
    }
    ((us8*)&R1b[v * 192])[col_unit + q] = o;
}

// ------- fused layer-1: E2 agg | E1 agg | self (blockIdx ranges; E2 first) -------
__global__ void k_agg1f(const int* __restrict__ rs1, const unsigned short* __restrict__ ssrc1,
                        const float* __restrict__ dinv1,
                        const int* __restrict__ rs2, const unsigned short* __restrict__ ssrc2,
                        const float* __restrict__ dinv2,
                        const us8* __restrict__ hwb8, const float* __restrict__ b1,
                        unsigned short* __restrict__ R1b, int n, int nba) {
    int bid = blockIdx.x;
    if (bid < nba) {
        agg64_body(rs2, ssrc2, dinv2, hwb8, b1, R1b, 8, n, bid * 256 + threadIdx.x);
    } else if (bid < 2 * nba) {
        agg64_body(rs1, ssrc1, dinv1, hwb8, b1, R1b, 0, n,
                   (bid - nba) * 256 + threadIdx.x);
    } else {
        int tid = (bid - 2 * nba) * 256 + threadIdx.x;
        int v = tid >> 3, q = tid & 7;
        if (v >= n) return;
        us8 h = hwb8[v * 8 + q];
        us8 o;
        #pragma unroll
        for (int j = 0; j < 8; ++j) {
            float r = b2f(h[j]) + b1[q * 8 + j];
            o[j] = f2b(r > 0.f ? r : 0.f);
        }
        ((us8*)&R1b[v * 192])[16 + q] = o;
    }
}

// ---------------- GEMM2: hwb2 = bf16(R1 @ w2)  ([n,192]@[192,16]) ----------------
__global__ void __launch_bounds__(256)
k_gemm2(const unsigned short* __restrict__ R1b, const float* __restrict__ w2,
        unsigned short* __restrict__ hwb2, int n) {
    __shared__ float ws[192 * 16];
    __shared__ float rs[16][193];
    int t = threadIdx.x;
    for (int i = t; i < 192 * 16; i += 256) ws[i] = w2[i];
    int row0 = blockIdx.x * 16;
    for (int i = t; i < 16 * 192; i += 256) {
        int r = i / 192, j = i - r * 192;
        int v = row0 + r;
        rs[r][j] = (v < n) ? b2f(R1b[v * 192 + j]) : 0.f;
    }
    __syncthreads();
    int r = t >> 4, c = t & 15;
    int v = row0 + r;
    if (v >= n) return;
    float acc = 0.f;
    #pragma unroll 8
    for (int j = 0; j < 192; ++j) acc += rs[r][j] * ws[j * 16 + c];
    hwb2[v * 16 + c] = f2b(acc);
}

// ------- 16-feat gather (2 lanes/node) with vectorized index loads -------
__device__ inline void gath16(const int* __restrict__ rs,
                              const unsigned short* __restrict__ ssrc,
                              const float* __restrict__ dinv,
                              const us8* __restrict__ h8,
                              int v, int q, float* __restrict__ a) {
    int beg = rs[v], end = rs[v + 1];
    #pragma unroll
    for (int j = 0; j < 8; ++j) a[j] = 0.f;
    int i = beg;
    int al = (beg + 7) & ~7;
    int stop = (al < end) ? al : end;
    for (; i < stop; ++i) {
        int s = ssrc[i];
        float sc = dinv[s];
        us8 h = h8[s * 2 + q];
        #pragma unroll
        for (int j = 0; j < 8; ++j) a[j] = fmaf(b2f(h[j]), sc, a[j]);
    }
    for (; i + 8 <= end; i += 8) {
        us8 sv = *(const us8*)(ssrc + i);
        int s0 = sv[0], s1 = sv[1], s2 = sv[2], s3 = sv[3];
        int s4 = sv[4], s5 = sv[5], s6 = sv[6], s7 = sv[7];
        float c0 = dinv[s0], c1 = dinv[s1], c2 = dinv[s2], c3 = dinv[s3];
        float c4 = dinv[s4], c5 = dinv[s5], c6 = dinv[s6], c7 = dinv[s7];
        us8 h0 = h8[s0 * 2 + q], h1 = h8[s1 * 2 + q];
        us8 h2 = h8[s2 * 2 + q], h3 = h8[s3 * 2 + q];
        us8 h4 = h8[s4 * 2 + q], h5 = h8[s5 * 2 + q];
        us8 h6 = h8[s6 * 2 + q], h7 = h8[s7 * 2 + q];
        #pragma unroll
        for (int j = 0; j < 8; ++j) {
            a[j] = fmaf(b2f(h0[j]), c0, a[j]);
            a[j] = fmaf(b2f(h1[j]), c1, a[j]);
            a[j] = fmaf(b2f(h2[j]), c2, a[j]);
            a[j] = fmaf(b2f(h3[j]), c3, a[j]);
            a[j] = fmaf(b2f(h4[j]), c4, a[j]);
            a[j] = fmaf(b2f(h5[j]), c5, a[j]);
            a[j] = fmaf(b2f(h6[j]), c6, a[j]);
            a[j] = fmaf(b2f(h7[j]), c7, a[j]);
        }
    }
    for (; i < end; ++i) {
        int s = ssrc[i];
        float sc = dinv[s];
        us8 h = h8[s * 2 + q];
        #pragma unroll
        for (int j = 0; j < 8; ++j) a[j] = fmaf(b2f(h[j]), sc, a[j]);
    }
}

// ------- fused layer-2 aggregate + linear head + log_softmax (128 nodes/block) ----
__global__ void __launch_bounds__(256)
k_l2f(const int* __restrict__ rs1, const unsigned short* __restrict__ ssrc1,
      const float* __restrict__ dinv1,
      const int* __restrict__ rs2, const unsigned short* __restrict__ ssrc2,
      const float* __restrict__ dinv2,
      const us8* __restrict__ hwb2_8, const unsigned short* __restrict__ hwb2,
      const float* __restrict__ b2, const float* __restrict__ lw,
      const float* __restrict__ lb, float* __restrict__ out, int n) {
    __shared__ float accA[128 * 16];   // E1 sums
    __shared__ float accB[128 * 16];   // E2 sums
    __shared__ float lws[48 * 16];
    __shared__ float r2s[16][49];
    int t = threadIdx.x;
    int v0 = blockIdx.x * 128;
    for (int i = t; i < 48 * 16; i += 256) lws[i] = lw[i];
    int vl = t >> 1, q = t & 1;
    int v = v0 + vl;
    if (v < n) {
        float a[8];
        gath16(rs2, ssrc2, dinv2, hwb2_8, v, q, a);
        #pragma unroll
        for (int j = 0; j < 8; ++j) accB[vl * 16 + q * 8 + j] = a[j];
        gath16(rs1, ssrc1, dinv1, hwb2_8, v, q, a);
        #pragma unroll
        for (int j = 0; j < 8; ++j) accA[vl * 16 + q * 8 + j] = a[j];
    }
    __syncthreads();
    int ni = t >> 4, c = t & 15;
    for (int p = 0; p < 8; ++p) {
        int vv = v0 + p * 16 + ni;
        int vl2 = p * 16 + ni;
        if (vv < n) {
            float bb = b2[c];
            r2s[ni][c]      = fmaf(dinv1[vv], accA[vl2 * 16 + c], bb);
            r2s[ni][16 + c] = fmaf(dinv2[vv], accB[vl2 * 16 + c], bb);
            r2s[ni][32 + c] = b2f(hwb2[vv * 16 + c]) + bb;
        }
        __syncthreads();
        if (vv < n) {
            float o = lb[c];
            #pragma unroll
            for (int j = 0; j < 48; ++j) o += r2s[ni][j] * lws[j * 16 + c];
            float m = o;
            for (int off = 8; off >= 1; off >>= 1) m = fmaxf(m, __shfl_xor(m, off, 16));
            float e = expf(o - m);
            float ssum = e;
            for (int off = 8; off >= 1; off >>= 1) ssum += __shfl_xor(ssum, off, 16);
            out[vv * 16 + c] = (o - m) - logf(ssum);
        }
        __syncthreads();
    }
}

extern "C" void kernel_launch(void* const* d_in, const int* in_sizes, int n_in,
                              void* d_out, int out_size, void* d_ws, size_t ws_size,
                              hipStream_t stream) {
    const float* x     = (const float*)d_in[0];
    const float* w1    = (const float*)d_in[1];
    const float* b1    = (const float*)d_in[2];
    const float* w2    = (const float*)d_in[3];
    const float* b2    = (const float*)d_in[4];
    const float* lin_w = (const float*)d_in[5];
    const float* lin_b = (const float*)d_in[6];
    const int*   ei    = (const int*)d_in[7];
    const int*   ei2   = (const int*)d_in[8];

    const int n  = in_sizes[0] / 128;   // 50000
    const int E1 = in_sizes[7] / 2;     // 800000
    const int E2 = in_sizes[8] / 2;     // 3000000
    const int B  = (n + NPB - 1) / NPB; // 782

    char* ws = (char*)d_ws;
    unsigned short* hwb   = (unsigned short*)(ws + 0);         // [n,64] bf16 -> 6.4M
    unsigned short* hwb2  = (unsigned short*)(ws + 6400000);   // [n,16] bf16 -> 8.0M
    unsigned short* R1b   = (unsigned short*)(ws + 8000000);   // [n,192] bf16 -> 27.2M
    unsigned short* ssrc1 = (unsigned short*)(ws + 27200000);  // [E1] -> 28.8M
    unsigned short* ssrc2 = (unsigned short*)(ws + 28800000);  // [E2] -> 34.8M
    unsigned int* ebuf1   = (unsigned int*)(ws + 34800000);    // [E1] -> 38.0M
    unsigned int* ebuf2   = (unsigned int*)(ws + 38000000);    // [E2] -> 50.0M
    float*        dinv1   = (float*)(ws + 56800000);           // [n]
    float*        dinv2   = (float*)(ws + 57000000);           // [n]
    int*          rs1     = (int*)(ws + 57200000);             // [n+1]
    int*          rs2     = (int*)(ws + 57400016);             // [n+1]
    int*          bhist1  = (int*)(ws + 58000032);             // [1024]
    int*          bhist2  = (int*)(ws + 58004128);             // [1024] (contiguous)
    int*          bbase1  = (int*)(ws + 58008224);             // [B+1]
    int*          bbase2  = (int*)(ws + 58012320);             // [B+1]
    int*          bcur1   = (int*)(ws + 58016416);             // [B..1024]
    int*          bcur2   = (int*)(ws + 58020512);             // [B..1024]

    hipMemsetAsync(bhist1, 0, 8192, stream);   // bhist1+bhist2, contiguous

    k_gemm1<<<(n + 63) / 64, 256, 0, stream>>>(x, w1, hwb, n);

    const int nbh1 = (E1 + HCHUNK - 1) / HCHUNK, nbh2 = (E2 + HCHUNK - 1) / HCHUNK;
    k_hist2<<<nbh1 + nbh2, 256, 0, stream>>>(ei + E1, bhist1, E1, nbh1,
                                             ei2 + E2, bhist2, E2);
    k_bscan<<<2, 64, 0, stream>>>(bhist1, bbase1, bcur1, bhist2, bbase2, bcur2, B);

    const int nbp1 = (E1 + CHUNK - 1) / CHUNK, nbp2 = (E2 + CHUNK - 1) / CHUNK;
    k_part2<<<nbp1 + nbp2, 1024, 0, stream>>>(ei, ei + E1, bcur1, ebuf1, E1, nbp1,
                                              ei2, ei2 + E2, bcur2, ebuf2, E2);

    k_csr2<<<2 * B, 256, 0, stream>>>(bbase1, ebuf1, rs1, dinv1, ssrc1, E1,
                                      bbase2, ebuf2, rs2, dinv2, ssrc2, E2, B, n);

    const int nba = (n * 8 + 255) / 256;
    k_agg1f<<<3 * nba, 256, 0, stream>>>(rs1, ssrc1, dinv1, rs2, ssrc2, dinv2,
                                         (const us8*)hwb, b1, R1b, n, nba);

    k_gemm2<<<(n + 15) / 16, 256, 0, stream>>>(R1b, w2, hwb2, n);

    k_l2f<<<(n + 127) / 128, 256, 0, stream>>>(rs1, ssrc1, dinv1, rs2, ssrc2, dinv2,
                                               (const us8*)hwb2, hwb2, b2,
                                               lin_w, lin_b, (float*)d_out, n);
}

// Round 16
// 244.235 us; speedup vs baseline: 9.7949x; 1.0374x over previous
//
#include <hip/hip_runtime.h>
#include <math.h>

// x[50000,128] w1[128,64] b1[64] w2[192,16] b2[16] lin_w[48,16] lin_b[16]
// edge_index[2,800000] edge_index2[2,3000000] (int32, row0=src, row1=dst)
//
// R16 = R15 with (a) agg index loads reverted to SCALAR (R15's us8 index loads
// broke the broadcast pattern: 59.5->68.4us regression), (b) dinv[src] baked
// into a packed uint stream psrc = src | bf16(dinv[src])<<16 (k_pack, reuses
// dead ebuf space) -- removes the per-edge random dinv gather from both
// aggregation layers; scale recovered by a shift (VALU, no load).

#define NPB    64
#define CHUNK  16384
#define HCHUNK 16384

typedef unsigned short us8 __attribute__((ext_vector_type(8)));

__device__ inline float b2f(unsigned short u) {
    return __uint_as_float(((unsigned int)u) << 16);
}
// round-to-nearest-even f32 -> bf16 (finite values; matches __float2bfloat16)
__device__ inline unsigned short f2b(float f) {
    unsigned int u = __float_as_uint(f);
    u = (u + 0x7FFFu + ((u >> 16) & 1u)) >> 16;
    return (unsigned short)u;
}

// ---- GEMM1: hwb = bf16(x @ w1), 64 rows/block, 4x4 tile/thread ----
__global__ void __launch_bounds__(256)
k_gemm1(const float* __restrict__ x, const float* __restrict__ w1,
        unsigned short* __restrict__ hwb, int n) {
    __shared__ float ws[128 * 64];   // 32 KB, [k][c]
    __shared__ float xs[64 * 128];   // 32 KB, [r][k]
    int t = threadIdx.x;
    int row0 = blockIdx.x * 64;
    for (int i = t; i < 128 * 16; i += 256)
        ((float4*)ws)[i] = ((const float4*)w1)[i];
    for (int i = t; i < 64 * 32; i += 256) {
        int r = row0 + (i >> 5);
        ((float4*)xs)[i] = (r < n) ? ((const float4*)x)[r * 32 + (i & 31)]
                                   : make_float4(0.f, 0.f, 0.f, 0.f);
    }
    __syncthreads();
    int tr = t >> 4, tc = t & 15;
    float acc[4][4] = {};
    #pragma unroll 4
    for (int k4 = 0; k4 < 32; ++k4) {
        float4 wv0 = *(const float4*)&ws[(k4 * 4 + 0) * 64 + tc * 4];
        float4 wv1 = *(const float4*)&ws[(k4 * 4 + 1) * 64 + tc * 4];
        float4 wv2 = *(const float4*)&ws[(k4 * 4 + 2) * 64 + tc * 4];
        float4 wv3 = *(const float4*)&ws[(k4 * 4 + 3) * 64 + tc * 4];
        #pragma unroll
        for (int r = 0; r < 4; ++r) {
            float4 xv = *(const float4*)&xs[(tr * 4 + r) * 128 + k4 * 4];
            acc[r][0] = fmaf(xv.x, wv0.x, acc[r][0]);
            acc[r][1] = fmaf(xv.x, wv0.y, acc[r][1]);
            acc[r][2] = fmaf(xv.x, wv0.z, acc[r][2]);
            acc[r][3] = fmaf(xv.x, wv0.w, acc[r][3]);
            acc[r][0] = fmaf(xv.y, wv1.x, acc[r][0]);
            acc[r][1] = fmaf(xv.y, wv1.y, acc[r][1]);
            acc[r][2] = fmaf(xv.y, wv1.z, acc[r][2]);
            acc[r][3] = fmaf(xv.y, wv1.w, acc[r][3]);
            acc[r][0] = fmaf(xv.z, wv2.x, acc[r][0]);
            acc[r][1] = fmaf(xv.z, wv2.y, acc[r][1]);
            acc[r][2] = fmaf(xv.z, wv2.z, acc[r][2]);
            acc[r][3] = fmaf(xv.z, wv2.w, acc[r][3]);
            acc[r][0] = fmaf(xv.w, wv3.x, acc[r][0]);
            acc[r][1] = fmaf(xv.w, wv3.y, acc[r][1]);
            acc[r][2] = fmaf(xv.w, wv3.z, acc[r][2]);
            acc[r][3] = fmaf(xv.w, wv3.w, acc[r][3]);
        }
    }
    #pragma unroll
    for (int r = 0; r < 4; ++r) {
        int rr = row0 + tr * 4 + r;
        if (rr < n) {
            ushort4 o;
            o.x = f2b(acc[r][0]); o.y = f2b(acc[r][1]);
            o.z = f2b(acc[r][2]); o.w = f2b(acc[r][3]);
            *(ushort4*)&hwb[rr * 64 + tc * 4] = o;
        }
    }
}

// ------- fused bucket histogram, both edge sets (blockIdx split) -------
__global__ void k_hist2(const int* __restrict__ dstA, int* __restrict__ bhA, int EA, int nbA,
                        const int* __restrict__ dstB, int* __restrict__ bhB, int EB) {
    __shared__ int lh[1024];
    const int* dst; int* bh; int E; int cb;
    if ((int)blockIdx.x < nbA) { dst = dstA; bh = bhA; E = EA; cb = blockIdx.x; }
    else                       { dst = dstB; bh = bhB; E = EB; cb = blockIdx.x - nbA; }
    int t = threadIdx.x;
    for (int i = t; i < 1024; i += 256) lh[i] = 0;
    __syncthreads();
    int base = cb * HCHUNK;
    int cnt = min(HCHUNK, E - base);
    for (int i = t; i < cnt; i += 256) atomicAdd(&lh[dst[base + i] >> 6], 1);
    __syncthreads();
    for (int b = t; b < 1024; b += 256)
        if (lh[b]) atomicAdd(&bh[b], lh[b]);
}

// ------- scan bucket histograms -> bbase (exclusive) and bcur -------
__global__ void k_bscan(const int* __restrict__ bhA, int* __restrict__ bbA, int* __restrict__ bcA,
                        const int* __restrict__ bhB, int* __restrict__ bbB, int* __restrict__ bcB,
                        int B) {
    const int* bh = blockIdx.x ? bhB : bhA;
    int* bb = blockIdx.x ? bbB : bbA;
    int* bc = blockIdx.x ? bcB : bcA;
    int t = threadIdx.x;
    int carry = 0;
    int nch = (B + 63) >> 6;
    for (int c = 0; c < nch; ++c) {
        int idx = c * 64 + t;
        int v = (idx < B) ? bh[idx] : 0;
        int incl = v;
        #pragma unroll
        for (int off = 1; off < 64; off <<= 1) {
            int tv = __shfl_up(incl, off);
            if (t >= off) incl += tv;
        }
        if (idx < B) { bb[idx] = incl - v + carry; bc[idx] = incl - v + carry; }
        carry += __shfl(incl, 63);
    }
    if (t == 0) bb[B] = carry;
}

// ------- fused coarse partition, 1024 threads, both edge sets -------
__global__ void __launch_bounds__(1024)
k_part2(const int* __restrict__ srcA, const int* __restrict__ dstA,
        int* __restrict__ bcurA, unsigned int* __restrict__ outA, int EA, int nbA,
        const int* __restrict__ srcB, const int* __restrict__ dstB,
        int* __restrict__ bcurB, unsigned int* __restrict__ outB, int EB) {
    __shared__ int lh[1024];
    __shared__ int loff[1024];
    __shared__ int gof[1024];
    __shared__ int lcur[1024];
    __shared__ unsigned int stage[CHUNK];   // 64 KB
    const int *src, *dst; int *bcur; unsigned int *out; int E, cb;
    if ((int)blockIdx.x < nbA) { src = srcA; dst = dstA; bcur = bcurA; out = outA; E = EA; cb = blockIdx.x; }
    else                       { src = srcB; dst = dstB; bcur = bcurB; out = outB; E = EB; cb = blockIdx.x - nbA; }
    int t = threadIdx.x;
    int base = cb * CHUNK;
    int cnt = min(CHUNK, E - base);
    lh[t] = 0;
    __syncthreads();
    for (int i = t; i < cnt; i += 1024) atomicAdd(&lh[dst[base + i] >> 6], 1);
    __syncthreads();
    int vdeg = lh[t];
    int incl = vdeg;
    #pragma unroll
    for (int off = 1; off < 64; off <<= 1) {
        int tv = __shfl_up(incl, off);
        if ((t & 63) >= off) incl += tv;
    }
    if ((t & 63) == 63) gof[t >> 6] = incl;
    __syncthreads();
    if (t < 16) {
        int wv = gof[t];
        int winc = wv;
        #pragma unroll
        for (int off = 1; off < 16; off <<= 1) {
            int tv = __shfl_up(winc, off, 16);
            if (t >= off) winc += tv;
        }
        gof[16 + t] = winc - wv;
    }
    __syncthreads();
    int excl = incl - vdeg + gof[16 + (t >> 6)];
    loff[t] = excl;
    lcur[t] = excl;
    __syncthreads();
    gof[t] = vdeg ? atomicAdd(&bcur[t], vdeg) : 0;
    __syncthreads();
    for (int i = t; i < cnt; i += 1024) {
        int d = dst[base + i];
        int s = src[base + i];
        int bkt = d >> 6;
        int p = atomicAdd(&lcur[bkt], 1);
        stage[p] = (unsigned int)s | ((unsigned int)(d & 63) << 16) |
                   ((unsigned int)bkt << 22);
    }
    __syncthreads();
    for (int i = t; i < cnt; i += 1024) {
        unsigned int e = stage[i];
        int bkt = (int)(e >> 22);
        out[gof[bkt] + (i - loff[bkt])] = e & 0x3FFFFFu;
    }
}

// ------- fused CSR build: deg count + scan -> rs/dinv, then in-window scatter ----
__global__ void __launch_bounds__(256)
k_csr2(const int* __restrict__ bbaseA, const unsigned int* __restrict__ ebufA,
       int* __restrict__ rsA, float* __restrict__ dvA, unsigned short* __restrict__ ssrcA, int EA,
       const int* __restrict__ bbaseB, const unsigned int* __restrict__ ebufB,
       int* __restrict__ rsB, float* __restrict__ dvB, unsigned short* __restrict__ ssrcB, int EB,
       int B, int n) {
    __shared__ int cnt[64];
    __shared__ int lcur[64];
    const int* bbase; const unsigned int* ebuf; int* rs; float* dv;
    unsigned short* ssrc; int b, Etot;
    if ((int)blockIdx.x < B) { bbase = bbaseA; ebuf = ebufA; rs = rsA; dv = dvA; ssrc = ssrcA; b = blockIdx.x; Etot = EA; }
    else                     { bbase = bbaseB; ebuf = ebufB; rs = rsB; dv = dvB; ssrc = ssrcB; b = blockIdx.x - B; Etot = EB; }
    int t = threadIdx.x;
    if (t < 64) cnt[t] = 0;
    __syncthreads();
    int beg = bbase[b], end = bbase[b + 1];
    for (int i = beg + t; i < end; i += 256)
        atomicAdd(&cnt[(ebuf[i] >> 16) & 63u], 1);
    __syncthreads();
    if (t < 64) {
        int v = cnt[t];
        int incl = v;
        #pragma unroll
        for (int off = 1; off < 64; off <<= 1) {
            int tv = __shfl_up(incl, off);
            if (t >= off) incl += tv;
        }
        int start = beg + incl - v;
        lcur[t] = start;
        int node = b * NPB + t;
        if (node < n) {
            rs[node] = start;
            dv[node] = (v > 0) ? rsqrtf((float)v) : 0.f;
        }
    }
    __syncthreads();
    for (int i = beg + t; i < end; i += 256) {
        unsigned int e = ebuf[i];
        int p = atomicAdd(&lcur[(e >> 16) & 63u], 1);
        ssrc[p] = (unsigned short)(e & 0xFFFFu);
    }
    if (t == 0 && b == B - 1) rs[n] = Etot;
}

// ------- pack: psrc[i] = src | bf16(dinv[src])<<16 (both sets, grid-stride) ----
__global__ void k_pack(const unsigned short* __restrict__ ssrc1, const float* __restrict__ dinv1,
                       unsigned int* __restrict__ p1, int E1,
                       const unsigned short* __restrict__ ssrc2, const float* __restrict__ dinv2,
                       unsigned int* __restrict__ p2, int E2) {
    int stride = gridDim.x * 256;
    for (int i = blockIdx.x * 256 + threadIdx.x; i < E1 + E2; i += stride) {
        if (i < E1) {
            int s = ssrc1[i];
            p1[i] = (unsigned int)s | ((unsigned int)f2b(dinv1[s]) << 16);
        } else {
            int j = i - E1;
            int s = ssrc2[j];
            p2[j] = (unsigned int)s | ((unsigned int)f2b(dinv2[s]) << 16);
        }
    }
}

// ------- x8-unrolled 64-feat gather body; packed src+scale stream -------
__device__ inline void agg64_body(const int* __restrict__ rs,
                                  const unsigned int* __restrict__ psrc,
                                  const float* __restrict__ dinv,
                                  const us8* __restrict__ hwb8,
                                  const float* __restrict__ b1,
                                  unsigned short* __restrict__ R1b,
                                  int col_unit, int n, int tid) {
    int v = tid >> 3, q = tid & 7;
    if (v >= n) return;
    int beg = rs[v], end = rs[v + 1];
    float a[8] = {0.f, 0.f, 0.f, 0.f, 0.f, 0.f, 0.f, 0.f};
    int i = beg;
    for (; i + 8 <= end; i += 8) {   // 8 independent chains; scalar broadcast loads
        unsigned int e0 = psrc[i + 0], e1 = psrc[i + 1], e2 = psrc[i + 2], e3 = psrc[i + 3];
        unsigned int e4 = psrc[i + 4], e5 = psrc[i + 5], e6 = psrc[i + 6], e7 = psrc[i + 7];
        int s0 = e0 & 0xFFFFu, s1 = e1 & 0xFFFFu, s2 = e2 & 0xFFFFu, s3 = e3 & 0xFFFFu;
        int s4 = e4 & 0xFFFFu, s5 = e5 & 0xFFFFu, s6 = e6 & 0xFFFFu, s7 = e7 & 0xFFFFu;
        float c0 = b2f((unsigned short)(e0 >> 16)), c1 = b2f((unsigned short)(e1 >> 16));
        float c2 = b2f((unsigned short)(e2 >> 16)), c3 = b2f((unsigned short)(e3 >> 16));
        float c4 = b2f((unsigned short)(e4 >> 16)), c5 = b2f((unsigned short)(e5 >> 16));
        float c6 = b2f((unsigned short)(e6 >> 16)), c7 = b2f((unsigned short)(e7 >> 16));
        us8 h0 = hwb8[s0 * 8 + q], h1 = hwb8[s1 * 8 + q];
        us8 h2 = hwb8[s2 * 8 + q], h3 = hwb8[s3 * 8 + q];
        us8 h4 = hwb8[s4 * 8 + q], h5 = hwb8[s5 * 8 + q];
        us8 h6 = hwb8[s6 * 8 + q], h7 = hwb8[s7 * 8 + q];
        #pragma unroll
        for (int j = 0; j < 8; ++j) {
            a[j] = fmaf(b2f(h0[j]), c0, a[j]);
            a[j] = fmaf(b2f(h1[j]), c1, a[j]);
            a[j] = fmaf(b2f(h2[j]), c2, a[j]);
            a[j] = fmaf(b2f(h3[j]), c3, a[j]);
            a[j] = fmaf(b2f(h4[j]), c4, a[j]);
            a[j] = fmaf(b2f(h5[j]), c5, a[j]);
            a[j] = fmaf(b2f(h6[j]), c6, a[j]);
            a[j] = fmaf(b2f(h7[j]), c7, a[j]);
        }
    }
    for (; i < end; ++i) {
        unsigned int e = psrc[i];
        int s = e & 0xFFFFu;
        float sc = b2f((unsigned short)(e >> 16));
        us8 h = hwb8[s * 8 + q];
        #pragma unroll
        for (int j = 0; j < 8; ++j) a[j] = fmaf(b2f(h[j]), sc, a[j]);
    }
    float dd = dinv[v];
    us8 o;
    #pragma unroll
    for (int j = 0; j < 8; ++j) {
        float r = fmaf(a[j], dd, b1[q * 8 + j]);
        o[j] = f2b(r > 0.f ? r : 0.f);
    }
    ((us8*)&R1b[v * 192])[col_unit + q] = o;
}

// ------- fused layer-1: E2 agg | E1 agg | self (blockIdx ranges; E2 first) -------
__global__ void k_agg1f(const int* __restrict__ rs1, const unsigned int* __restrict__ psrc1,
                        const float* __restrict__ dinv1,
                        const int* __restrict__ rs2, const unsigned int* __restrict__ psrc2,
                        const float* __restrict__ dinv2,
                        const us8* __restrict__ hwb8, const float* __restrict__ b1,
                        unsigned short* __restrict__ R1b, int n, int nba) {
    int bid = blockIdx.x;
    if (bid < nba) {
        agg64_body(rs2, psrc2, dinv2, hwb8, b1, R1b, 8, n, bid * 256 + threadIdx.x);
    } else if (bid < 2 * nba) {
        agg64_body(rs1, psrc1, dinv1, hwb8, b1, R1b, 0, n,
                   (bid - nba) * 256 + threadIdx.x);
    } else {
        int tid = (bid - 2 * nba) * 256 + threadIdx.x;
        int v = tid >> 3, q = tid & 7;
        if (v >= n) return;
        us8 h = hwb8[v * 8 + q];
        us8 o;
        #pragma unroll
        for (int j = 0; j < 8; ++j) {
            float r = b2f(h[j]) + b1[q * 8 + j];
            o[j] = f2b(r > 0.f ? r : 0.f);
        }
        ((us8*)&R1b[v * 192])[16 + q] = o;
    }
}

// ---------------- GEMM2: hwb2 = bf16(R1 @ w2)  ([n,192]@[192,16]) ----------------
__global__ void __launch_bounds__(256)
k_gemm2(const unsigned short* __restrict__ R1b, const float* __restrict__ w2,
        unsigned short* __restrict__ hwb2, int n) {
    __shared__ float ws[192 * 16];
    __shared__ float rs[16][193];
    int t = threadIdx.x;
    for (int i = t; i < 192 * 16; i += 256) ws[i] = w2[i];
    int row0 = blockIdx.x * 16;
    for (int i = t; i < 16 * 192; i += 256) {
        int r = i / 192, j = i - r * 192;
        int v = row0 + r;
        rs[r][j] = (v < n) ? b2f(R1b[v * 192 + j]) : 0.f;
    }
    __syncthreads();
    int r = t >> 4, c = t & 15;
    int v = row0 + r;
    if (v >= n) return;
    float acc = 0.f;
    #pragma unroll 8
    for (int j = 0; j < 192; ++j) acc += rs[r][j] * ws[j * 16 + c];
    hwb2[v * 16 + c] = f2b(acc);
}

// ------- 16-feat gather (2 lanes/node), packed stream, scalar loads -------
__device__ inline void gath16(const int* __restrict__ rs,
                              const unsigned int* __restrict__ psrc,
                              const us8* __restrict__ h8,
                              int v, int q, float* __restrict__ a) {
    int beg = rs[v], end = rs[v + 1];
    #pragma unroll
    for (int j = 0; j < 8; ++j) a[j] = 0.f;
    int i = beg;
    for (; i + 8 <= end; i += 8) {
        unsigned int e0 = psrc[i + 0], e1 = psrc[i + 1], e2 = psrc[i + 2], e3 = psrc[i + 3];
        unsigned int e4 = psrc[i + 4], e5 = psrc[i + 5], e6 = psrc[i + 6], e7 = psrc[i + 7];
        int s0 = e0 & 0xFFFFu, s1 = e1 & 0xFFFFu, s2 = e2 & 0xFFFFu, s3 = e3 & 0xFFFFu;
        int s4 = e4 & 0xFFFFu, s5 = e5 & 0xFFFFu, s6 = e6 & 0xFFFFu, s7 = e7 & 0xFFFFu;
        float c0 = b2f((unsigned short)(e0 >> 16)), c1 = b2f((unsigned short)(e1 >> 16));
        float c2 = b2f((unsigned short)(e2 >> 16)), c3 = b2f((unsigned short)(e3 >> 16));
        float c4 = b2f((unsigned short)(e4 >> 16)), c5 = b2f((unsigned short)(e5 >> 16));
        float c6 = b2f((unsigned short)(e6 >> 16)), c7 = b2f((unsigned short)(e7 >> 16));
        us8 h0 = h8[s0 * 2 + q], h1 = h8[s1 * 2 + q];
        us8 h2 = h8[s2 * 2 + q], h3 = h8[s3 * 2 + q];
        us8 h4 = h8[s4 * 2 + q], h5 = h8[s5 * 2 + q];
        us8 h6 = h8[s6 * 2 + q], h7 = h8[s7 * 2 + q];
        #pragma unroll
        for (int j = 0; j < 8; ++j) {
            a[j] = fmaf(b2f(h0[j]), c0, a[j]);
            a[j] = fmaf(b2f(h1[j]), c1, a[j]);
            a[j] = fmaf(b2f(h2[j]), c2, a[j]);
            a[j] = fmaf(b2f(h3[j]), c3, a[j]);
            a[j] = fmaf(b2f(h4[j]), c4, a[j]);
            a[j] = fmaf(b2f(h5[j]), c5, a[j]);
            a[j] = fmaf(b2f(h6[j]), c6, a[j]);
            a[j] = fmaf(b2f(h7[j]), c7, a[j]);
        }
    }
    for (; i < end; ++i) {
        unsigned int e = psrc[i];
        int s = e & 0xFFFFu;
        float sc = b2f((unsigned short)(e >> 16));
        us8 h = h8[s * 2 + q];
        #pragma unroll
        for (int j = 0; j < 8; ++j) a[j] = fmaf(b2f(h[j]), sc, a[j]);
    }
}

// ------- fused layer-2 aggregate + linear head + log_softmax (128 nodes/block) ----
__global__ void __launch_bounds__(256)
k_l2f(const int* __restrict__ rs1, const unsigned int* __restrict__ psrc1,
      const float* __restrict__ dinv1,
      const int* __restrict__ rs2, const unsigned int* __restrict__ psrc2,
      const float* __restrict__ dinv2,
      const us8* __restrict__ hwb2_8, const unsigned short* __restrict__ hwb2,
      const float* __restrict__ b2, const float* __restrict__ lw,
      const float* __restrict__ lb, float* __restrict__ out, int n) {
    __shared__ float accA[128 * 16];
    __shared__ float accB[128 * 16];
    __shared__ float lws[48 * 16];
    __shared__ float r2s[16][49];
    int t = threadIdx.x;
    int v0 = blockIdx.x * 128;
    for (int i = t; i < 48 * 16; i += 256) lws[i] = lw[i];
    int vl = t >> 1, q = t & 1;
    int v = v0 + vl;
    if (v < n) {
        float a[8];
        gath16(rs2, psrc2, hwb2_8, v, q, a);
        #pragma unroll
        for (int j = 0; j < 8; ++j) accB[vl * 16 + q * 8 + j] = a[j];
        gath16(rs1, psrc1, hwb2_8, v, q, a);
        #pragma unroll
        for (int j = 0; j < 8; ++j) accA[vl * 16 + q * 8 + j] = a[j];
    }
    __syncthreads();
    int ni = t >> 4, c = t & 15;
    for (int p = 0; p < 8; ++p) {
        int vv = v0 + p * 16 + ni;
        int vl2 = p * 16 + ni;
        if (vv < n) {
            float bb = b2[c];
            r2s[ni][c]      = fmaf(dinv1[vv], accA[vl2 * 16 + c], bb);
            r2s[ni][16 + c] = fmaf(dinv2[vv], accB[vl2 * 16 + c], bb);
            r2s[ni][32 + c] = b2f(hwb2[vv * 16 + c]) + bb;
        }
        __syncthreads();
        if (vv < n) {
            float o = lb[c];
            #pragma unroll
            for (int j = 0; j < 48; ++j) o += r2s[ni][j] * lws[j * 16 + c];
            float m = o;
            for (int off = 8; off >= 1; off >>= 1) m = fmaxf(m, __shfl_xor(m, off, 16));
            float e = expf(o - m);
            float ssum = e;
            for (int off = 8; off >= 1; off >>= 1) ssum += __shfl_xor(ssum, off, 16);
            out[vv * 16 + c] = (o - m) - logf(ssum);
        }
        __syncthreads();
    }
}

extern "C" void kernel_launch(void* const* d_in, const int* in_sizes, int n_in,
                              void* d_out, int out_size, void* d_ws, size_t ws_size,
                              hipStream_t stream) {
    const float* x     = (const float*)d_in[0];
    const float* w1    = (const float*)d_in[1];
    const float* b1    = (const float*)d_in[2];
    const float* w2    = (const float*)d_in[3];
    const float* b2    = (const float*)d_in[4];
    const float* lin_w = (const float*)d_in[5];
    const float* lin_b = (const float*)d_in[6];
    const int*   ei    = (const int*)d_in[7];
    const int*   ei2   = (const int*)d_in[8];

    const int n  = in_sizes[0] / 128;   // 50000
    const int E1 = in_sizes[7] / 2;     // 800000
    const int E2 = in_sizes[8] / 2;     // 3000000
    const int B  = (n + NPB - 1) / NPB; // 782

    char* ws = (char*)d_ws;
    unsigned short* hwb   = (unsigned short*)(ws + 0);         // [n,64] bf16 -> 6.4M
    unsigned short* hwb2  = (unsigned short*)(ws + 6400000);   // [n,16] bf16 -> 8.0M
    unsigned short* R1b   = (unsigned short*)(ws + 8000000);   // [n,192] bf16 -> 27.2M
    unsigned short* ssrc1 = (unsigned short*)(ws + 27200000);  // [E1] -> 28.8M
    unsigned short* ssrc2 = (unsigned short*)(ws + 28800000);  // [E2] -> 34.8M
    unsigned int* ebuf1   = (unsigned int*)(ws + 34800000);    // [E1] -> 38.0M (dead after csr2)
    unsigned int* ebuf2   = (unsigned int*)(ws + 38000000);    // [E2] -> 50.0M (dead after csr2)
    unsigned int* psrc1   = ebuf1;                             // packed reuse
    unsigned int* psrc2   = ebuf2;                             // packed reuse
    float*        dinv1   = (float*)(ws + 56800000);           // [n]
    float*        dinv2   = (float*)(ws + 57000000);           // [n]
    int*          rs1     = (int*)(ws + 57200000);             // [n+1]
    int*          rs2     = (int*)(ws + 57400016);             // [n+1]
    int*          bhist1  = (int*)(ws + 58000032);             // [1024]
    int*          bhist2  = (int*)(ws + 58004128);             // [1024] (contiguous)
    int*          bbase1  = (int*)(ws + 58008224);             // [B+1]
    int*          bbase2  = (int*)(ws + 58012320);             // [B+1]
    int*          bcur1   = (int*)(ws + 58016416);             // [1024]
    int*          bcur2   = (int*)(ws + 58020512);             // [1024]

    hipMemsetAsync(bhist1, 0, 8192, stream);   // bhist1+bhist2, contiguous

    k_gemm1<<<(n + 63) / 64, 256, 0, stream>>>(x, w1, hwb, n);

    const int nbh1 = (E1 + HCHUNK - 1) / HCHUNK, nbh2 = (E2 + HCHUNK - 1) / HCHUNK;
    k_hist2<<<nbh1 + nbh2, 256, 0, stream>>>(ei + E1, bhist1, E1, nbh1,
                                             ei2 + E2, bhist2, E2);
    k_bscan<<<2, 64, 0, stream>>>(bhist1, bbase1, bcur1, bhist2, bbase2, bcur2, B);

    const int nbp1 = (E1 + CHUNK - 1) / CHUNK, nbp2 = (E2 + CHUNK - 1) / CHUNK;
    k_part2<<<nbp1 + nbp2, 1024, 0, stream>>>(ei, ei + E1, bcur1, ebuf1, E1, nbp1,
                                              ei2, ei2 + E2, bcur2, ebuf2, E2);

    k_csr2<<<2 * B, 256, 0, stream>>>(bbase1, ebuf1, rs1, dinv1, ssrc1, E1,
                                      bbase2, ebuf2, rs2, dinv2, ssrc2, E2, B, n);

    k_pack<<<2048, 256, 0, stream>>>(ssrc1, dinv1, psrc1, E1, ssrc2, dinv2, psrc2, E2);

    const int nba = (n * 8 + 255) / 256;
    k_agg1f<<<3 * nba, 256, 0, stream>>>(rs1, psrc1, dinv1, rs2, psrc2, dinv2,
                                         (const us8*)hwb, b1, R1b, n, nba);

    k_gemm2<<<(n + 15) / 16, 256, 0, stream>>>(R1b, w2, hwb2, n);

    k_l2f<<<(n + 127) / 128, 256, 0, stream>>>(rs1, psrc1, dinv1, rs2, psrc2, dinv2,
                                               (const us8*)hwb2, hwb2, b2,
                                               lin_w, lin_b, (float*)d_out, n);
}